// Round 12
// baseline (376.471 us; speedup 1.0000x reference)
//
#include <hip/hip_runtime.h>

#define N_ 384
#define LNEPS 1e-5f

typedef __attribute__((ext_vector_type(8))) short bf16x8;
typedef __attribute__((ext_vector_type(4))) float f32x4;

__device__ __forceinline__ float bf2f(unsigned int u) {
    union { unsigned int i; float f; } v; v.i = u << 16; return v.f;
}
__device__ __forceinline__ unsigned short f2bf(float f) {
    union { float f; unsigned int i; } v; v.f = f;
    return (unsigned short)((v.i + 0x7FFFu + ((v.i >> 16) & 1u)) >> 16);
}
__device__ __forceinline__ void gload16(const void* g, void* l) {
    __builtin_amdgcn_global_load_lds(
        (const __attribute__((address_space(1))) void*)g,
        (__attribute__((address_space(3))) void*)l, 16, 0, 0);
}

// ---------------------------------------------------------------------------
// Kernel 0: convert projection weights to bf16 hi/lo pairs, [col][k] layout.
// ---------------------------------------------------------------------------
__global__ __launch_bounds__(256) void k0_prep(
    const float* __restrict__ W_V, const float* __restrict__ W_EG,
    unsigned short* __restrict__ Whi, unsigned short* __restrict__ Wlo)
{
    int x = blockIdx.x * 256 + threadIdx.x;
    if (x >= 10240) return;
    int col = x >> 6, k = x & 63;
    float wv = (col < 128) ? W_V[k * 128 + col] : W_EG[k * 32 + (col - 128)];
    unsigned short hi = f2bf(wv);
    Whi[x] = hi;
    Wlo[x] = f2bf(wv - bf2f(hi));
}

// ---------------------------------------------------------------------------
// Kernel 1: LN + V/EG projections. Round-11-verified per-tile pipeline; change:
// 4 row-tiles per block (grid /4) with cross-tile e-prefetch and L1-hot W
// fragment reuse. Per-row numerics identical to round 11.
// ---------------------------------------------------------------------------
__global__ __launch_bounds__(256, 4) void k1_ln_proj(
    const float* __restrict__ e, const float* __restrict__ mask,
    const float* __restrict__ ln_w, const float* __restrict__ ln_b,
    const unsigned short* __restrict__ Whi_g, const unsigned short* __restrict__ Wlo_g,
    const float* __restrict__ b_V, const float* __restrict__ b_EG,
    unsigned short* __restrict__ VtIn, unsigned short* __restrict__ VtOut,
    float* __restrict__ EGin, float* __restrict__ EGoutT)
{
    // s_v [64r][130] bf16 (16,640 B) + s_eg [64r][33] f32 (8,448 B)
    __shared__ __align__(16) char smem[25088];
    unsigned short* s_v = (unsigned short*)smem;
    float* s_eg = (float*)(smem + 16640);

    const int t = threadIdx.x;
    const int j0 = blockIdx.x * 4;    // r2 base (96 tiles)
    const int i0 = blockIdx.y * 64;   // r1 base (6 tiles)
    const int b  = blockIdx.z;

    const int l = t & 63, w = t >> 6;
    const int l15 = l & 15, lq = l >> 4;
    const int rr = w * 16 + l15;                 // fragment row in tile
    const int r2f = j0 + (rr & 3);
    const int r1b = i0 + (rr >> 2);              // + tau*16

    float4 ecur[4], enx[4];
    {
        const float* erow = e + ((size_t)((b * N_ + r1b) * N_ + r2f)) * 64;
        ecur[0] = *(const float4*)(erow + lq * 8);
        ecur[1] = *(const float4*)(erow + lq * 8 + 4);
        ecur[2] = *(const float4*)(erow + 32 + lq * 8);
        ecur[3] = *(const float4*)(erow + 32 + lq * 8 + 4);
    }

    #pragma unroll
    for (int tau = 0; tau < 4; ++tau) {
        // prefetch next tile's e (hidden under MFMA + epilogue)
        if (tau < 3) {
            const float* erow = e + ((size_t)((b * N_ + r1b + (tau + 1) * 16) * N_ + r2f)) * 64;
            enx[0] = *(const float4*)(erow + lq * 8);
            enx[1] = *(const float4*)(erow + lq * 8 + 4);
            enx[2] = *(const float4*)(erow + 32 + lq * 8);
            enx[3] = *(const float4*)(erow + 32 + lq * 8 + 4);
        }

        // in-register LN (round-11 numerics)
        float s = 0.f, sq = 0.f;
        #pragma unroll
        for (int p = 0; p < 4; ++p) {
            s  += ecur[p].x + ecur[p].y + ecur[p].z + ecur[p].w;
            sq += ecur[p].x*ecur[p].x + ecur[p].y*ecur[p].y
                + ecur[p].z*ecur[p].z + ecur[p].w*ecur[p].w;
        }
        s  += __shfl_xor(s, 16);  s  += __shfl_xor(s, 32);
        sq += __shfl_xor(sq, 16); sq += __shfl_xor(sq, 32);
        const float mean = s * (1.f / 64.f);
        const float rstd = rsqrtf(sq * (1.f / 64.f) - mean * mean + LNEPS);

        bf16x8 ahi[2], alo[2];
        #pragma unroll
        for (int ks = 0; ks < 2; ++ks) {
            #pragma unroll
            for (int g4 = 0; g4 < 2; ++g4) {
                float4 xv = ecur[ks * 2 + g4];
                float4 wv4 = *(const float4*)(ln_w + ks * 32 + lq * 8 + g4 * 4);
                float4 bv4 = *(const float4*)(ln_b + ks * 32 + lq * 8 + g4 * 4);
                float xs[4] = {xv.x, xv.y, xv.z, xv.w};
                float ws[4] = {wv4.x, wv4.y, wv4.z, wv4.w};
                float bs[4] = {bv4.x, bv4.y, bv4.z, bv4.w};
                #pragma unroll
                for (int u = 0; u < 4; ++u) {
                    float x = (xs[u] - mean) * rstd * ws[u] + bs[u];
                    unsigned short h = f2bf(x);
                    unsigned short lo = f2bf(x - bf2f(h));
                    ahi[ks][g4 * 4 + u] = (short)h;
                    alo[ks][g4 * 4 + u] = (short)lo;
                }
            }
        }

        // MFMA inner product (verified verbatim; W L1-hot for tau>0)
        f32x4 acc[10];
        #pragma unroll
        for (int n = 0; n < 10; ++n) acc[n] = (f32x4){0.f, 0.f, 0.f, 0.f};
        #pragma unroll
        for (int n = 0; n < 10; ++n) {
            int brow = n * 16 + l15;
            const unsigned short* wh = Whi_g + brow * 64;
            const unsigned short* wl = Wlo_g + brow * 64;
            bf16x8 bh0 = *(const bf16x8*)(wh + lq * 8);
            bf16x8 bh1 = *(const bf16x8*)(wh + 32 + lq * 8);
            bf16x8 bl0 = *(const bf16x8*)(wl + lq * 8);
            bf16x8 bl1 = *(const bf16x8*)(wl + 32 + lq * 8);
            acc[n] = __builtin_amdgcn_mfma_f32_16x16x32_bf16(ahi[0], bh0, acc[n], 0, 0, 0);
            acc[n] = __builtin_amdgcn_mfma_f32_16x16x32_bf16(ahi[1], bh1, acc[n], 0, 0, 0);
            acc[n] = __builtin_amdgcn_mfma_f32_16x16x32_bf16(ahi[0], bl0, acc[n], 0, 0, 0);
            acc[n] = __builtin_amdgcn_mfma_f32_16x16x32_bf16(ahi[1], bl1, acc[n], 0, 0, 0);
            acc[n] = __builtin_amdgcn_mfma_f32_16x16x32_bf16(alo[0], bh0, acc[n], 0, 0, 0);
            acc[n] = __builtin_amdgcn_mfma_f32_16x16x32_bf16(alo[1], bh1, acc[n], 0, 0, 0);
        }

        // D write-back (verified layout)
        #pragma unroll
        for (int n = 0; n < 8; ++n) {
            float bb = b_V[n * 16 + l15];
            #pragma unroll
            for (int q = 0; q < 4; ++q)
                s_v[(w * 16 + lq * 4 + q) * 130 + n * 16 + l15] = f2bf(acc[n][q] + bb);
        }
        #pragma unroll
        for (int n = 8; n < 10; ++n) {
            #pragma unroll
            for (int q = 0; q < 4; ++q)
                s_eg[(w * 16 + lq * 4 + q) * 33 + (n - 8) * 16 + l15] = acc[n][q];
        }
        __syncthreads();

        // epilogue (verified formulas; r1 shifted by tau*16)
        {
            const int rv = t & 63, g = t >> 6;
            const int r1 = i0 + tau * 16 + (rv >> 2);
            const int r2 = j0 + (rv & 3);
            #pragma unroll
            for (int io = 0; io < 2; ++io) {
                #pragma unroll
                for (int hs = 0; hs < 2; ++hs) {
                    const int h = g + hs * 4;
                    uint4 u4;
                    unsigned int wv[4];
                    #pragma unroll
                    for (int dp = 0; dp < 4; ++dp) {
                        int c0 = io * 64 + (2 * dp) * 8 + h;
                        int c1 = io * 64 + (2 * dp + 1) * 8 + h;
                        wv[dp] = (unsigned int)s_v[rv * 130 + c0]
                               | ((unsigned int)s_v[rv * 130 + c1] << 16);
                    }
                    u4.x = wv[0]; u4.y = wv[1]; u4.z = wv[2]; u4.w = wv[3];
                    if (io == 0) {
                        *(uint4*)(VtIn + ((size_t)((b * 8 + h) * N_ + r2)) * 3072 + (size_t)r1 * 8) = u4;
                    } else {
                        *(uint4*)(VtOut + ((size_t)((b * 8 + h) * N_ + r1)) * 3072 + (size_t)r2 * 8) = u4;
                    }
                }
            }
        }
        {
            const int rv = t >> 2, cq = (t & 3) * 4;
            const int r1 = i0 + tau * 16 + (rv >> 2);
            const int r2 = j0 + (rv & 3);
            const float maskv = mask[(size_t)(b * N_ + r1) * N_ + r2];
            float4 v0, v1;
            float tmp0[4], tmp1[4];
            #pragma unroll
            for (int u = 0; u < 4; ++u) {
                int c2 = cq + u;
                float x = s_eg[rv * 33 + c2] + b_EG[c2] + maskv;
                if (c2 >= 8) x = 1.f / (1.f + expf(-x));
                tmp0[u] = x;
                int c3 = 16 + cq + u;
                float y = s_eg[rv * 33 + c3] + b_EG[c3] + maskv;
                if ((cq + u) >= 8) y = 1.f / (1.f + expf(-y));
                tmp1[u] = y;
            }
            v0.x = tmp0[0]; v0.y = tmp0[1]; v0.z = tmp0[2]; v0.w = tmp0[3];
            v1.x = tmp1[0]; v1.y = tmp1[1]; v1.z = tmp1[2]; v1.w = tmp1[3];
            *(float4*)(EGin   + ((size_t)((b * N_ + r1) * N_ + r2)) * 16 + cq) = v0;
            *(float4*)(EGoutT + ((size_t)((b * N_ + r2) * N_ + r1)) * 16 + cq) = v1;
        }
        __syncthreads();   // protect s_v/s_eg reuse by next tau

        ecur[0] = enx[0]; ecur[1] = enx[1]; ecur[2] = enx[2]; ecur[3] = enx[3];
    }
}

// ---------------------------------------------------------------------------
// Kernel 2: gated softmax over k (verified).
// ---------------------------------------------------------------------------
__global__ __launch_bounds__(256) void k2_softmax(
    const float* __restrict__ EG, unsigned short* __restrict__ A)
{
    __shared__ float s[384 * 17];
    const int t = threadIdx.x;
    const int i = blockIdx.x % N_, b = blockIdx.x / N_;
    const float* base = EG + ((size_t)(b * N_ + i) * N_) * 16;
    for (int x = t; x < 6144; x += 256) {
        int k = x >> 4, c = x & 15;
        s[k * 17 + c] = base[x];
    }
    __syncthreads();
    const int h = t >> 5, l = t & 31;
    float ev[12];
    float mx = -1e30f;
    #pragma unroll
    for (int j = 0; j < 12; ++j) {
        ev[j] = s[(l + 32 * j) * 17 + h];
        mx = fmaxf(mx, ev[j]);
    }
    #pragma unroll
    for (int off = 16; off >= 1; off >>= 1) mx = fmaxf(mx, __shfl_xor(mx, off));
    float sum = 0.f;
    #pragma unroll
    for (int j = 0; j < 12; ++j) { ev[j] = expf(ev[j] - mx); sum += ev[j]; }
    #pragma unroll
    for (int off = 16; off >= 1; off >>= 1) sum += __shfl_xor(sum, off);
    const float inv = 1.f / sum;
    unsigned short* arow = A + ((size_t)((b * 8 + h) * N_ + i)) * N_;
    #pragma unroll
    for (int j = 0; j < 12; ++j) {
        int k = l + 32 * j;
        arow[k] = f2bf(ev[j] * inv * s[k * 17 + 8 + h]);
    }
}

// ---------------------------------------------------------------------------
// Kernel 2t: transpose V planes: [plane][k=384][jd=3072] -> [plane][jd][k].
// (round-2-verified verbatim)
// ---------------------------------------------------------------------------
__global__ __launch_bounds__(256) void k2t_transpose(
    const unsigned short* __restrict__ VtIn, const unsigned short* __restrict__ VtOut,
    unsigned short* __restrict__ VT2In, unsigned short* __restrict__ VT2Out)
{
    __shared__ unsigned short s[64 * 72];
    const int t = threadIdx.x;
    const int ktile = blockIdx.x % 6, jt = blockIdx.x / 6;
    const int q = blockIdx.y;
    const int arr = blockIdx.z;
    const unsigned short* src = (arr ? VtOut : VtIn) + (size_t)q * 1179648;
    unsigned short* dst = (arr ? VT2Out : VT2In) + (size_t)q * 1179648;
    const int k0 = ktile * 64, jd0 = jt * 64;

    {
        const int kk = t >> 2, cgq = t & 3;
        const unsigned short* g = src + (size_t)(k0 + kk) * 3072 + jd0 + cgq * 16;
        uint4 u0 = *(const uint4*)g;
        uint4 u1 = *(const uint4*)(g + 8);
        int cp = (cgq ^ (kk & 3)) * 16;
        *(uint4*)&s[kk * 72 + cp] = u0;
        *(uint4*)&s[kk * 72 + cp + 8] = u1;
    }
    __syncthreads();
    {
        const int jj = t & 63, kq = (t >> 6) * 16;
        unsigned int wv[8];
        #pragma unroll
        for (int p = 0; p < 8; ++p) {
            int u0 = 2 * p, u1 = 2 * p + 1;
            unsigned short a = s[(kq + u0) * 72 + (((jj >> 4) ^ (u0 & 3)) << 4) + (jj & 15)];
            unsigned short c = s[(kq + u1) * 72 + (((jj >> 4) ^ (u1 & 3)) << 4) + (jj & 15)];
            wv[p] = (unsigned int)a | ((unsigned int)c << 16);
        }
        unsigned short* o = dst + (size_t)(jd0 + jj) * 384 + k0 + kq;
        uint4 x0; x0.x = wv[0]; x0.y = wv[1]; x0.z = wv[2]; x0.w = wv[3];
        uint4 x1; x1.x = wv[4]; x1.y = wv[5]; x1.z = wv[6]; x1.w = wv[7];
        *(uint4*)o = x0;
        *(uint4*)(o + 8) = x1;
    }
}

// ---------------------------------------------------------------------------
// Kernel 3: batched MFMA GEMM, BK=64, global_load_lds staging (verified).
// ---------------------------------------------------------------------------
__global__ __launch_bounds__(256) void k3_mfma(
    const unsigned short* __restrict__ Aall,   // [32][384][384]
    const unsigned short* __restrict__ Vall,   // [32][3072][384]
    unsigned short* __restrict__ C)            // [32][384][3072]
{
    __shared__ __align__(16) short sAB[16384];   // sA [128][64] + sB [128][64]
    short* sA = sAB;
    short* sB = sAB + 8192;

    const int t = threadIdx.x;
    const int n0 = blockIdx.x * 128;
    const int i0 = blockIdx.y * 128;
    const int z  = blockIdx.z;

    const unsigned short* Ap = Aall + (size_t)z * 147456;
    const unsigned short* Bp = Vall + (size_t)z * 1179648;

    const int l = t & 63;
    const int w = t >> 6;
    const int wr = w >> 1, wc = w & 1;
    const int l15 = l & 15, lq = l >> 4;
    const int srow = l >> 3, schunk = (l & 7) ^ (l >> 3);

    f32x4 acc[4][4];
    #pragma unroll
    for (int mi = 0; mi < 4; ++mi)
        #pragma unroll
        for (int ni = 0; ni < 4; ++ni) acc[mi][ni] = (f32x4){0.f, 0.f, 0.f, 0.f};

    #pragma unroll 1
    for (int kt = 0; kt < 6; ++kt) {
        const int k0 = kt * 64;
        #pragma unroll
        for (int i = 0; i < 4; ++i) {
            int rbase = w * 32 + i * 8;
            gload16(Ap + (size_t)(i0 + rbase + srow) * 384 + k0 + schunk * 8,
                    (char*)sA + rbase * 128);
            gload16(Bp + (size_t)(n0 + rbase + srow) * 384 + k0 + schunk * 8,
                    (char*)sB + rbase * 128);
        }
        __syncthreads();

        bf16x8 av[4][2], bv[4][2];
        #pragma unroll
        for (int mi = 0; mi < 4; ++mi) {
            int row = wr * 64 + mi * 16 + l15;
            #pragma unroll
            for (int ks = 0; ks < 2; ++ks) {
                int kc = ks * 4 + lq;
                av[mi][ks] = *(const bf16x8*)((const char*)sA + row * 128 + ((kc ^ (row & 7)) << 4));
            }
        }
        #pragma unroll
        for (int ni = 0; ni < 4; ++ni) {
            int row = wc * 64 + ni * 16 + l15;
            #pragma unroll
            for (int ks = 0; ks < 2; ++ks) {
                int kc = ks * 4 + lq;
                bv[ni][ks] = *(const bf16x8*)((const char*)sB + row * 128 + ((kc ^ (row & 7)) << 4));
            }
        }
        #pragma unroll
        for (int mi = 0; mi < 4; ++mi)
            #pragma unroll
            for (int ni = 0; ni < 4; ++ni) {
                acc[mi][ni] = __builtin_amdgcn_mfma_f32_16x16x32_bf16(av[mi][0], bv[ni][0], acc[mi][ni], 0, 0, 0);
                acc[mi][ni] = __builtin_amdgcn_mfma_f32_16x16x32_bf16(av[mi][1], bv[ni][1], acc[mi][ni], 0, 0, 0);
            }
        __syncthreads();
    }

    unsigned short* Cp = C + (size_t)z * 1179648;
    #pragma unroll
    for (int mi = 0; mi < 4; ++mi) {
        #pragma unroll
        for (int qq = 0; qq < 4; ++qq) {
            int row = i0 + wr * 64 + mi * 16 + lq * 4 + qq;
            unsigned short* crow = Cp + (size_t)row * 3072 + n0 + wc * 64 + l15;
            #pragma unroll
            for (int ni = 0; ni < 4; ++ni) crow[ni * 16] = f2bf(acc[mi][ni][qq]);
        }
    }
}

// ---------------------------------------------------------------------------
// Kernel 4: out = b_O + C(gathered) @ W_O (fp32). (verified)
// ---------------------------------------------------------------------------
__global__ __launch_bounds__(256) void k4_proj(
    const unsigned short* __restrict__ C, const float* __restrict__ W_O,
    const float* __restrict__ b_O, float* __restrict__ out)
{
    __shared__ float s_w[8192];             // [128][64]
    __shared__ unsigned short s_c[20480];   // [16 p][128 j][10]
    const int t = threadIdx.x;
    const int jt = blockIdx.x;
    const int i  = blockIdx.y;
    const int b  = blockIdx.z;

    for (int x = t; x < 8192; x += 256) s_w[x] = W_O[x];
    {
        unsigned int* s_c32 = (unsigned int*)s_c;
        #pragma unroll
        for (int rep = 0; rep < 8; ++rep) {
            int flat = rep * 256 + t;
            int p = flat >> 7, jj = flat & 127;
            int plane = b * 8 + (p & 7) + (p >> 3) * 16;
            uint4 v = *(const uint4*)(C + (size_t)plane * 1179648 + (size_t)i * 3072 + jt * 1024 + jj * 8);
            int base = p * 640 + jj * 5;
            s_c32[base] = v.x; s_c32[base + 1] = v.y; s_c32[base + 2] = v.z; s_c32[base + 3] = v.w;
        }
    }
    __syncthreads();

    const int jg = t & 63, cg = t >> 6;
    const int chb = cg * 16;
    float acc0[16], acc1[16];
    #pragma unroll
    for (int u = 0; u < 16; ++u) { float bb = b_O[chb + u]; acc0[u] = bb; acc1[u] = bb; }

    #pragma unroll 4
    for (int c = 0; c < 128; ++c) {
        const int p = c & 15, d = c >> 4;
        const int sbase = p * 1280 + (jg * 2) * 10 + d;
        float v0 = bf2f((unsigned int)s_c[sbase]);
        float v1 = bf2f((unsigned int)s_c[sbase + 10]);
        const float* wrp = s_w + c * 64 + chb;
        #pragma unroll
        for (int u4 = 0; u4 < 4; ++u4) {
            float4 wv = *(const float4*)(wrp + u4 * 4);
            acc0[u4*4+0] += v0 * wv.x; acc0[u4*4+1] += v0 * wv.y;
            acc0[u4*4+2] += v0 * wv.z; acc0[u4*4+3] += v0 * wv.w;
            acc1[u4*4+0] += v1 * wv.x; acc1[u4*4+1] += v1 * wv.y;
            acc1[u4*4+2] += v1 * wv.z; acc1[u4*4+3] += v1 * wv.w;
        }
    }
    float* o0 = out + ((size_t)(b * N_ + i) * N_ + jt * 128 + jg * 2) * 64 + chb;
    #pragma unroll
    for (int u4 = 0; u4 < 4; ++u4) {
        float4 a; a.x = acc0[u4*4]; a.y = acc0[u4*4+1]; a.z = acc0[u4*4+2]; a.w = acc0[u4*4+3];
        *(float4*)(o0 + u4 * 4) = a;
        float4 c4; c4.x = acc1[u4*4]; c4.y = acc1[u4*4+1]; c4.z = acc1[u4*4+2]; c4.w = acc1[u4*4+3];
        *(float4*)(o0 + 64 + u4 * 4) = c4;
    }
}

// ---------------------------------------------------------------------------
extern "C" void kernel_launch(void* const* d_in, const int* in_sizes, int n_in,
                              void* d_out, int out_size, void* d_ws, size_t ws_size,
                              hipStream_t stream)
{
    const float* e    = (const float*)d_in[0];
    const float* mask = (const float*)d_in[1];
    const float* ln_w = (const float*)d_in[2];
    const float* ln_b = (const float*)d_in[3];
    const float* W_V  = (const float*)d_in[4];
    const float* b_V  = (const float*)d_in[5];
    const float* W_EG = (const float*)d_in[6];
    const float* b_EG = (const float*)d_in[7];
    const float* W_O  = (const float*)d_in[8];
    const float* b_O  = (const float*)d_in[9];
    float* out = (float*)d_out;

    char* ws = (char*)d_ws;
    unsigned short* VtIn   = (unsigned short*)(ws);               // 37,748,736
    unsigned short* VtOut  = (unsigned short*)(ws + 37748736);    // 37,748,736
    unsigned short* A_in   = (unsigned short*)(ws + 75497472);    //  4,718,592
    unsigned short* A_outT = (unsigned short*)(ws + 80216064);    //  4,718,592
    float* EGin   = (float*)(ws + 84934656);                      // 18,874,368 (dead after k2)
    float* EGoutT = (float*)(ws + 103809024);                     // 18,874,368 (dead after k2)
    unsigned short* VT2In  = (unsigned short*)(ws + 84934656);    // 37,748,736 (overlays EG after k2)
    unsigned short* VT2Out = (unsigned short*)(ws + 122683392);   // 37,748,736
    unsigned short* Cws    = (unsigned short*)(ws);               // 75,497,472 (overlays Vt after k2t)
    unsigned short* Whi = A_in;                                   // 20,480 B (k0->k1 transient)
    unsigned short* Wlo = A_in + 10240;                           // 20,480 B

    hipLaunchKernelGGL(k0_prep, dim3(40), dim3(256), 0, stream, W_V, W_EG, Whi, Wlo);
    hipLaunchKernelGGL(k1_ln_proj, dim3(96, 6, 2), dim3(256), 0, stream,
                       e, mask, ln_w, ln_b, Whi, Wlo, b_V, b_EG, VtIn, VtOut, EGin, EGoutT);
    hipLaunchKernelGGL(k2_softmax, dim3(768), dim3(256), 0, stream, EGin, A_in);
    hipLaunchKernelGGL(k2_softmax, dim3(768), dim3(256), 0, stream, EGoutT, A_outT);
    hipLaunchKernelGGL(k2t_transpose, dim3(288, 16, 2), dim3(256), 0, stream,
                       VtIn, VtOut, VT2In, VT2Out);
    hipLaunchKernelGGL(k3_mfma, dim3(24, 3, 32), dim3(256), 0, stream,
                       A_in, VT2In, Cws);
    hipLaunchKernelGGL(k4_proj, dim3(3, 384, 2), dim3(256), 0, stream,
                       Cws, W_O, b_O, out);
}

// Round 13
// 310.733 us; speedup vs baseline: 1.2116x; 1.2116x over previous
//
#include <hip/hip_runtime.h>

#define N_ 384
#define LNEPS 1e-5f

typedef __attribute__((ext_vector_type(8))) short bf16x8;
typedef __attribute__((ext_vector_type(4))) float f32x4;

__device__ __forceinline__ float bf2f(unsigned int u) {
    union { unsigned int i; float f; } v; v.i = u << 16; return v.f;
}
__device__ __forceinline__ unsigned short f2bf(float f) {
    union { float f; unsigned int i; } v; v.f = f;
    return (unsigned short)((v.i + 0x7FFFu + ((v.i >> 16) & 1u)) >> 16);
}
__device__ __forceinline__ void gload16(const void* g, void* l) {
    __builtin_amdgcn_global_load_lds(
        (const __attribute__((address_space(1))) void*)g,
        (__attribute__((address_space(3))) void*)l, 16, 0, 0);
}

// ---------------------------------------------------------------------------
// Kernel 0: convert projection weights to bf16 hi/lo pairs, [col][k] layout.
// ---------------------------------------------------------------------------
__global__ __launch_bounds__(256) void k0_prep(
    const float* __restrict__ W_V, const float* __restrict__ W_EG,
    unsigned short* __restrict__ Whi, unsigned short* __restrict__ Wlo)
{
    int x = blockIdx.x * 256 + threadIdx.x;
    if (x >= 10240) return;
    int col = x >> 6, k = x & 63;
    float wv = (col < 128) ? W_V[k * 128 + col] : W_EG[k * 32 + (col - 128)];
    unsigned short hi = f2bf(wv);
    Whi[x] = hi;
    Wlo[x] = f2bf(wv - bf2f(hi));
}

// ---------------------------------------------------------------------------
// Kernel 1: LN + V/EG projections (round-11-verified VERBATIM: fragment-layout
// e load, in-register LN, one barrier, 25KB LDS).
// ---------------------------------------------------------------------------
__global__ __launch_bounds__(256) void k1_ln_proj(
    const float* __restrict__ e, const float* __restrict__ mask,
    const float* __restrict__ ln_w, const float* __restrict__ ln_b,
    const unsigned short* __restrict__ Whi_g, const unsigned short* __restrict__ Wlo_g,
    const float* __restrict__ b_V, const float* __restrict__ b_EG,
    unsigned short* __restrict__ VtIn, unsigned short* __restrict__ VtOut,
    float* __restrict__ EGin, float* __restrict__ EGoutT)
{
    __shared__ __align__(16) char smem[25088];
    unsigned short* s_v = (unsigned short*)smem;
    float* s_eg = (float*)(smem + 16640);

    const int t = threadIdx.x;
    const int j0 = blockIdx.x * 4;    // r2 base
    const int i0 = blockIdx.y * 16;   // r1 base
    const int b  = blockIdx.z;

    const int l = t & 63, w = t >> 6;
    const int l15 = l & 15, lq = l >> 4;

    const int r = w * 16 + l15;
    const int r1f = i0 + (r >> 2), r2f = j0 + (r & 3);
    const float* erow = e + ((size_t)((b * N_ + r1f) * N_ + r2f)) * 64;
    float ev[16];
    {
        float4 e0 = *(const float4*)(erow + lq * 8);
        float4 e1 = *(const float4*)(erow + lq * 8 + 4);
        float4 e2 = *(const float4*)(erow + 32 + lq * 8);
        float4 e3 = *(const float4*)(erow + 32 + lq * 8 + 4);
        ev[0]=e0.x; ev[1]=e0.y; ev[2]=e0.z;  ev[3]=e0.w;
        ev[4]=e1.x; ev[5]=e1.y; ev[6]=e1.z;  ev[7]=e1.w;
        ev[8]=e2.x; ev[9]=e2.y; ev[10]=e2.z; ev[11]=e2.w;
        ev[12]=e3.x; ev[13]=e3.y; ev[14]=e3.z; ev[15]=e3.w;
    }
    float s = 0.f, sq = 0.f;
    #pragma unroll
    for (int j = 0; j < 16; ++j) { s += ev[j]; sq += ev[j] * ev[j]; }
    s  += __shfl_xor(s, 16);  s  += __shfl_xor(s, 32);
    sq += __shfl_xor(sq, 16); sq += __shfl_xor(sq, 32);
    const float mean = s * (1.f / 64.f);
    const float rstd = rsqrtf(sq * (1.f / 64.f) - mean * mean + LNEPS);

    bf16x8 ahi[2], alo[2];
    {
        float lnwv[16], lnbv[16];
        float4 w0 = *(const float4*)(ln_w + lq * 8);
        float4 w1 = *(const float4*)(ln_w + lq * 8 + 4);
        float4 w2 = *(const float4*)(ln_w + 32 + lq * 8);
        float4 w3 = *(const float4*)(ln_w + 32 + lq * 8 + 4);
        lnwv[0]=w0.x; lnwv[1]=w0.y; lnwv[2]=w0.z;  lnwv[3]=w0.w;
        lnwv[4]=w1.x; lnwv[5]=w1.y; lnwv[6]=w1.z;  lnwv[7]=w1.w;
        lnwv[8]=w2.x; lnwv[9]=w2.y; lnwv[10]=w2.z; lnwv[11]=w2.w;
        lnwv[12]=w3.x; lnwv[13]=w3.y; lnwv[14]=w3.z; lnwv[15]=w3.w;
        float4 b0 = *(const float4*)(ln_b + lq * 8);
        float4 b1 = *(const float4*)(ln_b + lq * 8 + 4);
        float4 b2 = *(const float4*)(ln_b + 32 + lq * 8);
        float4 b3 = *(const float4*)(ln_b + 32 + lq * 8 + 4);
        lnbv[0]=b0.x; lnbv[1]=b0.y; lnbv[2]=b0.z;  lnbv[3]=b0.w;
        lnbv[4]=b1.x; lnbv[5]=b1.y; lnbv[6]=b1.z;  lnbv[7]=b1.w;
        lnbv[8]=b2.x; lnbv[9]=b2.y; lnbv[10]=b2.z; lnbv[11]=b2.w;
        lnbv[12]=b3.x; lnbv[13]=b3.y; lnbv[14]=b3.z; lnbv[15]=b3.w;
        #pragma unroll
        for (int ks = 0; ks < 2; ++ks) {
            #pragma unroll
            for (int j = 0; j < 8; ++j) {
                float x = (ev[ks * 8 + j] - mean) * rstd * lnwv[ks * 8 + j] + lnbv[ks * 8 + j];
                unsigned short h = f2bf(x);
                unsigned short lo = f2bf(x - bf2f(h));
                ahi[ks][j] = (short)h;
                alo[ks][j] = (short)lo;
            }
        }
    }

    f32x4 acc[10];
    #pragma unroll
    for (int n = 0; n < 10; ++n) acc[n] = (f32x4){0.f, 0.f, 0.f, 0.f};

    #pragma unroll
    for (int n = 0; n < 10; ++n) {
        int brow = n * 16 + l15;
        const unsigned short* wh = Whi_g + brow * 64;
        const unsigned short* wl = Wlo_g + brow * 64;
        bf16x8 bh0 = *(const bf16x8*)(wh + lq * 8);
        bf16x8 bh1 = *(const bf16x8*)(wh + 32 + lq * 8);
        bf16x8 bl0 = *(const bf16x8*)(wl + lq * 8);
        bf16x8 bl1 = *(const bf16x8*)(wl + 32 + lq * 8);
        acc[n] = __builtin_amdgcn_mfma_f32_16x16x32_bf16(ahi[0], bh0, acc[n], 0, 0, 0);
        acc[n] = __builtin_amdgcn_mfma_f32_16x16x32_bf16(ahi[1], bh1, acc[n], 0, 0, 0);
        acc[n] = __builtin_amdgcn_mfma_f32_16x16x32_bf16(ahi[0], bl0, acc[n], 0, 0, 0);
        acc[n] = __builtin_amdgcn_mfma_f32_16x16x32_bf16(ahi[1], bl1, acc[n], 0, 0, 0);
        acc[n] = __builtin_amdgcn_mfma_f32_16x16x32_bf16(alo[0], bh0, acc[n], 0, 0, 0);
        acc[n] = __builtin_amdgcn_mfma_f32_16x16x32_bf16(alo[1], bh1, acc[n], 0, 0, 0);
    }

    #pragma unroll
    for (int n = 0; n < 8; ++n) {
        float bb = b_V[n * 16 + l15];
        #pragma unroll
        for (int q = 0; q < 4; ++q)
            s_v[(w * 16 + lq * 4 + q) * 130 + n * 16 + l15] = f2bf(acc[n][q] + bb);
    }
    #pragma unroll
    for (int n = 8; n < 10; ++n) {
        #pragma unroll
        for (int q = 0; q < 4; ++q)
            s_eg[(w * 16 + lq * 4 + q) * 33 + (n - 8) * 16 + l15] = acc[n][q];
    }
    __syncthreads();

    {
        const int rr = t & 63, g = t >> 6;
        const int r1 = i0 + (rr >> 2);
        const int r2 = j0 + (rr & 3);
        #pragma unroll
        for (int io = 0; io < 2; ++io) {
            #pragma unroll
            for (int hs = 0; hs < 2; ++hs) {
                const int h = g + hs * 4;
                uint4 u4;
                unsigned int wv[4];
                #pragma unroll
                for (int dp = 0; dp < 4; ++dp) {
                    int c0 = io * 64 + (2 * dp) * 8 + h;
                    int c1 = io * 64 + (2 * dp + 1) * 8 + h;
                    wv[dp] = (unsigned int)s_v[rr * 130 + c0]
                           | ((unsigned int)s_v[rr * 130 + c1] << 16);
                }
                u4.x = wv[0]; u4.y = wv[1]; u4.z = wv[2]; u4.w = wv[3];
                if (io == 0) {
                    *(uint4*)(VtIn + ((size_t)((b * 8 + h) * N_ + r2)) * 3072 + (size_t)r1 * 8) = u4;
                } else {
                    *(uint4*)(VtOut + ((size_t)((b * 8 + h) * N_ + r1)) * 3072 + (size_t)r2 * 8) = u4;
                }
            }
        }
    }
    {
        const int rr = t >> 2, cq = (t & 3) * 4;
        const int r1 = i0 + (rr >> 2);
        const int r2 = j0 + (rr & 3);
        const float maskv = mask[(size_t)(b * N_ + r1) * N_ + r2];
        float4 v0, v1;
        float tmp0[4], tmp1[4];
        #pragma unroll
        for (int u = 0; u < 4; ++u) {
            int c2 = cq + u;
            float x = s_eg[rr * 33 + c2] + b_EG[c2] + maskv;
            if (c2 >= 8) x = 1.f / (1.f + expf(-x));
            tmp0[u] = x;
            int c3 = 16 + cq + u;
            float y = s_eg[rr * 33 + c3] + b_EG[c3] + maskv;
            if ((cq + u) >= 8) y = 1.f / (1.f + expf(-y));
            tmp1[u] = y;
        }
        v0.x = tmp0[0]; v0.y = tmp0[1]; v0.z = tmp0[2]; v0.w = tmp0[3];
        v1.x = tmp1[0]; v1.y = tmp1[1]; v1.z = tmp1[2]; v1.w = tmp1[3];
        *(float4*)(EGin   + ((size_t)((b * N_ + r1) * N_ + r2)) * 16 + cq) = v0;
        *(float4*)(EGoutT + ((size_t)((b * N_ + r2) * N_ + r1)) * 16 + cq) = v1;
    }
}

// ---------------------------------------------------------------------------
// Kernel 2: gated softmax over k (verified).
// ---------------------------------------------------------------------------
__global__ __launch_bounds__(256) void k2_softmax(
    const float* __restrict__ EG, unsigned short* __restrict__ A)
{
    __shared__ float s[384 * 17];
    const int t = threadIdx.x;
    const int i = blockIdx.x % N_, b = blockIdx.x / N_;
    const float* base = EG + ((size_t)(b * N_ + i) * N_) * 16;
    for (int x = t; x < 6144; x += 256) {
        int k = x >> 4, c = x & 15;
        s[k * 17 + c] = base[x];
    }
    __syncthreads();
    const int h = t >> 5, l = t & 31;
    float ev[12];
    float mx = -1e30f;
    #pragma unroll
    for (int j = 0; j < 12; ++j) {
        ev[j] = s[(l + 32 * j) * 17 + h];
        mx = fmaxf(mx, ev[j]);
    }
    #pragma unroll
    for (int off = 16; off >= 1; off >>= 1) mx = fmaxf(mx, __shfl_xor(mx, off));
    float sum = 0.f;
    #pragma unroll
    for (int j = 0; j < 12; ++j) { ev[j] = expf(ev[j] - mx); sum += ev[j]; }
    #pragma unroll
    for (int off = 16; off >= 1; off >>= 1) sum += __shfl_xor(sum, off);
    const float inv = 1.f / sum;
    unsigned short* arow = A + ((size_t)((b * 8 + h) * N_ + i)) * N_;
    #pragma unroll
    for (int j = 0; j < 12; ++j) {
        int k = l + 32 * j;
        arow[k] = f2bf(ev[j] * inv * s[k * 17 + 8 + h]);
    }
}

// ---------------------------------------------------------------------------
// Kernel 2t: transpose V planes: [plane][k=384][jd=3072] -> [plane][jd][k].
// (round-2-verified verbatim)
// ---------------------------------------------------------------------------
__global__ __launch_bounds__(256) void k2t_transpose(
    const unsigned short* __restrict__ VtIn, const unsigned short* __restrict__ VtOut,
    unsigned short* __restrict__ VT2In, unsigned short* __restrict__ VT2Out)
{
    __shared__ unsigned short s[64 * 72];
    const int t = threadIdx.x;
    const int ktile = blockIdx.x % 6, jt = blockIdx.x / 6;
    const int q = blockIdx.y;
    const int arr = blockIdx.z;
    const unsigned short* src = (arr ? VtOut : VtIn) + (size_t)q * 1179648;
    unsigned short* dst = (arr ? VT2Out : VT2In) + (size_t)q * 1179648;
    const int k0 = ktile * 64, jd0 = jt * 64;

    {
        const int kk = t >> 2, cgq = t & 3;
        const unsigned short* g = src + (size_t)(k0 + kk) * 3072 + jd0 + cgq * 16;
        uint4 u0 = *(const uint4*)g;
        uint4 u1 = *(const uint4*)(g + 8);
        int cp = (cgq ^ (kk & 3)) * 16;
        *(uint4*)&s[kk * 72 + cp] = u0;
        *(uint4*)&s[kk * 72 + cp + 8] = u1;
    }
    __syncthreads();
    {
        const int jj = t & 63, kq = (t >> 6) * 16;
        unsigned int wv[8];
        #pragma unroll
        for (int p = 0; p < 8; ++p) {
            int u0 = 2 * p, u1 = 2 * p + 1;
            unsigned short a = s[(kq + u0) * 72 + (((jj >> 4) ^ (u0 & 3)) << 4) + (jj & 15)];
            unsigned short c = s[(kq + u1) * 72 + (((jj >> 4) ^ (u1 & 3)) << 4) + (jj & 15)];
            wv[p] = (unsigned int)a | ((unsigned int)c << 16);
        }
        unsigned short* o = dst + (size_t)(jd0 + jj) * 384 + k0 + kq;
        uint4 x0; x0.x = wv[0]; x0.y = wv[1]; x0.z = wv[2]; x0.w = wv[3];
        uint4 x1; x1.x = wv[4]; x1.y = wv[5]; x1.z = wv[6]; x1.w = wv[7];
        *(uint4*)o = x0;
        *(uint4*)(o + 8) = x1;
    }
}

// ---------------------------------------------------------------------------
// Kernel 3: batched MFMA GEMM, BK=64, global_load_lds staging (verified).
// CHANGE: C written in [b][i][zp][n] layout (zp = io*8+h) for sequential k4.
// ---------------------------------------------------------------------------
__global__ __launch_bounds__(256) void k3_mfma(
    const unsigned short* __restrict__ Aall,   // [32][384][384]
    const unsigned short* __restrict__ Vall,   // [32][3072][384]
    unsigned short* __restrict__ C)            // [2][384][16][3072]
{
    __shared__ __align__(16) short sAB[16384];   // sA [128][64] + sB [128][64]
    short* sA = sAB;
    short* sB = sAB + 8192;

    const int t = threadIdx.x;
    const int n0 = blockIdx.x * 128;
    const int i0 = blockIdx.y * 128;
    const int z  = blockIdx.z;             // z = io*16 + b*8 + h

    const unsigned short* Ap = Aall + (size_t)z * 147456;
    const unsigned short* Bp = Vall + (size_t)z * 1179648;

    const int l = t & 63;
    const int w = t >> 6;
    const int wr = w >> 1, wc = w & 1;
    const int l15 = l & 15, lq = l >> 4;
    const int srow = l >> 3, schunk = (l & 7) ^ (l >> 3);

    f32x4 acc[4][4];
    #pragma unroll
    for (int mi = 0; mi < 4; ++mi)
        #pragma unroll
        for (int ni = 0; ni < 4; ++ni) acc[mi][ni] = (f32x4){0.f, 0.f, 0.f, 0.f};

    #pragma unroll 1
    for (int kt = 0; kt < 6; ++kt) {
        const int k0 = kt * 64;
        #pragma unroll
        for (int i = 0; i < 4; ++i) {
            int rbase = w * 32 + i * 8;
            gload16(Ap + (size_t)(i0 + rbase + srow) * 384 + k0 + schunk * 8,
                    (char*)sA + rbase * 128);
            gload16(Bp + (size_t)(n0 + rbase + srow) * 384 + k0 + schunk * 8,
                    (char*)sB + rbase * 128);
        }
        __syncthreads();

        bf16x8 av[4][2], bv[4][2];
        #pragma unroll
        for (int mi = 0; mi < 4; ++mi) {
            int row = wr * 64 + mi * 16 + l15;
            #pragma unroll
            for (int ks = 0; ks < 2; ++ks) {
                int kc = ks * 4 + lq;
                av[mi][ks] = *(const bf16x8*)((const char*)sA + row * 128 + ((kc ^ (row & 7)) << 4));
            }
        }
        #pragma unroll
        for (int ni = 0; ni < 4; ++ni) {
            int row = wc * 64 + ni * 16 + l15;
            #pragma unroll
            for (int ks = 0; ks < 2; ++ks) {
                int kc = ks * 4 + lq;
                bv[ni][ks] = *(const bf16x8*)((const char*)sB + row * 128 + ((kc ^ (row & 7)) << 4));
            }
        }
        #pragma unroll
        for (int mi = 0; mi < 4; ++mi)
            #pragma unroll
            for (int ni = 0; ni < 4; ++ni) {
                acc[mi][ni] = __builtin_amdgcn_mfma_f32_16x16x32_bf16(av[mi][0], bv[ni][0], acc[mi][ni], 0, 0, 0);
                acc[mi][ni] = __builtin_amdgcn_mfma_f32_16x16x32_bf16(av[mi][1], bv[ni][1], acc[mi][ni], 0, 0, 0);
            }
        __syncthreads();
    }

    // C layout: [b][i][zp][n], zp = io*8 + h
    const int io_ = z >> 4, b_ = (z >> 3) & 1, h_ = z & 7;
    const int zp = io_ * 8 + h_;
    #pragma unroll
    for (int mi = 0; mi < 4; ++mi) {
        #pragma unroll
        for (int qq = 0; qq < 4; ++qq) {
            int row = i0 + wr * 64 + mi * 16 + lq * 4 + qq;
            unsigned short* crow = C + ((size_t)((b_ * N_ + row) * 16 + zp)) * 3072 + n0 + wc * 64 + l15;
            #pragma unroll
            for (int ni = 0; ni < 4; ++ni) crow[ni * 16] = f2bf(acc[mi][ni][qq]);
        }
    }
}

// ---------------------------------------------------------------------------
// Kernel 4: out = b_O + C(gathered) @ W_O (fp32). C now [b][i][p][n] ->
// fully sequential 2KB reads. Summation order unchanged.
// ---------------------------------------------------------------------------
__global__ __launch_bounds__(256) void k4_proj(
    const unsigned short* __restrict__ C, const float* __restrict__ W_O,
    const float* __restrict__ b_O, float* __restrict__ out)
{
    __shared__ float s_w[8192];             // [128][64]
    __shared__ unsigned short s_c[20480];   // [16 p][128 j][10]
    const int t = threadIdx.x;
    const int jt = blockIdx.x;
    const int i  = blockIdx.y;
    const int b  = blockIdx.z;

    for (int x = t; x < 8192; x += 256) s_w[x] = W_O[x];
    {
        unsigned int* s_c32 = (unsigned int*)s_c;
        const unsigned short* cbase = C + ((size_t)(b * N_ + i) * 16) * 3072 + jt * 1024;
        #pragma unroll
        for (int rep = 0; rep < 8; ++rep) {
            int flat = rep * 256 + t;
            int p = flat >> 7, jj = flat & 127;
            uint4 v = *(const uint4*)(cbase + (size_t)p * 3072 + jj * 8);
            int base = p * 640 + jj * 5;
            s_c32[base] = v.x; s_c32[base + 1] = v.y; s_c32[base + 2] = v.z; s_c32[base + 3] = v.w;
        }
    }
    __syncthreads();

    const int jg = t & 63, cg = t >> 6;
    const int chb = cg * 16;
    float acc0[16], acc1[16];
    #pragma unroll
    for (int u = 0; u < 16; ++u) { float bb = b_O[chb + u]; acc0[u] = bb; acc1[u] = bb; }

    #pragma unroll 4
    for (int c = 0; c < 128; ++c) {
        const int p = c & 15, d = c >> 4;
        const int sbase = p * 1280 + (jg * 2) * 10 + d;
        float v0 = bf2f((unsigned int)s_c[sbase]);
        float v1 = bf2f((unsigned int)s_c[sbase + 10]);
        const float* wrp = s_w + c * 64 + chb;
        #pragma unroll
        for (int u4 = 0; u4 < 4; ++u4) {
            float4 wv = *(const float4*)(wrp + u4 * 4);
            acc0[u4*4+0] += v0 * wv.x; acc0[u4*4+1] += v0 * wv.y;
            acc0[u4*4+2] += v0 * wv.z; acc0[u4*4+3] += v0 * wv.w;
            acc1[u4*4+0] += v1 * wv.x; acc1[u4*4+1] += v1 * wv.y;
            acc1[u4*4+2] += v1 * wv.z; acc1[u4*4+3] += v1 * wv.w;
        }
    }
    float* o0 = out + ((size_t)(b * N_ + i) * N_ + jt * 128 + jg * 2) * 64 + chb;
    #pragma unroll
    for (int u4 = 0; u4 < 4; ++u4) {
        float4 a; a.x = acc0[u4*4]; a.y = acc0[u4*4+1]; a.z = acc0[u4*4+2]; a.w = acc0[u4*4+3];
        *(float4*)(o0 + u4 * 4) = a;
        float4 c4; c4.x = acc1[u4*4]; c4.y = acc1[u4*4+1]; c4.z = acc1[u4*4+2]; c4.w = acc1[u4*4+3];
        *(float4*)(o0 + 64 + u4 * 4) = c4;
    }
}

// ---------------------------------------------------------------------------
extern "C" void kernel_launch(void* const* d_in, const int* in_sizes, int n_in,
                              void* d_out, int out_size, void* d_ws, size_t ws_size,
                              hipStream_t stream)
{
    const float* e    = (const float*)d_in[0];
    const float* mask = (const float*)d_in[1];
    const float* ln_w = (const float*)d_in[2];
    const float* ln_b = (const float*)d_in[3];
    const float* W_V  = (const float*)d_in[4];
    const float* b_V  = (const float*)d_in[5];
    const float* W_EG = (const float*)d_in[6];
    const float* b_EG = (const float*)d_in[7];
    const float* W_O  = (const float*)d_in[8];
    const float* b_O  = (const float*)d_in[9];
    float* out = (float*)d_out;

    char* ws = (char*)d_ws;
    unsigned short* VtIn   = (unsigned short*)(ws);               // 37,748,736
    unsigned short* VtOut  = (unsigned short*)(ws + 37748736);    // 37,748,736
    unsigned short* A_in   = (unsigned short*)(ws + 75497472);    //  4,718,592
    unsigned short* A_outT = (unsigned short*)(ws + 80216064);    //  4,718,592
    float* EGin   = (float*)(ws + 84934656);                      // 18,874,368 (dead after k2)
    float* EGoutT = (float*)(ws + 103809024);                     // 18,874,368 (dead after k2)
    unsigned short* VT2In  = (unsigned short*)(ws + 84934656);    // 37,748,736 (overlays EG after k2)
    unsigned short* VT2Out = (unsigned short*)(ws + 122683392);   // 37,748,736
    unsigned short* Cws    = (unsigned short*)(ws);               // 75,497,472 (overlays Vt after k2t)
    unsigned short* Whi = A_in;                                   // 20,480 B (k0->k1 transient)
    unsigned short* Wlo = A_in + 10240;                           // 20,480 B

    hipLaunchKernelGGL(k0_prep, dim3(40), dim3(256), 0, stream, W_V, W_EG, Whi, Wlo);
    hipLaunchKernelGGL(k1_ln_proj, dim3(96, 24, 2), dim3(256), 0, stream,
                       e, mask, ln_w, ln_b, Whi, Wlo, b_V, b_EG, VtIn, VtOut, EGin, EGoutT);
    hipLaunchKernelGGL(k2_softmax, dim3(768), dim3(256), 0, stream, EGin, A_in);
    hipLaunchKernelGGL(k2_softmax, dim3(768), dim3(256), 0, stream, EGoutT, A_outT);
    hipLaunchKernelGGL(k2t_transpose, dim3(288, 16, 2), dim3(256), 0, stream,
                       VtIn, VtOut, VT2In, VT2Out);
    hipLaunchKernelGGL(k3_mfma, dim3(24, 3, 32), dim3(256), 0, stream,
                       A_in, VT2In, Cws);
    hipLaunchKernelGGL(k4_proj, dim3(3, 384, 2), dim3(256), 0, stream,
                       Cws, W_O, b_O, out);
}

// Round 15
// 292.179 us; speedup vs baseline: 1.2885x; 1.0635x over previous
//
#include <hip/hip_runtime.h>

#define N_ 384
#define LNEPS 1e-5f

typedef __attribute__((ext_vector_type(8))) short bf16x8;
typedef __attribute__((ext_vector_type(4))) float f32x4;

__device__ __forceinline__ float bf2f(unsigned int u) {
    union { unsigned int i; float f; } v; v.i = u << 16; return v.f;
}
__device__ __forceinline__ unsigned short f2bf(float f) {
    union { float f; unsigned int i; } v; v.f = f;
    return (unsigned short)((v.i + 0x7FFFu + ((v.i >> 16) & 1u)) >> 16);
}
__device__ __forceinline__ void gload16(const void* g, void* l) {
    __builtin_amdgcn_global_load_lds(
        (const __attribute__((address_space(1))) void*)g,
        (__attribute__((address_space(3))) void*)l, 16, 0, 0);
}

// ---------------------------------------------------------------------------
// Kernel 0: convert projection weights to bf16 hi/lo pairs, [col][k] layout.
// ---------------------------------------------------------------------------
__global__ __launch_bounds__(256) void k0_prep(
    const float* __restrict__ W_V, const float* __restrict__ W_EG,
    unsigned short* __restrict__ Whi, unsigned short* __restrict__ Wlo)
{
    int x = blockIdx.x * 256 + threadIdx.x;
    if (x >= 10240) return;
    int col = x >> 6, k = x & 63;
    float wv = (col < 128) ? W_V[k * 128 + col] : W_EG[k * 32 + (col - 128)];
    unsigned short hi = f2bf(wv);
    Whi[x] = hi;
    Wlo[x] = f2bf(wv - bf2f(hi));
}

// ---------------------------------------------------------------------------
// Kernel 1: LN + V/EG projections (round-11-verified VERBATIM).
// ---------------------------------------------------------------------------
__global__ __launch_bounds__(256) void k1_ln_proj(
    const float* __restrict__ e, const float* __restrict__ mask,
    const float* __restrict__ ln_w, const float* __restrict__ ln_b,
    const unsigned short* __restrict__ Whi_g, const unsigned short* __restrict__ Wlo_g,
    const float* __restrict__ b_V, const float* __restrict__ b_EG,
    unsigned short* __restrict__ VtIn, unsigned short* __restrict__ VtOut,
    float* __restrict__ EGin, float* __restrict__ EGoutT)
{
    __shared__ __align__(16) char smem[25088];
    unsigned short* s_v = (unsigned short*)smem;
    float* s_eg = (float*)(smem + 16640);

    const int t = threadIdx.x;
    const int j0 = blockIdx.x * 4;
    const int i0 = blockIdx.y * 16;
    const int b  = blockIdx.z;

    const int l = t & 63, w = t >> 6;
    const int l15 = l & 15, lq = l >> 4;

    const int r = w * 16 + l15;
    const int r1f = i0 + (r >> 2), r2f = j0 + (r & 3);
    const float* erow = e + ((size_t)((b * N_ + r1f) * N_ + r2f)) * 64;
    float ev[16];
    {
        float4 e0 = *(const float4*)(erow + lq * 8);
        float4 e1 = *(const float4*)(erow + lq * 8 + 4);
        float4 e2 = *(const float4*)(erow + 32 + lq * 8);
        float4 e3 = *(const float4*)(erow + 32 + lq * 8 + 4);
        ev[0]=e0.x; ev[1]=e0.y; ev[2]=e0.z;  ev[3]=e0.w;
        ev[4]=e1.x; ev[5]=e1.y; ev[6]=e1.z;  ev[7]=e1.w;
        ev[8]=e2.x; ev[9]=e2.y; ev[10]=e2.z; ev[11]=e2.w;
        ev[12]=e3.x; ev[13]=e3.y; ev[14]=e3.z; ev[15]=e3.w;
    }
    float s = 0.f, sq = 0.f;
    #pragma unroll
    for (int j = 0; j < 16; ++j) { s += ev[j]; sq += ev[j] * ev[j]; }
    s  += __shfl_xor(s, 16);  s  += __shfl_xor(s, 32);
    sq += __shfl_xor(sq, 16); sq += __shfl_xor(sq, 32);
    const float mean = s * (1.f / 64.f);
    const float rstd = rsqrtf(sq * (1.f / 64.f) - mean * mean + LNEPS);

    bf16x8 ahi[2], alo[2];
    {
        float lnwv[16], lnbv[16];
        float4 w0 = *(const float4*)(ln_w + lq * 8);
        float4 w1 = *(const float4*)(ln_w + lq * 8 + 4);
        float4 w2 = *(const float4*)(ln_w + 32 + lq * 8);
        float4 w3 = *(const float4*)(ln_w + 32 + lq * 8 + 4);
        lnwv[0]=w0.x; lnwv[1]=w0.y; lnwv[2]=w0.z;  lnwv[3]=w0.w;
        lnwv[4]=w1.x; lnwv[5]=w1.y; lnwv[6]=w1.z;  lnwv[7]=w1.w;
        lnwv[8]=w2.x; lnwv[9]=w2.y; lnwv[10]=w2.z; lnwv[11]=w2.w;
        lnwv[12]=w3.x; lnwv[13]=w3.y; lnwv[14]=w3.z; lnwv[15]=w3.w;
        float4 b0 = *(const float4*)(ln_b + lq * 8);
        float4 b1 = *(const float4*)(ln_b + lq * 8 + 4);
        float4 b2 = *(const float4*)(ln_b + 32 + lq * 8);
        float4 b3 = *(const float4*)(ln_b + 32 + lq * 8 + 4);
        lnbv[0]=b0.x; lnbv[1]=b0.y; lnbv[2]=b0.z;  lnbv[3]=b0.w;
        lnbv[4]=b1.x; lnbv[5]=b1.y; lnbv[6]=b1.z;  lnbv[7]=b1.w;
        lnbv[8]=b2.x; lnbv[9]=b2.y; lnbv[10]=b2.z; lnbv[11]=b2.w;
        lnbv[12]=b3.x; lnbv[13]=b3.y; lnbv[14]=b3.z; lnbv[15]=b3.w;
        #pragma unroll
        for (int ks = 0; ks < 2; ++ks) {
            #pragma unroll
            for (int j = 0; j < 8; ++j) {
                float x = (ev[ks * 8 + j] - mean) * rstd * lnwv[ks * 8 + j] + lnbv[ks * 8 + j];
                unsigned short h = f2bf(x);
                unsigned short lo = f2bf(x - bf2f(h));
                ahi[ks][j] = (short)h;
                alo[ks][j] = (short)lo;
            }
        }
    }

    f32x4 acc[10];
    #pragma unroll
    for (int n = 0; n < 10; ++n) acc[n] = (f32x4){0.f, 0.f, 0.f, 0.f};

    #pragma unroll
    for (int n = 0; n < 10; ++n) {
        int brow = n * 16 + l15;
        const unsigned short* wh = Whi_g + brow * 64;
        const unsigned short* wl = Wlo_g + brow * 64;
        bf16x8 bh0 = *(const bf16x8*)(wh + lq * 8);
        bf16x8 bh1 = *(const bf16x8*)(wh + 32 + lq * 8);
        bf16x8 bl0 = *(const bf16x8*)(wl + lq * 8);
        bf16x8 bl1 = *(const bf16x8*)(wl + 32 + lq * 8);
        acc[n] = __builtin_amdgcn_mfma_f32_16x16x32_bf16(ahi[0], bh0, acc[n], 0, 0, 0);
        acc[n] = __builtin_amdgcn_mfma_f32_16x16x32_bf16(ahi[1], bh1, acc[n], 0, 0, 0);
        acc[n] = __builtin_amdgcn_mfma_f32_16x16x32_bf16(ahi[0], bl0, acc[n], 0, 0, 0);
        acc[n] = __builtin_amdgcn_mfma_f32_16x16x32_bf16(ahi[1], bl1, acc[n], 0, 0, 0);
        acc[n] = __builtin_amdgcn_mfma_f32_16x16x32_bf16(alo[0], bh0, acc[n], 0, 0, 0);
        acc[n] = __builtin_amdgcn_mfma_f32_16x16x32_bf16(alo[1], bh1, acc[n], 0, 0, 0);
    }

    #pragma unroll
    for (int n = 0; n < 8; ++n) {
        float bb = b_V[n * 16 + l15];
        #pragma unroll
        for (int q = 0; q < 4; ++q)
            s_v[(w * 16 + lq * 4 + q) * 130 + n * 16 + l15] = f2bf(acc[n][q] + bb);
    }
    #pragma unroll
    for (int n = 8; n < 10; ++n) {
        #pragma unroll
        for (int q = 0; q < 4; ++q)
            s_eg[(w * 16 + lq * 4 + q) * 33 + (n - 8) * 16 + l15] = acc[n][q];
    }
    __syncthreads();

    {
        const int rr = t & 63, g = t >> 6;
        const int r1 = i0 + (rr >> 2);
        const int r2 = j0 + (rr & 3);
        #pragma unroll
        for (int io = 0; io < 2; ++io) {
            #pragma unroll
            for (int hs = 0; hs < 2; ++hs) {
                const int h = g + hs * 4;
                uint4 u4;
                unsigned int wv[4];
                #pragma unroll
                for (int dp = 0; dp < 4; ++dp) {
                    int c0 = io * 64 + (2 * dp) * 8 + h;
                    int c1 = io * 64 + (2 * dp + 1) * 8 + h;
                    wv[dp] = (unsigned int)s_v[rr * 130 + c0]
                           | ((unsigned int)s_v[rr * 130 + c1] << 16);
                }
                u4.x = wv[0]; u4.y = wv[1]; u4.z = wv[2]; u4.w = wv[3];
                if (io == 0) {
                    *(uint4*)(VtIn + ((size_t)((b * 8 + h) * N_ + r2)) * 3072 + (size_t)r1 * 8) = u4;
                } else {
                    *(uint4*)(VtOut + ((size_t)((b * 8 + h) * N_ + r1)) * 3072 + (size_t)r2 * 8) = u4;
                }
            }
        }
    }
    {
        const int rr = t >> 2, cq = (t & 3) * 4;
        const int r1 = i0 + (rr >> 2);
        const int r2 = j0 + (rr & 3);
        const float maskv = mask[(size_t)(b * N_ + r1) * N_ + r2];
        float4 v0, v1;
        float tmp0[4], tmp1[4];
        #pragma unroll
        for (int u = 0; u < 4; ++u) {
            int c2 = cq + u;
            float x = s_eg[rr * 33 + c2] + b_EG[c2] + maskv;
            if (c2 >= 8) x = 1.f / (1.f + expf(-x));
            tmp0[u] = x;
            int c3 = 16 + cq + u;
            float y = s_eg[rr * 33 + c3] + b_EG[c3] + maskv;
            if ((cq + u) >= 8) y = 1.f / (1.f + expf(-y));
            tmp1[u] = y;
        }
        v0.x = tmp0[0]; v0.y = tmp0[1]; v0.z = tmp0[2]; v0.w = tmp0[3];
        v1.x = tmp1[0]; v1.y = tmp1[1]; v1.z = tmp1[2]; v1.w = tmp1[3];
        *(float4*)(EGin   + ((size_t)((b * N_ + r1) * N_ + r2)) * 16 + cq) = v0;
        *(float4*)(EGoutT + ((size_t)((b * N_ + r2) * N_ + r1)) * 16 + cq) = v1;
    }
}

// ---------------------------------------------------------------------------
// Merged kernel: softmax (x2) + V transpose, role by flat blockIdx.
// Inner bodies verified verbatim; FIX: b2 computed by subtraction (768 is not
// a power of two, so `bid & 767` was wrong).
// ---------------------------------------------------------------------------
__global__ __launch_bounds__(256) void k2m(
    const float* __restrict__ EGin, const float* __restrict__ EGoutT,
    unsigned short* __restrict__ A_in, unsigned short* __restrict__ A_outT,
    const unsigned short* __restrict__ VtIn, const unsigned short* __restrict__ VtOut,
    unsigned short* __restrict__ VT2In, unsigned short* __restrict__ VT2Out)
{
    __shared__ __align__(16) char sm[26112];
    const int t = threadIdx.x;
    const int bid = blockIdx.x;

    if (bid < 1536) {
        // --- softmax role (verified verbatim) ---
        float* s = (float*)sm;
        const float* EG = (bid < 768) ? EGin : EGoutT;
        unsigned short* A = (bid < 768) ? A_in : A_outT;
        const int b2 = (bid < 768) ? bid : bid - 768;   // FIX (was bid & 767)
        const int i = b2 % N_, b = b2 / N_;
        const float* base = EG + ((size_t)(b * N_ + i) * N_) * 16;
        for (int x = t; x < 6144; x += 256) {
            int k = x >> 4, c = x & 15;
            s[k * 17 + c] = base[x];
        }
        __syncthreads();
        const int h = t >> 5, l = t & 31;
        float ev[12];
        float mx = -1e30f;
        #pragma unroll
        for (int j = 0; j < 12; ++j) {
            ev[j] = s[(l + 32 * j) * 17 + h];
            mx = fmaxf(mx, ev[j]);
        }
        #pragma unroll
        for (int off = 16; off >= 1; off >>= 1) mx = fmaxf(mx, __shfl_xor(mx, off));
        float sum = 0.f;
        #pragma unroll
        for (int j = 0; j < 12; ++j) { ev[j] = expf(ev[j] - mx); sum += ev[j]; }
        #pragma unroll
        for (int off = 16; off >= 1; off >>= 1) sum += __shfl_xor(sum, off);
        const float inv = 1.f / sum;
        unsigned short* arow = A + ((size_t)((b * 8 + h) * N_ + i)) * N_;
        #pragma unroll
        for (int j = 0; j < 12; ++j) {
            int k = l + 32 * j;
            arow[k] = f2bf(ev[j] * inv * s[k * 17 + 8 + h]);
        }
    } else {
        // --- transpose role (verified verbatim) ---
        unsigned short* s = (unsigned short*)sm;
        const int bid2 = bid - 1536;
        const int xx = bid2 % 288;
        const int rest = bid2 / 288;
        const int q = rest & 15, arr = rest >> 4;
        const int ktile = xx % 6, jt = xx / 6;
        const unsigned short* src = (arr ? VtOut : VtIn) + (size_t)q * 1179648;
        unsigned short* dst = (arr ? VT2Out : VT2In) + (size_t)q * 1179648;
        const int k0 = ktile * 64, jd0 = jt * 64;

        {
            const int kk = t >> 2, cgq = t & 3;
            const unsigned short* g = src + (size_t)(k0 + kk) * 3072 + jd0 + cgq * 16;
            uint4 u0 = *(const uint4*)g;
            uint4 u1 = *(const uint4*)(g + 8);
            int cp = (cgq ^ (kk & 3)) * 16;
            *(uint4*)&s[kk * 72 + cp] = u0;
            *(uint4*)&s[kk * 72 + cp + 8] = u1;
        }
        __syncthreads();
        {
            const int jj = t & 63, kq = (t >> 6) * 16;
            unsigned int wv[8];
            #pragma unroll
            for (int p = 0; p < 8; ++p) {
                int u0 = 2 * p, u1 = 2 * p + 1;
                unsigned short a = s[(kq + u0) * 72 + (((jj >> 4) ^ (u0 & 3)) << 4) + (jj & 15)];
                unsigned short c = s[(kq + u1) * 72 + (((jj >> 4) ^ (u1 & 3)) << 4) + (jj & 15)];
                wv[p] = (unsigned int)a | ((unsigned int)c << 16);
            }
            unsigned short* o = dst + (size_t)(jd0 + jj) * 384 + k0 + kq;
            uint4 x0; x0.x = wv[0]; x0.y = wv[1]; x0.z = wv[2]; x0.w = wv[3];
            uint4 x1; x1.x = wv[4]; x1.y = wv[5]; x1.z = wv[6]; x1.w = wv[7];
            *(uint4*)o = x0;
            *(uint4*)(o + 8) = x1;
        }
    }
}

// Serial-fallback copies (verbatim round-11 kernels) for small workspaces.
__global__ __launch_bounds__(256) void k2_softmax(
    const float* __restrict__ EG, unsigned short* __restrict__ A)
{
    __shared__ float s[384 * 17];
    const int t = threadIdx.x;
    const int i = blockIdx.x % N_, b = blockIdx.x / N_;
    const float* base = EG + ((size_t)(b * N_ + i) * N_) * 16;
    for (int x = t; x < 6144; x += 256) {
        int k = x >> 4, c = x & 15;
        s[k * 17 + c] = base[x];
    }
    __syncthreads();
    const int h = t >> 5, l = t & 31;
    float ev[12];
    float mx = -1e30f;
    #pragma unroll
    for (int j = 0; j < 12; ++j) {
        ev[j] = s[(l + 32 * j) * 17 + h];
        mx = fmaxf(mx, ev[j]);
    }
    #pragma unroll
    for (int off = 16; off >= 1; off >>= 1) mx = fmaxf(mx, __shfl_xor(mx, off));
    float sum = 0.f;
    #pragma unroll
    for (int j = 0; j < 12; ++j) { ev[j] = expf(ev[j] - mx); sum += ev[j]; }
    #pragma unroll
    for (int off = 16; off >= 1; off >>= 1) sum += __shfl_xor(sum, off);
    const float inv = 1.f / sum;
    unsigned short* arow = A + ((size_t)((b * 8 + h) * N_ + i)) * N_;
    #pragma unroll
    for (int j = 0; j < 12; ++j) {
        int k = l + 32 * j;
        arow[k] = f2bf(ev[j] * inv * s[k * 17 + 8 + h]);
    }
}

__global__ __launch_bounds__(256) void k2t_transpose(
    const unsigned short* __restrict__ VtIn, const unsigned short* __restrict__ VtOut,
    unsigned short* __restrict__ VT2In, unsigned short* __restrict__ VT2Out)
{
    __shared__ unsigned short s[64 * 72];
    const int t = threadIdx.x;
    const int ktile = blockIdx.x % 6, jt = blockIdx.x / 6;
    const int q = blockIdx.y;
    const int arr = blockIdx.z;
    const unsigned short* src = (arr ? VtOut : VtIn) + (size_t)q * 1179648;
    unsigned short* dst = (arr ? VT2Out : VT2In) + (size_t)q * 1179648;
    const int k0 = ktile * 64, jd0 = jt * 64;

    {
        const int kk = t >> 2, cgq = t & 3;
        const unsigned short* g = src + (size_t)(k0 + kk) * 3072 + jd0 + cgq * 16;
        uint4 u0 = *(const uint4*)g;
        uint4 u1 = *(const uint4*)(g + 8);
        int cp = (cgq ^ (kk & 3)) * 16;
        *(uint4*)&s[kk * 72 + cp] = u0;
        *(uint4*)&s[kk * 72 + cp + 8] = u1;
    }
    __syncthreads();
    {
        const int jj = t & 63, kq = (t >> 6) * 16;
        unsigned int wv[8];
        #pragma unroll
        for (int p = 0; p < 8; ++p) {
            int u0 = 2 * p, u1 = 2 * p + 1;
            unsigned short a = s[(kq + u0) * 72 + (((jj >> 4) ^ (u0 & 3)) << 4) + (jj & 15)];
            unsigned short c = s[(kq + u1) * 72 + (((jj >> 4) ^ (u1 & 3)) << 4) + (jj & 15)];
            wv[p] = (unsigned int)a | ((unsigned int)c << 16);
        }
        unsigned short* o = dst + (size_t)(jd0 + jj) * 384 + k0 + kq;
        uint4 x0; x0.x = wv[0]; x0.y = wv[1]; x0.z = wv[2]; x0.w = wv[3];
        uint4 x1; x1.x = wv[4]; x1.y = wv[5]; x1.z = wv[6]; x1.w = wv[7];
        *(uint4*)o = x0;
        *(uint4*)(o + 8) = x1;
    }
}

// ---------------------------------------------------------------------------
// Kernel 3: batched MFMA GEMM (round-11-verified verbatim, plane-major C).
// ---------------------------------------------------------------------------
__global__ __launch_bounds__(256) void k3_mfma(
    const unsigned short* __restrict__ Aall,   // [32][384][384]
    const unsigned short* __restrict__ Vall,   // [32][3072][384]
    unsigned short* __restrict__ C)            // [32][384][3072]
{
    __shared__ __align__(16) short sAB[16384];
    short* sA = sAB;
    short* sB = sAB + 8192;

    const int t = threadIdx.x;
    const int n0 = blockIdx.x * 128;
    const int i0 = blockIdx.y * 128;
    const int z  = blockIdx.z;

    const unsigned short* Ap = Aall + (size_t)z * 147456;
    const unsigned short* Bp = Vall + (size_t)z * 1179648;

    const int l = t & 63;
    const int w = t >> 6;
    const int wr = w >> 1, wc = w & 1;
    const int l15 = l & 15, lq = l >> 4;
    const int srow = l >> 3, schunk = (l & 7) ^ (l >> 3);

    f32x4 acc[4][4];
    #pragma unroll
    for (int mi = 0; mi < 4; ++mi)
        #pragma unroll
        for (int ni = 0; ni < 4; ++ni) acc[mi][ni] = (f32x4){0.f, 0.f, 0.f, 0.f};

    #pragma unroll 1
    for (int kt = 0; kt < 6; ++kt) {
        const int k0 = kt * 64;
        #pragma unroll
        for (int i = 0; i < 4; ++i) {
            int rbase = w * 32 + i * 8;
            gload16(Ap + (size_t)(i0 + rbase + srow) * 384 + k0 + schunk * 8,
                    (char*)sA + rbase * 128);
            gload16(Bp + (size_t)(n0 + rbase + srow) * 384 + k0 + schunk * 8,
                    (char*)sB + rbase * 128);
        }
        __syncthreads();

        bf16x8 av[4][2], bv[4][2];
        #pragma unroll
        for (int mi = 0; mi < 4; ++mi) {
            int row = wr * 64 + mi * 16 + l15;
            #pragma unroll
            for (int ks = 0; ks < 2; ++ks) {
                int kc = ks * 4 + lq;
                av[mi][ks] = *(const bf16x8*)((const char*)sA + row * 128 + ((kc ^ (row & 7)) << 4));
            }
        }
        #pragma unroll
        for (int ni = 0; ni < 4; ++ni) {
            int row = wc * 64 + ni * 16 + l15;
            #pragma unroll
            for (int ks = 0; ks < 2; ++ks) {
                int kc = ks * 4 + lq;
                bv[ni][ks] = *(const bf16x8*)((const char*)sB + row * 128 + ((kc ^ (row & 7)) << 4));
            }
        }
        #pragma unroll
        for (int mi = 0; mi < 4; ++mi)
            #pragma unroll
            for (int ni = 0; ni < 4; ++ni) {
                acc[mi][ni] = __builtin_amdgcn_mfma_f32_16x16x32_bf16(av[mi][0], bv[ni][0], acc[mi][ni], 0, 0, 0);
                acc[mi][ni] = __builtin_amdgcn_mfma_f32_16x16x32_bf16(av[mi][1], bv[ni][1], acc[mi][ni], 0, 0, 0);
            }
        __syncthreads();
    }

    unsigned short* Cp = C + (size_t)z * 1179648;
    #pragma unroll
    for (int mi = 0; mi < 4; ++mi) {
        #pragma unroll
        for (int qq = 0; qq < 4; ++qq) {
            int row = i0 + wr * 64 + mi * 16 + lq * 4 + qq;
            unsigned short* crow = Cp + (size_t)row * 3072 + n0 + wc * 64 + l15;
            #pragma unroll
            for (int ni = 0; ni < 4; ++ni) crow[ni * 16] = f2bf(acc[mi][ni][qq]);
        }
    }
}

// ---------------------------------------------------------------------------
// Kernel 4: out = b_O + C(gathered) @ W_O (round-11-verified verbatim).
// ---------------------------------------------------------------------------
__global__ __launch_bounds__(256) void k4_proj(
    const unsigned short* __restrict__ C, const float* __restrict__ W_O,
    const float* __restrict__ b_O, float* __restrict__ out)
{
    __shared__ float s_w[8192];
    __shared__ unsigned short s_c[20480];
    const int t = threadIdx.x;
    const int jt = blockIdx.x;
    const int i  = blockIdx.y;
    const int b  = blockIdx.z;

    for (int x = t; x < 8192; x += 256) s_w[x] = W_O[x];
    {
        unsigned int* s_c32 = (unsigned int*)s_c;
        #pragma unroll
        for (int rep = 0; rep < 8; ++rep) {
            int flat = rep * 256 + t;
            int p = flat >> 7, jj = flat & 127;
            int plane = b * 8 + (p & 7) + (p >> 3) * 16;
            uint4 v = *(const uint4*)(C + (size_t)plane * 1179648 + (size_t)i * 3072 + jt * 1024 + jj * 8);
            int base = p * 640 + jj * 5;
            s_c32[base] = v.x; s_c32[base + 1] = v.y; s_c32[base + 2] = v.z; s_c32[base + 3] = v.w;
        }
    }
    __syncthreads();

    const int jg = t & 63, cg = t >> 6;
    const int chb = cg * 16;
    float acc0[16], acc1[16];
    #pragma unroll
    for (int u = 0; u < 16; ++u) { float bb = b_O[chb + u]; acc0[u] = bb; acc1[u] = bb; }

    #pragma unroll 4
    for (int c = 0; c < 128; ++c) {
        const int p = c & 15, d = c >> 4;
        const int sbase = p * 1280 + (jg * 2) * 10 + d;
        float v0 = bf2f((unsigned int)s_c[sbase]);
        float v1 = bf2f((unsigned int)s_c[sbase + 10]);
        const float* wrp = s_w + c * 64 + chb;
        #pragma unroll
        for (int u4 = 0; u4 < 4; ++u4) {
            float4 wv = *(const float4*)(wrp + u4 * 4);
            acc0[u4*4+0] += v0 * wv.x; acc0[u4*4+1] += v0 * wv.y;
            acc0[u4*4+2] += v0 * wv.z; acc0[u4*4+3] += v0 * wv.w;
            acc1[u4*4+0] += v1 * wv.x; acc1[u4*4+1] += v1 * wv.y;
            acc1[u4*4+2] += v1 * wv.z; acc1[u4*4+3] += v1 * wv.w;
        }
    }
    float* o0 = out + ((size_t)(b * N_ + i) * N_ + jt * 128 + jg * 2) * 64 + chb;
    #pragma unroll
    for (int u4 = 0; u4 < 4; ++u4) {
        float4 a; a.x = acc0[u4*4]; a.y = acc0[u4*4+1]; a.z = acc0[u4*4+2]; a.w = acc0[u4*4+3];
        *(float4*)(o0 + u4 * 4) = a;
        float4 c4; c4.x = acc1[u4*4]; c4.y = acc1[u4*4+1]; c4.z = acc1[u4*4+2]; c4.w = acc1[u4*4+3];
        *(float4*)(o0 + 64 + u4 * 4) = c4;
    }
}

// ---------------------------------------------------------------------------
extern "C" void kernel_launch(void* const* d_in, const int* in_sizes, int n_in,
                              void* d_out, int out_size, void* d_ws, size_t ws_size,
                              hipStream_t stream)
{
    const float* e    = (const float*)d_in[0];
    const float* mask = (const float*)d_in[1];
    const float* ln_w = (const float*)d_in[2];
    const float* ln_b = (const float*)d_in[3];
    const float* W_V  = (const float*)d_in[4];
    const float* b_V  = (const float*)d_in[5];
    const float* W_EG = (const float*)d_in[6];
    const float* b_EG = (const float*)d_in[7];
    const float* W_O  = (const float*)d_in[8];
    const float* b_O  = (const float*)d_in[9];
    float* out = (float*)d_out;

    char* ws = (char*)d_ws;
    unsigned short* VtIn   = (unsigned short*)(ws);               // 37,748,736
    unsigned short* VtOut  = (unsigned short*)(ws + 37748736);    // 37,748,736
    unsigned short* A_in   = (unsigned short*)(ws + 75497472);    //  4,718,592
    unsigned short* A_outT = (unsigned short*)(ws + 80216064);    //  4,718,592
    float* EGin   = (float*)(ws + 84934656);                      // 18,874,368
    float* EGoutT = (float*)(ws + 103809024);                     // 18,874,368
    unsigned short* Cws    = (unsigned short*)(ws);               // overlays Vt after transpose
    unsigned short* Whi = A_in;                                   // k0->k1 transient
    unsigned short* Wlo = A_in + 10240;

    const bool big_ws = ws_size >= 198180864ull;
    // merged path: VT2 in fresh space (no overlap with EG => safe concurrency)
    unsigned short* VT2In  = (unsigned short*)(ws + (big_ws ? 122683392 : 84934656));
    unsigned short* VT2Out = (unsigned short*)(ws + (big_ws ? 160432128 : 122683392));

    hipLaunchKernelGGL(k0_prep, dim3(40), dim3(256), 0, stream, W_V, W_EG, Whi, Wlo);
    hipLaunchKernelGGL(k1_ln_proj, dim3(96, 24, 2), dim3(256), 0, stream,
                       e, mask, ln_w, ln_b, Whi, Wlo, b_V, b_EG, VtIn, VtOut, EGin, EGoutT);
    if (big_ws) {
        hipLaunchKernelGGL(k2m, dim3(1536 + 9216), dim3(256), 0, stream,
                           EGin, EGoutT, A_in, A_outT, VtIn, VtOut, VT2In, VT2Out);
    } else {
        hipLaunchKernelGGL(k2_softmax, dim3(768), dim3(256), 0, stream, EGin, A_in);
        hipLaunchKernelGGL(k2_softmax, dim3(768), dim3(256), 0, stream, EGoutT, A_outT);
        hipLaunchKernelGGL(k2t_transpose, dim3(288, 16, 2), dim3(256), 0, stream,
                           VtIn, VtOut, VT2In, VT2Out);
    }
    hipLaunchKernelGGL(k3_mfma, dim3(24, 3, 32), dim3(256), 0, stream,
                       A_in, VT2In, Cws);
    hipLaunchKernelGGL(k4_proj, dim3(3, 384, 2), dim3(256), 0, stream,
                       Cws, W_O, b_O, out);
}

// Round 16
// 262.197 us; speedup vs baseline: 1.4358x; 1.1144x over previous
//
#include <hip/hip_runtime.h>

#define N_ 384
#define LNEPS 1e-5f

typedef __attribute__((ext_vector_type(8))) short bf16x8;
typedef __attribute__((ext_vector_type(4))) float f32x4;

__device__ __forceinline__ float bf2f(unsigned int u) {
    union { unsigned int i; float f; } v; v.i = u << 16; return v.f;
}
__device__ __forceinline__ unsigned short f2bf(float f) {
    union { float f; unsigned int i; } v; v.f = f;
    return (unsigned short)((v.i + 0x7FFFu + ((v.i >> 16) & 1u)) >> 16);
}
__device__ __forceinline__ void gload16(const void* g, void* l) {
    __builtin_amdgcn_global_load_lds(
        (const __attribute__((address_space(1))) void*)g,
        (__attribute__((address_space(3))) void*)l, 16, 0, 0);
}

// ---------------------------------------------------------------------------
// Kernel 0: convert projection weights to bf16 hi/lo pairs, [col][k] layout.
// ---------------------------------------------------------------------------
__global__ __launch_bounds__(256) void k0_prep(
    const float* __restrict__ W_V, const float* __restrict__ W_EG,
    unsigned short* __restrict__ Whi, unsigned short* __restrict__ Wlo)
{
    int x = blockIdx.x * 256 + threadIdx.x;
    if (x >= 10240) return;
    int col = x >> 6, k = x & 63;
    float wv = (col < 128) ? W_V[k * 128 + col] : W_EG[k * 32 + (col - 128)];
    unsigned short hi = f2bf(wv);
    Whi[x] = hi;
    Wlo[x] = f2bf(wv - bf2f(hi));
}

// ---------------------------------------------------------------------------
// Kernel 1: LN + V/EG projections (round-11/15-verified structure). CHANGE:
// V cols (n<8) use (ahi+alo)*Whi only (no Wlo load) -> W working set 24KB,
// L1-resident; EG cols keep full 3-term. Everything else verbatim.
// ---------------------------------------------------------------------------
__global__ __launch_bounds__(256) void k1_ln_proj(
    const float* __restrict__ e, const float* __restrict__ mask,
    const float* __restrict__ ln_w, const float* __restrict__ ln_b,
    const unsigned short* __restrict__ Whi_g, const unsigned short* __restrict__ Wlo_g,
    const float* __restrict__ b_V, const float* __restrict__ b_EG,
    unsigned short* __restrict__ VtIn, unsigned short* __restrict__ VtOut,
    float* __restrict__ EGin, float* __restrict__ EGoutT)
{
    __shared__ __align__(16) char smem[25088];
    unsigned short* s_v = (unsigned short*)smem;
    float* s_eg = (float*)(smem + 16640);

    const int t = threadIdx.x;
    const int j0 = blockIdx.x * 4;
    const int i0 = blockIdx.y * 16;
    const int b  = blockIdx.z;

    const int l = t & 63, w = t >> 6;
    const int l15 = l & 15, lq = l >> 4;

    const int r = w * 16 + l15;
    const int r1f = i0 + (r >> 2), r2f = j0 + (r & 3);
    const float* erow = e + ((size_t)((b * N_ + r1f) * N_ + r2f)) * 64;
    float ev[16];
    {
        float4 e0 = *(const float4*)(erow + lq * 8);
        float4 e1 = *(const float4*)(erow + lq * 8 + 4);
        float4 e2 = *(const float4*)(erow + 32 + lq * 8);
        float4 e3 = *(const float4*)(erow + 32 + lq * 8 + 4);
        ev[0]=e0.x; ev[1]=e0.y; ev[2]=e0.z;  ev[3]=e0.w;
        ev[4]=e1.x; ev[5]=e1.y; ev[6]=e1.z;  ev[7]=e1.w;
        ev[8]=e2.x; ev[9]=e2.y; ev[10]=e2.z; ev[11]=e2.w;
        ev[12]=e3.x; ev[13]=e3.y; ev[14]=e3.z; ev[15]=e3.w;
    }
    float s = 0.f, sq = 0.f;
    #pragma unroll
    for (int j = 0; j < 16; ++j) { s += ev[j]; sq += ev[j] * ev[j]; }
    s  += __shfl_xor(s, 16);  s  += __shfl_xor(s, 32);
    sq += __shfl_xor(sq, 16); sq += __shfl_xor(sq, 32);
    const float mean = s * (1.f / 64.f);
    const float rstd = rsqrtf(sq * (1.f / 64.f) - mean * mean + LNEPS);

    bf16x8 ahi[2], alo[2];
    {
        float lnwv[16], lnbv[16];
        float4 w0 = *(const float4*)(ln_w + lq * 8);
        float4 w1 = *(const float4*)(ln_w + lq * 8 + 4);
        float4 w2 = *(const float4*)(ln_w + 32 + lq * 8);
        float4 w3 = *(const float4*)(ln_w + 32 + lq * 8 + 4);
        lnwv[0]=w0.x; lnwv[1]=w0.y; lnwv[2]=w0.z;  lnwv[3]=w0.w;
        lnwv[4]=w1.x; lnwv[5]=w1.y; lnwv[6]=w1.z;  lnwv[7]=w1.w;
        lnwv[8]=w2.x; lnwv[9]=w2.y; lnwv[10]=w2.z; lnwv[11]=w2.w;
        lnwv[12]=w3.x; lnwv[13]=w3.y; lnwv[14]=w3.z; lnwv[15]=w3.w;
        float4 b0 = *(const float4*)(ln_b + lq * 8);
        float4 b1 = *(const float4*)(ln_b + lq * 8 + 4);
        float4 b2 = *(const float4*)(ln_b + 32 + lq * 8);
        float4 b3 = *(const float4*)(ln_b + 32 + lq * 8 + 4);
        lnbv[0]=b0.x; lnbv[1]=b0.y; lnbv[2]=b0.z;  lnbv[3]=b0.w;
        lnbv[4]=b1.x; lnbv[5]=b1.y; lnbv[6]=b1.z;  lnbv[7]=b1.w;
        lnbv[8]=b2.x; lnbv[9]=b2.y; lnbv[10]=b2.z; lnbv[11]=b2.w;
        lnbv[12]=b3.x; lnbv[13]=b3.y; lnbv[14]=b3.z; lnbv[15]=b3.w;
        #pragma unroll
        for (int ks = 0; ks < 2; ++ks) {
            #pragma unroll
            for (int j = 0; j < 8; ++j) {
                float x = (ev[ks * 8 + j] - mean) * rstd * lnwv[ks * 8 + j] + lnbv[ks * 8 + j];
                unsigned short h = f2bf(x);
                unsigned short lo = f2bf(x - bf2f(h));
                ahi[ks][j] = (short)h;
                alo[ks][j] = (short)lo;
            }
        }
    }

    f32x4 acc[10];
    #pragma unroll
    for (int n = 0; n < 10; ++n) acc[n] = (f32x4){0.f, 0.f, 0.f, 0.f};

    #pragma unroll
    for (int n = 0; n < 10; ++n) {
        int brow = n * 16 + l15;
        const unsigned short* wh = Whi_g + brow * 64;
        bf16x8 bh0 = *(const bf16x8*)(wh + lq * 8);
        bf16x8 bh1 = *(const bf16x8*)(wh + 32 + lq * 8);
        acc[n] = __builtin_amdgcn_mfma_f32_16x16x32_bf16(ahi[0], bh0, acc[n], 0, 0, 0);
        acc[n] = __builtin_amdgcn_mfma_f32_16x16x32_bf16(ahi[1], bh1, acc[n], 0, 0, 0);
        acc[n] = __builtin_amdgcn_mfma_f32_16x16x32_bf16(alo[0], bh0, acc[n], 0, 0, 0);
        acc[n] = __builtin_amdgcn_mfma_f32_16x16x32_bf16(alo[1], bh1, acc[n], 0, 0, 0);
        if (n >= 8) {   // EG logits: compensate W rounding too
            const unsigned short* wl = Wlo_g + brow * 64;
            bf16x8 bl0 = *(const bf16x8*)(wl + lq * 8);
            bf16x8 bl1 = *(const bf16x8*)(wl + 32 + lq * 8);
            acc[n] = __builtin_amdgcn_mfma_f32_16x16x32_bf16(ahi[0], bl0, acc[n], 0, 0, 0);
            acc[n] = __builtin_amdgcn_mfma_f32_16x16x32_bf16(ahi[1], bl1, acc[n], 0, 0, 0);
        }
    }

    #pragma unroll
    for (int n = 0; n < 8; ++n) {
        float bb = b_V[n * 16 + l15];
        #pragma unroll
        for (int q = 0; q < 4; ++q)
            s_v[(w * 16 + lq * 4 + q) * 130 + n * 16 + l15] = f2bf(acc[n][q] + bb);
    }
    #pragma unroll
    for (int n = 8; n < 10; ++n) {
        #pragma unroll
        for (int q = 0; q < 4; ++q)
            s_eg[(w * 16 + lq * 4 + q) * 33 + (n - 8) * 16 + l15] = acc[n][q];
    }
    __syncthreads();

    {
        const int rr = t & 63, g = t >> 6;
        const int r1 = i0 + (rr >> 2);
        const int r2 = j0 + (rr & 3);
        #pragma unroll
        for (int io = 0; io < 2; ++io) {
            #pragma unroll
            for (int hs = 0; hs < 2; ++hs) {
                const int h = g + hs * 4;
                uint4 u4;
                unsigned int wv[4];
                #pragma unroll
                for (int dp = 0; dp < 4; ++dp) {
                    int c0 = io * 64 + (2 * dp) * 8 + h;
                    int c1 = io * 64 + (2 * dp + 1) * 8 + h;
                    wv[dp] = (unsigned int)s_v[rr * 130 + c0]
                           | ((unsigned int)s_v[rr * 130 + c1] << 16);
                }
                u4.x = wv[0]; u4.y = wv[1]; u4.z = wv[2]; u4.w = wv[3];
                if (io == 0) {
                    *(uint4*)(VtIn + ((size_t)((b * 8 + h) * N_ + r2)) * 3072 + (size_t)r1 * 8) = u4;
                } else {
                    *(uint4*)(VtOut + ((size_t)((b * 8 + h) * N_ + r1)) * 3072 + (size_t)r2 * 8) = u4;
                }
            }
        }
    }
    {
        const int rr = t >> 2, cq = (t & 3) * 4;
        const int r1 = i0 + (rr >> 2);
        const int r2 = j0 + (rr & 3);
        const float maskv = mask[(size_t)(b * N_ + r1) * N_ + r2];
        float4 v0, v1;
        float tmp0[4], tmp1[4];
        #pragma unroll
        for (int u = 0; u < 4; ++u) {
            int c2 = cq + u;
            float x = s_eg[rr * 33 + c2] + b_EG[c2] + maskv;
            if (c2 >= 8) x = 1.f / (1.f + expf(-x));
            tmp0[u] = x;
            int c3 = 16 + cq + u;
            float y = s_eg[rr * 33 + c3] + b_EG[c3] + maskv;
            if ((cq + u) >= 8) y = 1.f / (1.f + expf(-y));
            tmp1[u] = y;
        }
        v0.x = tmp0[0]; v0.y = tmp0[1]; v0.z = tmp0[2]; v0.w = tmp0[3];
        v1.x = tmp1[0]; v1.y = tmp1[1]; v1.z = tmp1[2]; v1.w = tmp1[3];
        *(float4*)(EGin   + ((size_t)((b * N_ + r1) * N_ + r2)) * 16 + cq) = v0;
        *(float4*)(EGoutT + ((size_t)((b * N_ + r2) * N_ + r1)) * 16 + cq) = v1;
    }
}

// ---------------------------------------------------------------------------
// Merged kernel: softmax (x2) + V transpose (round-15-verified verbatim).
// ---------------------------------------------------------------------------
__global__ __launch_bounds__(256) void k2m(
    const float* __restrict__ EGin, const float* __restrict__ EGoutT,
    unsigned short* __restrict__ A_in, unsigned short* __restrict__ A_outT,
    const unsigned short* __restrict__ VtIn, const unsigned short* __restrict__ VtOut,
    unsigned short* __restrict__ VT2In, unsigned short* __restrict__ VT2Out)
{
    __shared__ __align__(16) char sm[26112];
    const int t = threadIdx.x;
    const int bid = blockIdx.x;

    if (bid < 1536) {
        float* s = (float*)sm;
        const float* EG = (bid < 768) ? EGin : EGoutT;
        unsigned short* A = (bid < 768) ? A_in : A_outT;
        const int b2 = (bid < 768) ? bid : bid - 768;
        const int i = b2 % N_, b = b2 / N_;
        const float* base = EG + ((size_t)(b * N_ + i) * N_) * 16;
        for (int x = t; x < 6144; x += 256) {
            int k = x >> 4, c = x & 15;
            s[k * 17 + c] = base[x];
        }
        __syncthreads();
        const int h = t >> 5, l = t & 31;
        float ev[12];
        float mx = -1e30f;
        #pragma unroll
        for (int j = 0; j < 12; ++j) {
            ev[j] = s[(l + 32 * j) * 17 + h];
            mx = fmaxf(mx, ev[j]);
        }
        #pragma unroll
        for (int off = 16; off >= 1; off >>= 1) mx = fmaxf(mx, __shfl_xor(mx, off));
        float sum = 0.f;
        #pragma unroll
        for (int j = 0; j < 12; ++j) { ev[j] = expf(ev[j] - mx); sum += ev[j]; }
        #pragma unroll
        for (int off = 16; off >= 1; off >>= 1) sum += __shfl_xor(sum, off);
        const float inv = 1.f / sum;
        unsigned short* arow = A + ((size_t)((b * 8 + h) * N_ + i)) * N_;
        #pragma unroll
        for (int j = 0; j < 12; ++j) {
            int k = l + 32 * j;
            arow[k] = f2bf(ev[j] * inv * s[k * 17 + 8 + h]);
        }
    } else {
        unsigned short* s = (unsigned short*)sm;
        const int bid2 = bid - 1536;
        const int xx = bid2 % 288;
        const int rest = bid2 / 288;
        const int q = rest & 15, arr = rest >> 4;
        const int ktile = xx % 6, jt = xx / 6;
        const unsigned short* src = (arr ? VtOut : VtIn) + (size_t)q * 1179648;
        unsigned short* dst = (arr ? VT2Out : VT2In) + (size_t)q * 1179648;
        const int k0 = ktile * 64, jd0 = jt * 64;

        {
            const int kk = t >> 2, cgq = t & 3;
            const unsigned short* g = src + (size_t)(k0 + kk) * 3072 + jd0 + cgq * 16;
            uint4 u0 = *(const uint4*)g;
            uint4 u1 = *(const uint4*)(g + 8);
            int cp = (cgq ^ (kk & 3)) * 16;
            *(uint4*)&s[kk * 72 + cp] = u0;
            *(uint4*)&s[kk * 72 + cp + 8] = u1;
        }
        __syncthreads();
        {
            const int jj = t & 63, kq = (t >> 6) * 16;
            unsigned int wv[8];
            #pragma unroll
            for (int p = 0; p < 8; ++p) {
                int u0 = 2 * p, u1 = 2 * p + 1;
                unsigned short a = s[(kq + u0) * 72 + (((jj >> 4) ^ (u0 & 3)) << 4) + (jj & 15)];
                unsigned short c = s[(kq + u1) * 72 + (((jj >> 4) ^ (u1 & 3)) << 4) + (jj & 15)];
                wv[p] = (unsigned int)a | ((unsigned int)c << 16);
            }
            unsigned short* o = dst + (size_t)(jd0 + jj) * 384 + k0 + kq;
            uint4 x0; x0.x = wv[0]; x0.y = wv[1]; x0.z = wv[2]; x0.w = wv[3];
            uint4 x1; x1.x = wv[4]; x1.y = wv[5]; x1.z = wv[6]; x1.w = wv[7];
            *(uint4*)o = x0;
            *(uint4*)(o + 8) = x1;
        }
    }
}

// Serial-fallback copies (verbatim) for small workspaces.
__global__ __launch_bounds__(256) void k2_softmax(
    const float* __restrict__ EG, unsigned short* __restrict__ A)
{
    __shared__ float s[384 * 17];
    const int t = threadIdx.x;
    const int i = blockIdx.x % N_, b = blockIdx.x / N_;
    const float* base = EG + ((size_t)(b * N_ + i) * N_) * 16;
    for (int x = t; x < 6144; x += 256) {
        int k = x >> 4, c = x & 15;
        s[k * 17 + c] = base[x];
    }
    __syncthreads();
    const int h = t >> 5, l = t & 31;
    float ev[12];
    float mx = -1e30f;
    #pragma unroll
    for (int j = 0; j < 12; ++j) {
        ev[j] = s[(l + 32 * j) * 17 + h];
        mx = fmaxf(mx, ev[j]);
    }
    #pragma unroll
    for (int off = 16; off >= 1; off >>= 1) mx = fmaxf(mx, __shfl_xor(mx, off));
    float sum = 0.f;
    #pragma unroll
    for (int j = 0; j < 12; ++j) { ev[j] = expf(ev[j] - mx); sum += ev[j]; }
    #pragma unroll
    for (int off = 16; off >= 1; off >>= 1) sum += __shfl_xor(sum, off);
    const float inv = 1.f / sum;
    unsigned short* arow = A + ((size_t)((b * 8 + h) * N_ + i)) * N_;
    #pragma unroll
    for (int j = 0; j < 12; ++j) {
        int k = l + 32 * j;
        arow[k] = f2bf(ev[j] * inv * s[k * 17 + 8 + h]);
    }
}

__global__ __launch_bounds__(256) void k2t_transpose(
    const unsigned short* __restrict__ VtIn, const unsigned short* __restrict__ VtOut,
    unsigned short* __restrict__ VT2In, unsigned short* __restrict__ VT2Out)
{
    __shared__ unsigned short s[64 * 72];
    const int t = threadIdx.x;
    const int ktile = blockIdx.x % 6, jt = blockIdx.x / 6;
    const int q = blockIdx.y;
    const int arr = blockIdx.z;
    const unsigned short* src = (arr ? VtOut : VtIn) + (size_t)q * 1179648;
    unsigned short* dst = (arr ? VT2Out : VT2In) + (size_t)q * 1179648;
    const int k0 = ktile * 64, jd0 = jt * 64;

    {
        const int kk = t >> 2, cgq = t & 3;
        const unsigned short* g = src + (size_t)(k0 + kk) * 3072 + jd0 + cgq * 16;
        uint4 u0 = *(const uint4*)g;
        uint4 u1 = *(const uint4*)(g + 8);
        int cp = (cgq ^ (kk & 3)) * 16;
        *(uint4*)&s[kk * 72 + cp] = u0;
        *(uint4*)&s[kk * 72 + cp + 8] = u1;
    }
    __syncthreads();
    {
        const int jj = t & 63, kq = (t >> 6) * 16;
        unsigned int wv[8];
        #pragma unroll
        for (int p = 0; p < 8; ++p) {
            int u0 = 2 * p, u1 = 2 * p + 1;
            unsigned short a = s[(kq + u0) * 72 + (((jj >> 4) ^ (u0 & 3)) << 4) + (jj & 15)];
            unsigned short c = s[(kq + u1) * 72 + (((jj >> 4) ^ (u1 & 3)) << 4) + (jj & 15)];
            wv[p] = (unsigned int)a | ((unsigned int)c << 16);
        }
        unsigned short* o = dst + (size_t)(jd0 + jj) * 384 + k0 + kq;
        uint4 x0; x0.x = wv[0]; x0.y = wv[1]; x0.z = wv[2]; x0.w = wv[3];
        uint4 x1; x1.x = wv[4]; x1.y = wv[5]; x1.z = wv[6]; x1.w = wv[7];
        *(uint4*)o = x0;
        *(uint4*)(o + 8) = x1;
    }
}

// ---------------------------------------------------------------------------
// Kernel 3: batched MFMA GEMM (round-11-verified verbatim, plane-major C).
// ---------------------------------------------------------------------------
__global__ __launch_bounds__(256) void k3_mfma(
    const unsigned short* __restrict__ Aall,   // [32][384][384]
    const unsigned short* __restrict__ Vall,   // [32][3072][384]
    unsigned short* __restrict__ C)            // [32][384][3072]
{
    __shared__ __align__(16) short sAB[16384];
    short* sA = sAB;
    short* sB = sAB + 8192;

    const int t = threadIdx.x;
    const int n0 = blockIdx.x * 128;
    const int i0 = blockIdx.y * 128;
    const int z  = blockIdx.z;

    const unsigned short* Ap = Aall + (size_t)z * 147456;
    const unsigned short* Bp = Vall + (size_t)z * 1179648;

    const int l = t & 63;
    const int w = t >> 6;
    const int wr = w >> 1, wc = w & 1;
    const int l15 = l & 15, lq = l >> 4;
    const int srow = l >> 3, schunk = (l & 7) ^ (l >> 3);

    f32x4 acc[4][4];
    #pragma unroll
    for (int mi = 0; mi < 4; ++mi)
        #pragma unroll
        for (int ni = 0; ni < 4; ++ni) acc[mi][ni] = (f32x4){0.f, 0.f, 0.f, 0.f};

    #pragma unroll 1
    for (int kt = 0; kt < 6; ++kt) {
        const int k0 = kt * 64;
        #pragma unroll
        for (int i = 0; i < 4; ++i) {
            int rbase = w * 32 + i * 8;
            gload16(Ap + (size_t)(i0 + rbase + srow) * 384 + k0 + schunk * 8,
                    (char*)sA + rbase * 128);
            gload16(Bp + (size_t)(n0 + rbase + srow) * 384 + k0 + schunk * 8,
                    (char*)sB + rbase * 128);
        }
        __syncthreads();

        bf16x8 av[4][2], bv[4][2];
        #pragma unroll
        for (int mi = 0; mi < 4; ++mi) {
            int row = wr * 64 + mi * 16 + l15;
            #pragma unroll
            for (int ks = 0; ks < 2; ++ks) {
                int kc = ks * 4 + lq;
                av[mi][ks] = *(const bf16x8*)((const char*)sA + row * 128 + ((kc ^ (row & 7)) << 4));
            }
        }
        #pragma unroll
        for (int ni = 0; ni < 4; ++ni) {
            int row = wc * 64 + ni * 16 + l15;
            #pragma unroll
            for (int ks = 0; ks < 2; ++ks) {
                int kc = ks * 4 + lq;
                bv[ni][ks] = *(const bf16x8*)((const char*)sB + row * 128 + ((kc ^ (row & 7)) << 4));
            }
        }
        #pragma unroll
        for (int mi = 0; mi < 4; ++mi)
            #pragma unroll
            for (int ni = 0; ni < 4; ++ni) {
                acc[mi][ni] = __builtin_amdgcn_mfma_f32_16x16x32_bf16(av[mi][0], bv[ni][0], acc[mi][ni], 0, 0, 0);
                acc[mi][ni] = __builtin_amdgcn_mfma_f32_16x16x32_bf16(av[mi][1], bv[ni][1], acc[mi][ni], 0, 0, 0);
            }
        __syncthreads();
    }

    unsigned short* Cp = C + (size_t)z * 1179648;
    #pragma unroll
    for (int mi = 0; mi < 4; ++mi) {
        #pragma unroll
        for (int qq = 0; qq < 4; ++qq) {
            int row = i0 + wr * 64 + mi * 16 + lq * 4 + qq;
            unsigned short* crow = Cp + (size_t)row * 3072 + n0 + wc * 64 + l15;
            #pragma unroll
            for (int ni = 0; ni < 4; ++ni) crow[ni * 16] = f2bf(acc[mi][ni][qq]);
        }
    }
}

// ---------------------------------------------------------------------------
// Kernel 4: out = b_O + C(gathered) @ W_O (round-11-verified verbatim).
// ---------------------------------------------------------------------------
__global__ __launch_bounds__(256) void k4_proj(
    const unsigned short* __restrict__ C, const float* __restrict__ W_O,
    const float* __restrict__ b_O, float* __restrict__ out)
{
    __shared__ float s_w[8192];
    __shared__ unsigned short s_c[20480];
    const int t = threadIdx.x;
    const int jt = blockIdx.x;
    const int i  = blockIdx.y;
    const int b  = blockIdx.z;

    for (int x = t; x < 8192; x += 256) s_w[x] = W_O[x];
    {
        unsigned int* s_c32 = (unsigned int*)s_c;
        #pragma unroll
        for (int rep = 0; rep < 8; ++rep) {
            int flat = rep * 256 + t;
            int p = flat >> 7, jj = flat & 127;
            int plane = b * 8 + (p & 7) + (p >> 3) * 16;
            uint4 v = *(const uint4*)(C + (size_t)plane * 1179648 + (size_t)i * 3072 + jt * 1024 + jj * 8);
            int base = p * 640 + jj * 5;
            s_c32[base] = v.x; s_c32[base + 1] = v.y; s_c32[base + 2] = v.z; s_c32[base + 3] = v.w;
        }
    }
    __syncthreads();

    const int jg = t & 63, cg = t >> 6;
    const int chb = cg * 16;
    float acc0[16], acc1[16];
    #pragma unroll
    for (int u = 0; u < 16; ++u) { float bb = b_O[chb + u]; acc0[u] = bb; acc1[u] = bb; }

    #pragma unroll 4
    for (int c = 0; c < 128; ++c) {
        const int p = c & 15, d = c >> 4;
        const int sbase = p * 1280 + (jg * 2) * 10 + d;
        float v0 = bf2f((unsigned int)s_c[sbase]);
        float v1 = bf2f((unsigned int)s_c[sbase + 10]);
        const float* wrp = s_w + c * 64 + chb;
        #pragma unroll
        for (int u4 = 0; u4 < 4; ++u4) {
            float4 wv = *(const float4*)(wrp + u4 * 4);
            acc0[u4*4+0] += v0 * wv.x; acc0[u4*4+1] += v0 * wv.y;
            acc0[u4*4+2] += v0 * wv.z; acc0[u4*4+3] += v0 * wv.w;
            acc1[u4*4+0] += v1 * wv.x; acc1[u4*4+1] += v1 * wv.y;
            acc1[u4*4+2] += v1 * wv.z; acc1[u4*4+3] += v1 * wv.w;
        }
    }
    float* o0 = out + ((size_t)(b * N_ + i) * N_ + jt * 128 + jg * 2) * 64 + chb;
    #pragma unroll
    for (int u4 = 0; u4 < 4; ++u4) {
        float4 a; a.x = acc0[u4*4]; a.y = acc0[u4*4+1]; a.z = acc0[u4*4+2]; a.w = acc0[u4*4+3];
        *(float4*)(o0 + u4 * 4) = a;
        float4 c4; c4.x = acc1[u4*4]; c4.y = acc1[u4*4+1]; c4.z = acc1[u4*4+2]; c4.w = acc1[u4*4+3];
        *(float4*)(o0 + 64 + u4 * 4) = c4;
    }
}

// ---------------------------------------------------------------------------
extern "C" void kernel_launch(void* const* d_in, const int* in_sizes, int n_in,
                              void* d_out, int out_size, void* d_ws, size_t ws_size,
                              hipStream_t stream)
{
    const float* e    = (const float*)d_in[0];
    const float* mask = (const float*)d_in[1];
    const float* ln_w = (const float*)d_in[2];
    const float* ln_b = (const float*)d_in[3];
    const float* W_V  = (const float*)d_in[4];
    const float* b_V  = (const float*)d_in[5];
    const float* W_EG = (const float*)d_in[6];
    const float* b_EG = (const float*)d_in[7];
    const float* W_O  = (const float*)d_in[8];
    const float* b_O  = (const float*)d_in[9];
    float* out = (float*)d_out;

    char* ws = (char*)d_ws;
    unsigned short* VtIn   = (unsigned short*)(ws);               // 37,748,736
    unsigned short* VtOut  = (unsigned short*)(ws + 37748736);    // 37,748,736
    unsigned short* A_in   = (unsigned short*)(ws + 75497472);    //  4,718,592
    unsigned short* A_outT = (unsigned short*)(ws + 80216064);    //  4,718,592
    float* EGin   = (float*)(ws + 84934656);                      // 18,874,368
    float* EGoutT = (float*)(ws + 103809024);                     // 18,874,368
    unsigned short* Cws    = (unsigned short*)(ws);               // overlays Vt after transpose
    unsigned short* Whi = A_in;                                   // k0->k1 transient
    unsigned short* Wlo = A_in + 10240;

    const bool big_ws = ws_size >= 198180864ull;
    unsigned short* VT2In  = (unsigned short*)(ws + (big_ws ? 122683392 : 84934656));
    unsigned short* VT2Out = (unsigned short*)(ws + (big_ws ? 160432128 : 122683392));

    hipLaunchKernelGGL(k0_prep, dim3(40), dim3(256), 0, stream, W_V, W_EG, Whi, Wlo);
    hipLaunchKernelGGL(k1_ln_proj, dim3(96, 24, 2), dim3(256), 0, stream,
                       e, mask, ln_w, ln_b, Whi, Wlo, b_V, b_EG, VtIn, VtOut, EGin, EGoutT);
    if (big_ws) {
        hipLaunchKernelGGL(k2m, dim3(1536 + 9216), dim3(256), 0, stream,
                           EGin, EGoutT, A_in, A_outT, VtIn, VtOut, VT2In, VT2Out);
    } else {
        hipLaunchKernelGGL(k2_softmax, dim3(768), dim3(256), 0, stream, EGin, A_in);
        hipLaunchKernelGGL(k2_softmax, dim3(768), dim3(256), 0, stream, EGoutT, A_outT);
        hipLaunchKernelGGL(k2t_transpose, dim3(288, 16, 2), dim3(256), 0, stream,
                           VtIn, VtOut, VT2In, VT2Out);
    }
    hipLaunchKernelGGL(k3_mfma, dim3(24, 3, 32), dim3(256), 0, stream,
                       A_in, VT2In, Cws);
    hipLaunchKernelGGL(k4_proj, dim3(3, 384, 2), dim3(256), 0, stream,
                       Cws, W_O, b_O, out);
}

// Round 17
// 240.539 us; speedup vs baseline: 1.5651x; 1.0900x over previous
//
#include <hip/hip_runtime.h>

#define N_ 384
#define LNEPS 1e-5f

typedef __attribute__((ext_vector_type(8))) short bf16x8;
typedef __attribute__((ext_vector_type(4))) float f32x4;

__device__ __forceinline__ float bf2f(unsigned int u) {
    union { unsigned int i; float f; } v; v.i = u << 16; return v.f;
}
__device__ __forceinline__ unsigned short f2bf(float f) {
    union { float f; unsigned int i; } v; v.f = f;
    return (unsigned short)((v.i + 0x7FFFu + ((v.i >> 16) & 1u)) >> 16);
}
__device__ __forceinline__ void gload16(const void* g, void* l) {
    __builtin_amdgcn_global_load_lds(
        (const __attribute__((address_space(1))) void*)g,
        (__attribute__((address_space(3))) void*)l, 16, 0, 0);
}

// ---------------------------------------------------------------------------
// Kernel 0: convert projection weights to bf16 hi/lo pairs, [col][k] layout.
// ---------------------------------------------------------------------------
__global__ __launch_bounds__(256) void k0_prep(
    const float* __restrict__ W_V, const float* __restrict__ W_EG,
    unsigned short* __restrict__ Whi, unsigned short* __restrict__ Wlo)
{
    int x = blockIdx.x * 256 + threadIdx.x;
    if (x >= 10240) return;
    int col = x >> 6, k = x & 63;
    float wv = (col < 128) ? W_V[k * 128 + col] : W_EG[k * 32 + (col - 128)];
    unsigned short hi = f2bf(wv);
    Whi[x] = hi;
    Wlo[x] = f2bf(wv - bf2f(hi));
}

// ---------------------------------------------------------------------------
// Kernel 1: LN + V/EG projections (round-16-verified VERBATIM).
// ---------------------------------------------------------------------------
__global__ __launch_bounds__(256) void k1_ln_proj(
    const float* __restrict__ e, const float* __restrict__ mask,
    const float* __restrict__ ln_w, const float* __restrict__ ln_b,
    const unsigned short* __restrict__ Whi_g, const unsigned short* __restrict__ Wlo_g,
    const float* __restrict__ b_V, const float* __restrict__ b_EG,
    unsigned short* __restrict__ VtIn, unsigned short* __restrict__ VtOut,
    float* __restrict__ EGin, float* __restrict__ EGoutT)
{
    __shared__ __align__(16) char smem[25088];
    unsigned short* s_v = (unsigned short*)smem;
    float* s_eg = (float*)(smem + 16640);

    const int t = threadIdx.x;
    const int j0 = blockIdx.x * 4;
    const int i0 = blockIdx.y * 16;
    const int b  = blockIdx.z;

    const int l = t & 63, w = t >> 6;
    const int l15 = l & 15, lq = l >> 4;

    const int r = w * 16 + l15;
    const int r1f = i0 + (r >> 2), r2f = j0 + (r & 3);
    const float* erow = e + ((size_t)((b * N_ + r1f) * N_ + r2f)) * 64;
    float ev[16];
    {
        float4 e0 = *(const float4*)(erow + lq * 8);
        float4 e1 = *(const float4*)(erow + lq * 8 + 4);
        float4 e2 = *(const float4*)(erow + 32 + lq * 8);
        float4 e3 = *(const float4*)(erow + 32 + lq * 8 + 4);
        ev[0]=e0.x; ev[1]=e0.y; ev[2]=e0.z;  ev[3]=e0.w;
        ev[4]=e1.x; ev[5]=e1.y; ev[6]=e1.z;  ev[7]=e1.w;
        ev[8]=e2.x; ev[9]=e2.y; ev[10]=e2.z; ev[11]=e2.w;
        ev[12]=e3.x; ev[13]=e3.y; ev[14]=e3.z; ev[15]=e3.w;
    }
    float s = 0.f, sq = 0.f;
    #pragma unroll
    for (int j = 0; j < 16; ++j) { s += ev[j]; sq += ev[j] * ev[j]; }
    s  += __shfl_xor(s, 16);  s  += __shfl_xor(s, 32);
    sq += __shfl_xor(sq, 16); sq += __shfl_xor(sq, 32);
    const float mean = s * (1.f / 64.f);
    const float rstd = rsqrtf(sq * (1.f / 64.f) - mean * mean + LNEPS);

    bf16x8 ahi[2], alo[2];
    {
        float lnwv[16], lnbv[16];
        float4 w0 = *(const float4*)(ln_w + lq * 8);
        float4 w1 = *(const float4*)(ln_w + lq * 8 + 4);
        float4 w2 = *(const float4*)(ln_w + 32 + lq * 8);
        float4 w3 = *(const float4*)(ln_w + 32 + lq * 8 + 4);
        lnwv[0]=w0.x; lnwv[1]=w0.y; lnwv[2]=w0.z;  lnwv[3]=w0.w;
        lnwv[4]=w1.x; lnwv[5]=w1.y; lnwv[6]=w1.z;  lnwv[7]=w1.w;
        lnwv[8]=w2.x; lnwv[9]=w2.y; lnwv[10]=w2.z; lnwv[11]=w2.w;
        lnwv[12]=w3.x; lnwv[13]=w3.y; lnwv[14]=w3.z; lnwv[15]=w3.w;
        float4 b0 = *(const float4*)(ln_b + lq * 8);
        float4 b1 = *(const float4*)(ln_b + lq * 8 + 4);
        float4 b2 = *(const float4*)(ln_b + 32 + lq * 8);
        float4 b3 = *(const float4*)(ln_b + 32 + lq * 8 + 4);
        lnbv[0]=b0.x; lnbv[1]=b0.y; lnbv[2]=b0.z;  lnbv[3]=b0.w;
        lnbv[4]=b1.x; lnbv[5]=b1.y; lnbv[6]=b1.z;  lnbv[7]=b1.w;
        lnbv[8]=b2.x; lnbv[9]=b2.y; lnbv[10]=b2.z; lnbv[11]=b2.w;
        lnbv[12]=b3.x; lnbv[13]=b3.y; lnbv[14]=b3.z; lnbv[15]=b3.w;
        #pragma unroll
        for (int ks = 0; ks < 2; ++ks) {
            #pragma unroll
            for (int j = 0; j < 8; ++j) {
                float x = (ev[ks * 8 + j] - mean) * rstd * lnwv[ks * 8 + j] + lnbv[ks * 8 + j];
                unsigned short h = f2bf(x);
                unsigned short lo = f2bf(x - bf2f(h));
                ahi[ks][j] = (short)h;
                alo[ks][j] = (short)lo;
            }
        }
    }

    f32x4 acc[10];
    #pragma unroll
    for (int n = 0; n < 10; ++n) acc[n] = (f32x4){0.f, 0.f, 0.f, 0.f};

    #pragma unroll
    for (int n = 0; n < 10; ++n) {
        int brow = n * 16 + l15;
        const unsigned short* wh = Whi_g + brow * 64;
        bf16x8 bh0 = *(const bf16x8*)(wh + lq * 8);
        bf16x8 bh1 = *(const bf16x8*)(wh + 32 + lq * 8);
        acc[n] = __builtin_amdgcn_mfma_f32_16x16x32_bf16(ahi[0], bh0, acc[n], 0, 0, 0);
        acc[n] = __builtin_amdgcn_mfma_f32_16x16x32_bf16(ahi[1], bh1, acc[n], 0, 0, 0);
        acc[n] = __builtin_amdgcn_mfma_f32_16x16x32_bf16(alo[0], bh0, acc[n], 0, 0, 0);
        acc[n] = __builtin_amdgcn_mfma_f32_16x16x32_bf16(alo[1], bh1, acc[n], 0, 0, 0);
        if (n >= 8) {
            const unsigned short* wl = Wlo_g + brow * 64;
            bf16x8 bl0 = *(const bf16x8*)(wl + lq * 8);
            bf16x8 bl1 = *(const bf16x8*)(wl + 32 + lq * 8);
            acc[n] = __builtin_amdgcn_mfma_f32_16x16x32_bf16(ahi[0], bl0, acc[n], 0, 0, 0);
            acc[n] = __builtin_amdgcn_mfma_f32_16x16x32_bf16(ahi[1], bl1, acc[n], 0, 0, 0);
        }
    }

    #pragma unroll
    for (int n = 0; n < 8; ++n) {
        float bb = b_V[n * 16 + l15];
        #pragma unroll
        for (int q = 0; q < 4; ++q)
            s_v[(w * 16 + lq * 4 + q) * 130 + n * 16 + l15] = f2bf(acc[n][q] + bb);
    }
    #pragma unroll
    for (int n = 8; n < 10; ++n) {
        #pragma unroll
        for (int q = 0; q < 4; ++q)
            s_eg[(w * 16 + lq * 4 + q) * 33 + (n - 8) * 16 + l15] = acc[n][q];
    }
    __syncthreads();

    {
        const int rr = t & 63, g = t >> 6;
        const int r1 = i0 + (rr >> 2);
        const int r2 = j0 + (rr & 3);
        #pragma unroll
        for (int io = 0; io < 2; ++io) {
            #pragma unroll
            for (int hs = 0; hs < 2; ++hs) {
                const int h = g + hs * 4;
                uint4 u4;
                unsigned int wv[4];
                #pragma unroll
                for (int dp = 0; dp < 4; ++dp) {
                    int c0 = io * 64 + (2 * dp) * 8 + h;
                    int c1 = io * 64 + (2 * dp + 1) * 8 + h;
                    wv[dp] = (unsigned int)s_v[rr * 130 + c0]
                           | ((unsigned int)s_v[rr * 130 + c1] << 16);
                }
                u4.x = wv[0]; u4.y = wv[1]; u4.z = wv[2]; u4.w = wv[3];
                if (io == 0) {
                    *(uint4*)(VtIn + ((size_t)((b * 8 + h) * N_ + r2)) * 3072 + (size_t)r1 * 8) = u4;
                } else {
                    *(uint4*)(VtOut + ((size_t)((b * 8 + h) * N_ + r1)) * 3072 + (size_t)r2 * 8) = u4;
                }
            }
        }
    }
    {
        const int rr = t >> 2, cq = (t & 3) * 4;
        const int r1 = i0 + (rr >> 2);
        const int r2 = j0 + (rr & 3);
        const float maskv = mask[(size_t)(b * N_ + r1) * N_ + r2];
        float4 v0, v1;
        float tmp0[4], tmp1[4];
        #pragma unroll
        for (int u = 0; u < 4; ++u) {
            int c2 = cq + u;
            float x = s_eg[rr * 33 + c2] + b_EG[c2] + maskv;
            if (c2 >= 8) x = 1.f / (1.f + expf(-x));
            tmp0[u] = x;
            int c3 = 16 + cq + u;
            float y = s_eg[rr * 33 + c3] + b_EG[c3] + maskv;
            if ((cq + u) >= 8) y = 1.f / (1.f + expf(-y));
            tmp1[u] = y;
        }
        v0.x = tmp0[0]; v0.y = tmp0[1]; v0.z = tmp0[2]; v0.w = tmp0[3];
        v1.x = tmp1[0]; v1.y = tmp1[1]; v1.z = tmp1[2]; v1.w = tmp1[3];
        *(float4*)(EGin   + ((size_t)((b * N_ + r1) * N_ + r2)) * 16 + cq) = v0;
        *(float4*)(EGoutT + ((size_t)((b * N_ + r2) * N_ + r1)) * 16 + cq) = v1;
    }
}

// ---------------------------------------------------------------------------
// Kernel 2m: merged softmax over k for EGin and EGoutT (transpose role gone).
// ---------------------------------------------------------------------------
__global__ __launch_bounds__(256) void k2m(
    const float* __restrict__ EGin, const float* __restrict__ EGoutT,
    unsigned short* __restrict__ A_in, unsigned short* __restrict__ A_outT)
{
    __shared__ float s[384 * 17];
    const int t = threadIdx.x;
    const int bid = blockIdx.x;
    const float* EG = (bid < 768) ? EGin : EGoutT;
    unsigned short* A = (bid < 768) ? A_in : A_outT;
    const int b2 = (bid < 768) ? bid : bid - 768;
    const int i = b2 % N_, b = b2 / N_;
    const float* base = EG + ((size_t)(b * N_ + i) * N_) * 16;
    for (int x = t; x < 6144; x += 256) {
        int k = x >> 4, c = x & 15;
        s[k * 17 + c] = base[x];
    }
    __syncthreads();
    const int h = t >> 5, l = t & 31;
    float ev[12];
    float mx = -1e30f;
    #pragma unroll
    for (int j = 0; j < 12; ++j) {
        ev[j] = s[(l + 32 * j) * 17 + h];
        mx = fmaxf(mx, ev[j]);
    }
    #pragma unroll
    for (int off = 16; off >= 1; off >>= 1) mx = fmaxf(mx, __shfl_xor(mx, off));
    float sum = 0.f;
    #pragma unroll
    for (int j = 0; j < 12; ++j) { ev[j] = expf(ev[j] - mx); sum += ev[j]; }
    #pragma unroll
    for (int off = 16; off >= 1; off >>= 1) sum += __shfl_xor(sum, off);
    const float inv = 1.f / sum;
    unsigned short* arow = A + ((size_t)((b * 8 + h) * N_ + i)) * N_;
    #pragma unroll
    for (int j = 0; j < 12; ++j) {
        int k = l + 32 * j;
        arow[k] = f2bf(ev[j] * inv * s[k * 17 + 8 + h]);
    }
}

// ---------------------------------------------------------------------------
// Kernel 3: batched MFMA GEMM. A staged via gload16 (verified path). B now
// consumed DIRECTLY from Vt [plane][k][jd] with in-LDS transpose:
//   LDS slot(jd,k) = jd*72 + ((k>>3) ^ ((jd>>3)&7))*8 + (k&7)   (shorts)
// Row stride 144 B (16-aligned) + chunk-XOR => balanced banks on both the
// scalar scatter-writes and the ds_read_b128 fragment reads.
// ---------------------------------------------------------------------------
__global__ __launch_bounds__(256) void k3_mfma(
    const unsigned short* __restrict__ Aall,   // [32][384][384]
    const unsigned short* __restrict__ Vtall,  // [32][384][3072]  (k-major!)
    unsigned short* __restrict__ C)            // [32][384][3072]
{
    __shared__ __align__(16) short sAB[17408];   // sA [128][64] (8192) + sB [128][72] (9216)
    short* sA = sAB;
    unsigned short* sB = (unsigned short*)(sAB + 8192);

    const int t = threadIdx.x;
    const int n0 = blockIdx.x * 128;
    const int i0 = blockIdx.y * 128;
    const int z  = blockIdx.z;

    const unsigned short* Ap = Aall + (size_t)z * 147456;
    const unsigned short* Bp = Vtall + (size_t)z * 1179648;

    const int l = t & 63;
    const int w = t >> 6;
    const int wr = w >> 1, wc = w & 1;
    const int l15 = l & 15, lq = l >> 4;
    const int srow = l >> 3, schunk = (l & 7) ^ (l >> 3);

    f32x4 acc[4][4];
    #pragma unroll
    for (int mi = 0; mi < 4; ++mi)
        #pragma unroll
        for (int ni = 0; ni < 4; ++ni) acc[mi][ni] = (f32x4){0.f, 0.f, 0.f, 0.f};

    #pragma unroll 1
    for (int kt = 0; kt < 6; ++kt) {
        const int k0 = kt * 64;
        // A: async gload16, linear dest + pre-swizzled source (verified)
        #pragma unroll
        for (int i = 0; i < 4; ++i) {
            int rbase = w * 32 + i * 8;
            gload16(Ap + (size_t)(i0 + rbase + srow) * 384 + k0 + schunk * 8,
                    (char*)sA + rbase * 128);
        }
        // B: reg-stage 64k x 128jd from Vt[k][jd], scatter-transpose into sB
        #pragma unroll
        for (int rep = 0; rep < 4; ++rep) {
            int flat = rep * 256 + t;          // 0..1023
            int kk = flat >> 4;                // 0..63
            int o  = flat & 15;                // jd-oct
            uint4 v = *(const uint4*)(Bp + (size_t)(k0 + kk) * 3072 + n0 + o * 8);
            int cc = ((kk >> 3) ^ o) & 7;
            int base = (o * 8) * 72 + cc * 8 + (kk & 7);
            sB[base]       = (unsigned short)(v.x);
            sB[base + 72]  = (unsigned short)(v.x >> 16);
            sB[base + 144] = (unsigned short)(v.y);
            sB[base + 216] = (unsigned short)(v.y >> 16);
            sB[base + 288] = (unsigned short)(v.z);
            sB[base + 360] = (unsigned short)(v.z >> 16);
            sB[base + 432] = (unsigned short)(v.w);
            sB[base + 504] = (unsigned short)(v.w >> 16);
        }
        __syncthreads();

        bf16x8 av[4][2], bv[4][2];
        #pragma unroll
        for (int mi = 0; mi < 4; ++mi) {
            int row = wr * 64 + mi * 16 + l15;
            #pragma unroll
            for (int ks = 0; ks < 2; ++ks) {
                int kc = ks * 4 + lq;
                av[mi][ks] = *(const bf16x8*)((const char*)sA + row * 128 + ((kc ^ (row & 7)) << 4));
            }
        }
        #pragma unroll
        for (int ni = 0; ni < 4; ++ni) {
            int jd = wc * 64 + ni * 16 + l15;
            #pragma unroll
            for (int ks = 0; ks < 2; ++ks) {
                int c = ks * 4 + lq;
                int cc = (c ^ ((jd >> 3) & 7)) & 7;
                bv[ni][ks] = *(const bf16x8*)((const char*)sB + (jd * 72 + cc * 8) * 2);
            }
        }
        #pragma unroll
        for (int mi = 0; mi < 4; ++mi)
            #pragma unroll
            for (int ni = 0; ni < 4; ++ni) {
                acc[mi][ni] = __builtin_amdgcn_mfma_f32_16x16x32_bf16(av[mi][0], bv[ni][0], acc[mi][ni], 0, 0, 0);
                acc[mi][ni] = __builtin_amdgcn_mfma_f32_16x16x32_bf16(av[mi][1], bv[ni][1], acc[mi][ni], 0, 0, 0);
            }
        __syncthreads();
    }

    unsigned short* Cp = C + (size_t)z * 1179648;
    #pragma unroll
    for (int mi = 0; mi < 4; ++mi) {
        #pragma unroll
        for (int qq = 0; qq < 4; ++qq) {
            int row = i0 + wr * 64 + mi * 16 + lq * 4 + qq;
            unsigned short* crow = Cp + (size_t)row * 3072 + n0 + wc * 64 + l15;
            #pragma unroll
            for (int ni = 0; ni < 4; ++ni) crow[ni * 16] = f2bf(acc[mi][ni][qq]);
        }
    }
}

// ---------------------------------------------------------------------------
// Kernel 4: out = b_O + C(gathered) @ W_O (round-11-verified verbatim).
// ---------------------------------------------------------------------------
__global__ __launch_bounds__(256) void k4_proj(
    const unsigned short* __restrict__ C, const float* __restrict__ W_O,
    const float* __restrict__ b_O, float* __restrict__ out)
{
    __shared__ float s_w[8192];
    __shared__ unsigned short s_c[20480];
    const int t = threadIdx.x;
    const int jt = blockIdx.x;
    const int i  = blockIdx.y;
    const int b  = blockIdx.z;

    for (int x = t; x < 8192; x += 256) s_w[x] = W_O[x];
    {
        unsigned int* s_c32 = (unsigned int*)s_c;
        #pragma unroll
        for (int rep = 0; rep < 8; ++rep) {
            int flat = rep * 256 + t;
            int p = flat >> 7, jj = flat & 127;
            int plane = b * 8 + (p & 7) + (p >> 3) * 16;
            uint4 v = *(const uint4*)(C + (size_t)plane * 1179648 + (size_t)i * 3072 + jt * 1024 + jj * 8);
            int base = p * 640 + jj * 5;
            s_c32[base] = v.x; s_c32[base + 1] = v.y; s_c32[base + 2] = v.z; s_c32[base + 3] = v.w;
        }
    }
    __syncthreads();

    const int jg = t & 63, cg = t >> 6;
    const int chb = cg * 16;
    float acc0[16], acc1[16];
    #pragma unroll
    for (int u = 0; u < 16; ++u) { float bb = b_O[chb + u]; acc0[u] = bb; acc1[u] = bb; }

    #pragma unroll 4
    for (int c = 0; c < 128; ++c) {
        const int p = c & 15, d = c >> 4;
        const int sbase = p * 1280 + (jg * 2) * 10 + d;
        float v0 = bf2f((unsigned int)s_c[sbase]);
        float v1 = bf2f((unsigned int)s_c[sbase + 10]);
        const float* wrp = s_w + c * 64 + chb;
        #pragma unroll
        for (int u4 = 0; u4 < 4; ++u4) {
            float4 wv = *(const float4*)(wrp + u4 * 4);
            acc0[u4*4+0] += v0 * wv.x; acc0[u4*4+1] += v0 * wv.y;
            acc0[u4*4+2] += v0 * wv.z; acc0[u4*4+3] += v0 * wv.w;
            acc1[u4*4+0] += v1 * wv.x; acc1[u4*4+1] += v1 * wv.y;
            acc1[u4*4+2] += v1 * wv.z; acc1[u4*4+3] += v1 * wv.w;
        }
    }
    float* o0 = out + ((size_t)(b * N_ + i) * N_ + jt * 128 + jg * 2) * 64 + chb;
    #pragma unroll
    for (int u4 = 0; u4 < 4; ++u4) {
        float4 a; a.x = acc0[u4*4]; a.y = acc0[u4*4+1]; a.z = acc0[u4*4+2]; a.w = acc0[u4*4+3];
        *(float4*)(o0 + u4 * 4) = a;
        float4 c4; c4.x = acc1[u4*4]; c4.y = acc1[u4*4+1]; c4.z = acc1[u4*4+2]; c4.w = acc1[u4*4+3];
        *(float4*)(o0 + 64 + u4 * 4) = c4;
    }
}

// ---------------------------------------------------------------------------
extern "C" void kernel_launch(void* const* d_in, const int* in_sizes, int n_in,
                              void* d_out, int out_size, void* d_ws, size_t ws_size,
                              hipStream_t stream)
{
    const float* e    = (const float*)d_in[0];
    const float* mask = (const float*)d_in[1];
    const float* ln_w = (const float*)d_in[2];
    const float* ln_b = (const float*)d_in[3];
    const float* W_V  = (const float*)d_in[4];
    const float* b_V  = (const float*)d_in[5];
    const float* W_EG = (const float*)d_in[6];
    const float* b_EG = (const float*)d_in[7];
    const float* W_O  = (const float*)d_in[8];
    const float* b_O  = (const float*)d_in[9];
    float* out = (float*)d_out;

    char* ws = (char*)d_ws;
    unsigned short* VtIn   = (unsigned short*)(ws);               // [16][384][3072]  37,748,736
    unsigned short* VtOut  = (unsigned short*)(ws + 37748736);    // [16][384][3072]  37,748,736
    // VtIn+VtOut contiguous => Vt_all[32][384][3072], live through k3.
    unsigned short* A_in   = (unsigned short*)(ws + 75497472);    //  4,718,592
    unsigned short* A_outT = (unsigned short*)(ws + 80216064);    //  4,718,592 (contiguous after A_in)
    float* EGin   = (float*)(ws + 84934656);                      // 18,874,368 (dead after k2m)
    float* EGoutT = (float*)(ws + 103809024);                     // 18,874,368 (dead after k2m)
    unsigned short* Cws    = (unsigned short*)(ws + 84934656);    // 75,497,472 (overlays EG; k3->k4)
    unsigned short* Whi = A_in;                                   // k0->k1 transient
    unsigned short* Wlo = A_in + 10240;

    hipLaunchKernelGGL(k0_prep, dim3(40), dim3(256), 0, stream, W_V, W_EG, Whi, Wlo);
    hipLaunchKernelGGL(k1_ln_proj, dim3(96, 24, 2), dim3(256), 0, stream,
                       e, mask, ln_w, ln_b, Whi, Wlo, b_V, b_EG, VtIn, VtOut, EGin, EGoutT);
    hipLaunchKernelGGL(k2m, dim3(1536), dim3(256), 0, stream,
                       EGin, EGoutT, A_in, A_outT);
    hipLaunchKernelGGL(k3_mfma, dim3(24, 3, 32), dim3(256), 0, stream,
                       A_in, VtIn, Cws);
    hipLaunchKernelGGL(k4_proj, dim3(3, 384, 2), dim3(256), 0, stream,
                       Cws, W_O, b_O, out);
}

// Round 18
// 215.296 us; speedup vs baseline: 1.7486x; 1.1172x over previous
//
#include <hip/hip_runtime.h>

#define N_ 384
#define LNEPS 1e-5f

typedef __attribute__((ext_vector_type(8))) short bf16x8;
typedef __attribute__((ext_vector_type(4))) float f32x4;

__device__ __forceinline__ float bf2f(unsigned int u) {
    union { unsigned int i; float f; } v; v.i = u << 16; return v.f;
}
__device__ __forceinline__ unsigned short f2bf(float f) {
    union { float f; unsigned int i; } v; v.f = f;
    return (unsigned short)((v.i + 0x7FFFu + ((v.i >> 16) & 1u)) >> 16);
}
__device__ __forceinline__ void gload16(const void* g, void* l) {
    __builtin_amdgcn_global_load_lds(
        (const __attribute__((address_space(1))) void*)g,
        (__attribute__((address_space(3))) void*)l, 16, 0, 0);
}

// ---------------------------------------------------------------------------
// Kernel 0: bf16 hi/lo for projection weights [col][k] AND transposed W_O
// [cout][c] (c = d*16 + io*8 + h, the verified channel order).
// ---------------------------------------------------------------------------
__global__ __launch_bounds__(256) void k0_prep(
    const float* __restrict__ W_V, const float* __restrict__ W_EG,
    const float* __restrict__ W_O,
    unsigned short* __restrict__ Whi, unsigned short* __restrict__ Wlo,
    unsigned short* __restrict__ WoHi, unsigned short* __restrict__ WoLo)
{
    int x = blockIdx.x * 256 + threadIdx.x;
    if (x < 10240) {
        int col = x >> 6, k = x & 63;
        float wv = (col < 128) ? W_V[k * 128 + col] : W_EG[k * 32 + (col - 128)];
        unsigned short hi = f2bf(wv);
        Whi[x] = hi;
        Wlo[x] = f2bf(wv - bf2f(hi));
    } else if (x < 18432) {
        int y = x - 10240;
        int cout = y >> 7, c = y & 127;
        float wv = W_O[c * 64 + cout];
        unsigned short hi = f2bf(wv);
        WoHi[y] = hi;
        WoLo[y] = f2bf(wv - bf2f(hi));
    }
}

// ---------------------------------------------------------------------------
// Kernel 1: LN + V/EG projections (round-16/17-verified VERBATIM).
// ---------------------------------------------------------------------------
__global__ __launch_bounds__(256) void k1_ln_proj(
    const float* __restrict__ e, const float* __restrict__ mask,
    const float* __restrict__ ln_w, const float* __restrict__ ln_b,
    const unsigned short* __restrict__ Whi_g, const unsigned short* __restrict__ Wlo_g,
    const float* __restrict__ b_V, const float* __restrict__ b_EG,
    unsigned short* __restrict__ VtIn, unsigned short* __restrict__ VtOut,
    float* __restrict__ EGin, float* __restrict__ EGoutT)
{
    __shared__ __align__(16) char smem[25088];
    unsigned short* s_v = (unsigned short*)smem;
    float* s_eg = (float*)(smem + 16640);

    const int t = threadIdx.x;
    const int j0 = blockIdx.x * 4;
    const int i0 = blockIdx.y * 16;
    const int b  = blockIdx.z;

    const int l = t & 63, w = t >> 6;
    const int l15 = l & 15, lq = l >> 4;

    const int r = w * 16 + l15;
    const int r1f = i0 + (r >> 2), r2f = j0 + (r & 3);
    const float* erow = e + ((size_t)((b * N_ + r1f) * N_ + r2f)) * 64;
    float ev[16];
    {
        float4 e0 = *(const float4*)(erow + lq * 8);
        float4 e1 = *(const float4*)(erow + lq * 8 + 4);
        float4 e2 = *(const float4*)(erow + 32 + lq * 8);
        float4 e3 = *(const float4*)(erow + 32 + lq * 8 + 4);
        ev[0]=e0.x; ev[1]=e0.y; ev[2]=e0.z;  ev[3]=e0.w;
        ev[4]=e1.x; ev[5]=e1.y; ev[6]=e1.z;  ev[7]=e1.w;
        ev[8]=e2.x; ev[9]=e2.y; ev[10]=e2.z; ev[11]=e2.w;
        ev[12]=e3.x; ev[13]=e3.y; ev[14]=e3.z; ev[15]=e3.w;
    }
    float s = 0.f, sq = 0.f;
    #pragma unroll
    for (int j = 0; j < 16; ++j) { s += ev[j]; sq += ev[j] * ev[j]; }
    s  += __shfl_xor(s, 16);  s  += __shfl_xor(s, 32);
    sq += __shfl_xor(sq, 16); sq += __shfl_xor(sq, 32);
    const float mean = s * (1.f / 64.f);
    const float rstd = rsqrtf(sq * (1.f / 64.f) - mean * mean + LNEPS);

    bf16x8 ahi[2], alo[2];
    {
        float lnwv[16], lnbv[16];
        float4 w0 = *(const float4*)(ln_w + lq * 8);
        float4 w1 = *(const float4*)(ln_w + lq * 8 + 4);
        float4 w2 = *(const float4*)(ln_w + 32 + lq * 8);
        float4 w3 = *(const float4*)(ln_w + 32 + lq * 8 + 4);
        lnwv[0]=w0.x; lnwv[1]=w0.y; lnwv[2]=w0.z;  lnwv[3]=w0.w;
        lnwv[4]=w1.x; lnwv[5]=w1.y; lnwv[6]=w1.z;  lnwv[7]=w1.w;
        lnwv[8]=w2.x; lnwv[9]=w2.y; lnwv[10]=w2.z; lnwv[11]=w2.w;
        lnwv[12]=w3.x; lnwv[13]=w3.y; lnwv[14]=w3.z; lnwv[15]=w3.w;
        float4 b0 = *(const float4*)(ln_b + lq * 8);
        float4 b1 = *(const float4*)(ln_b + lq * 8 + 4);
        float4 b2 = *(const float4*)(ln_b + 32 + lq * 8);
        float4 b3 = *(const float4*)(ln_b + 32 + lq * 8 + 4);
        lnbv[0]=b0.x; lnbv[1]=b0.y; lnbv[2]=b0.z;  lnbv[3]=b0.w;
        lnbv[4]=b1.x; lnbv[5]=b1.y; lnbv[6]=b1.z;  lnbv[7]=b1.w;
        lnbv[8]=b2.x; lnbv[9]=b2.y; lnbv[10]=b2.z; lnbv[11]=b2.w;
        lnbv[12]=b3.x; lnbv[13]=b3.y; lnbv[14]=b3.z; lnbv[15]=b3.w;
        #pragma unroll
        for (int ks = 0; ks < 2; ++ks) {
            #pragma unroll
            for (int j = 0; j < 8; ++j) {
                float x = (ev[ks * 8 + j] - mean) * rstd * lnwv[ks * 8 + j] + lnbv[ks * 8 + j];
                unsigned short h = f2bf(x);
                unsigned short lo = f2bf(x - bf2f(h));
                ahi[ks][j] = (short)h;
                alo[ks][j] = (short)lo;
            }
        }
    }

    f32x4 acc[10];
    #pragma unroll
    for (int n = 0; n < 10; ++n) acc[n] = (f32x4){0.f, 0.f, 0.f, 0.f};

    #pragma unroll
    for (int n = 0; n < 10; ++n) {
        int brow = n * 16 + l15;
        const unsigned short* wh = Whi_g + brow * 64;
        bf16x8 bh0 = *(const bf16x8*)(wh + lq * 8);
        bf16x8 bh1 = *(const bf16x8*)(wh + 32 + lq * 8);
        acc[n] = __builtin_amdgcn_mfma_f32_16x16x32_bf16(ahi[0], bh0, acc[n], 0, 0, 0);
        acc[n] = __builtin_amdgcn_mfma_f32_16x16x32_bf16(ahi[1], bh1, acc[n], 0, 0, 0);
        acc[n] = __builtin_amdgcn_mfma_f32_16x16x32_bf16(alo[0], bh0, acc[n], 0, 0, 0);
        acc[n] = __builtin_amdgcn_mfma_f32_16x16x32_bf16(alo[1], bh1, acc[n], 0, 0, 0);
        if (n >= 8) {
            const unsigned short* wl = Wlo_g + brow * 64;
            bf16x8 bl0 = *(const bf16x8*)(wl + lq * 8);
            bf16x8 bl1 = *(const bf16x8*)(wl + 32 + lq * 8);
            acc[n] = __builtin_amdgcn_mfma_f32_16x16x32_bf16(ahi[0], bl0, acc[n], 0, 0, 0);
            acc[n] = __builtin_amdgcn_mfma_f32_16x16x32_bf16(ahi[1], bl1, acc[n], 0, 0, 0);
        }
    }

    #pragma unroll
    for (int n = 0; n < 8; ++n) {
        float bb = b_V[n * 16 + l15];
        #pragma unroll
        for (int q = 0; q < 4; ++q)
            s_v[(w * 16 + lq * 4 + q) * 130 + n * 16 + l15] = f2bf(acc[n][q] + bb);
    }
    #pragma unroll
    for (int n = 8; n < 10; ++n) {
        #pragma unroll
        for (int q = 0; q < 4; ++q)
            s_eg[(w * 16 + lq * 4 + q) * 33 + (n - 8) * 16 + l15] = acc[n][q];
    }
    __syncthreads();

    {
        const int rr = t & 63, g = t >> 6;
        const int r1 = i0 + (rr >> 2);
        const int r2 = j0 + (rr & 3);
        #pragma unroll
        for (int io = 0; io < 2; ++io) {
            #pragma unroll
            for (int hs = 0; hs < 2; ++hs) {
                const int h = g + hs * 4;
                uint4 u4;
                unsigned int wv[4];
                #pragma unroll
                for (int dp = 0; dp < 4; ++dp) {
                    int c0 = io * 64 + (2 * dp) * 8 + h;
                    int c1 = io * 64 + (2 * dp + 1) * 8 + h;
                    wv[dp] = (unsigned int)s_v[rr * 130 + c0]
                           | ((unsigned int)s_v[rr * 130 + c1] << 16);
                }
                u4.x = wv[0]; u4.y = wv[1]; u4.z = wv[2]; u4.w = wv[3];
                if (io == 0) {
                    *(uint4*)(VtIn + ((size_t)((b * 8 + h) * N_ + r2)) * 3072 + (size_t)r1 * 8) = u4;
                } else {
                    *(uint4*)(VtOut + ((size_t)((b * 8 + h) * N_ + r1)) * 3072 + (size_t)r2 * 8) = u4;
                }
            }
        }
    }
    {
        const int rr = t >> 2, cq = (t & 3) * 4;
        const int r1 = i0 + (rr >> 2);
        const int r2 = j0 + (rr & 3);
        const float maskv = mask[(size_t)(b * N_ + r1) * N_ + r2];
        float4 v0, v1;
        float tmp0[4], tmp1[4];
        #pragma unroll
        for (int u = 0; u < 4; ++u) {
            int c2 = cq + u;
            float x = s_eg[rr * 33 + c2] + b_EG[c2] + maskv;
            if (c2 >= 8) x = 1.f / (1.f + expf(-x));
            tmp0[u] = x;
            int c3 = 16 + cq + u;
            float y = s_eg[rr * 33 + c3] + b_EG[c3] + maskv;
            if ((cq + u) >= 8) y = 1.f / (1.f + expf(-y));
            tmp1[u] = y;
        }
        v0.x = tmp0[0]; v0.y = tmp0[1]; v0.z = tmp0[2]; v0.w = tmp0[3];
        v1.x = tmp1[0]; v1.y = tmp1[1]; v1.z = tmp1[2]; v1.w = tmp1[3];
        *(float4*)(EGin   + ((size_t)((b * N_ + r1) * N_ + r2)) * 16 + cq) = v0;
        *(float4*)(EGoutT + ((size_t)((b * N_ + r2) * N_ + r1)) * 16 + cq) = v1;
    }
}

// ---------------------------------------------------------------------------
// Kernel 2m: merged softmax over k (round-17-verified verbatim).
// ---------------------------------------------------------------------------
__global__ __launch_bounds__(256) void k2m(
    const float* __restrict__ EGin, const float* __restrict__ EGoutT,
    unsigned short* __restrict__ A_in, unsigned short* __restrict__ A_outT)
{
    __shared__ float s[384 * 17];
    const int t = threadIdx.x;
    const int bid = blockIdx.x;
    const float* EG = (bid < 768) ? EGin : EGoutT;
    unsigned short* A = (bid < 768) ? A_in : A_outT;
    const int b2 = (bid < 768) ? bid : bid - 768;
    const int i = b2 % N_, b = b2 / N_;
    const float* base = EG + ((size_t)(b * N_ + i) * N_) * 16;
    for (int x = t; x < 6144; x += 256) {
        int k = x >> 4, c = x & 15;
        s[k * 17 + c] = base[x];
    }
    __syncthreads();
    const int h = t >> 5, l = t & 31;
    float ev[12];
    float mx = -1e30f;
    #pragma unroll
    for (int j = 0; j < 12; ++j) {
        ev[j] = s[(l + 32 * j) * 17 + h];
        mx = fmaxf(mx, ev[j]);
    }
    #pragma unroll
    for (int off = 16; off >= 1; off >>= 1) mx = fmaxf(mx, __shfl_xor(mx, off));
    float sum = 0.f;
    #pragma unroll
    for (int j = 0; j < 12; ++j) { ev[j] = expf(ev[j] - mx); sum += ev[j]; }
    #pragma unroll
    for (int off = 16; off >= 1; off >>= 1) sum += __shfl_xor(sum, off);
    const float inv = 1.f / sum;
    unsigned short* arow = A + ((size_t)((b * 8 + h) * N_ + i)) * N_;
    #pragma unroll
    for (int j = 0; j < 12; ++j) {
        int k = l + 32 * j;
        arow[k] = f2bf(ev[j] * inv * s[k * 17 + 8 + h]);
    }
}

// ---------------------------------------------------------------------------
// Kernel 3: batched MFMA GEMM (round-17-verified body). CHANGE: 1-D grid with
// bijective XCD swizzle — each XCD gets 4 whole planes for L2 locality.
// ---------------------------------------------------------------------------
__global__ __launch_bounds__(256) void k3_mfma(
    const unsigned short* __restrict__ Aall,   // [32][384][384]
    const unsigned short* __restrict__ Vtall,  // [32][384][3072]  (k-major)
    unsigned short* __restrict__ C)            // [32][384][3072]
{
    __shared__ __align__(16) short sAB[17408];   // sA [128][64] + sB [128][72]
    short* sA = sAB;
    unsigned short* sB = (unsigned short*)(sAB + 8192);

    const int t = threadIdx.x;
    const int flat = blockIdx.x;                 // 0..2303
    const int swz = (flat & 7) * 288 + (flat >> 3);
    const int z  = swz / 72;
    const int rem = swz % 72;
    const int i0 = (rem / 24) * 128;
    const int n0 = (rem % 24) * 128;

    const unsigned short* Ap = Aall + (size_t)z * 147456;
    const unsigned short* Bp = Vtall + (size_t)z * 1179648;

    const int l = t & 63;
    const int w = t >> 6;
    const int wr = w >> 1, wc = w & 1;
    const int l15 = l & 15, lq = l >> 4;
    const int srow = l >> 3, schunk = (l & 7) ^ (l >> 3);

    f32x4 acc[4][4];
    #pragma unroll
    for (int mi = 0; mi < 4; ++mi)
        #pragma unroll
        for (int ni = 0; ni < 4; ++ni) acc[mi][ni] = (f32x4){0.f, 0.f, 0.f, 0.f};

    #pragma unroll 1
    for (int kt = 0; kt < 6; ++kt) {
        const int k0 = kt * 64;
        #pragma unroll
        for (int i = 0; i < 4; ++i) {
            int rbase = w * 32 + i * 8;
            gload16(Ap + (size_t)(i0 + rbase + srow) * 384 + k0 + schunk * 8,
                    (char*)sA + rbase * 128);
        }
        #pragma unroll
        for (int rep = 0; rep < 4; ++rep) {
            int flat2 = rep * 256 + t;
            int kk = flat2 >> 4;
            int o  = flat2 & 15;
            uint4 v = *(const uint4*)(Bp + (size_t)(k0 + kk) * 3072 + n0 + o * 8);
            int cc = ((kk >> 3) ^ o) & 7;
            int base = (o * 8) * 72 + cc * 8 + (kk & 7);
            sB[base]       = (unsigned short)(v.x);
            sB[base + 72]  = (unsigned short)(v.x >> 16);
            sB[base + 144] = (unsigned short)(v.y);
            sB[base + 216] = (unsigned short)(v.y >> 16);
            sB[base + 288] = (unsigned short)(v.z);
            sB[base + 360] = (unsigned short)(v.z >> 16);
            sB[base + 432] = (unsigned short)(v.w);
            sB[base + 504] = (unsigned short)(v.w >> 16);
        }
        __syncthreads();

        bf16x8 av[4][2], bv[4][2];
        #pragma unroll
        for (int mi = 0; mi < 4; ++mi) {
            int row = wr * 64 + mi * 16 + l15;
            #pragma unroll
            for (int ks = 0; ks < 2; ++ks) {
                int kc = ks * 4 + lq;
                av[mi][ks] = *(const bf16x8*)((const char*)sA + row * 128 + ((kc ^ (row & 7)) << 4));
            }
        }
        #pragma unroll
        for (int ni = 0; ni < 4; ++ni) {
            int jd = wc * 64 + ni * 16 + l15;
            #pragma unroll
            for (int ks = 0; ks < 2; ++ks) {
                int c = ks * 4 + lq;
                int cc = (c ^ ((jd >> 3) & 7)) & 7;
                bv[ni][ks] = *(const bf16x8*)((const char*)sB + (jd * 72 + cc * 8) * 2);
            }
        }
        #pragma unroll
        for (int mi = 0; mi < 4; ++mi)
            #pragma unroll
            for (int ni = 0; ni < 4; ++ni) {
                acc[mi][ni] = __builtin_amdgcn_mfma_f32_16x16x32_bf16(av[mi][0], bv[ni][0], acc[mi][ni], 0, 0, 0);
                acc[mi][ni] = __builtin_amdgcn_mfma_f32_16x16x32_bf16(av[mi][1], bv[ni][1], acc[mi][ni], 0, 0, 0);
            }
        __syncthreads();
    }

    unsigned short* Cp = C + (size_t)z * 1179648;
    #pragma unroll
    for (int mi = 0; mi < 4; ++mi) {
        #pragma unroll
        for (int qq = 0; qq < 4; ++qq) {
            int row = i0 + wr * 64 + mi * 16 + lq * 4 + qq;
            unsigned short* crow = Cp + (size_t)row * 3072 + n0 + wc * 64 + l15;
            #pragma unroll
            for (int ni = 0; ni < 4; ++ni) crow[ni * 16] = f2bf(acc[mi][ni][qq]);
        }
    }
}

// ---------------------------------------------------------------------------
// Kernel 4: out = b_O + Va @ W_O via MFMA. Gather stages C transposed into
// s_ct[128 j][136 c] (c = d*16+p, verified order); W_O^T bf16 hi/lo from k0.
// ---------------------------------------------------------------------------
__global__ __launch_bounds__(256) void k4_proj(
    const unsigned short* __restrict__ C,
    const unsigned short* __restrict__ WoHi, const unsigned short* __restrict__ WoLo,
    const float* __restrict__ b_O, float* __restrict__ out)
{
    __shared__ __align__(16) unsigned short s_ct[128 * 136];   // 34,816 B
    const int t = threadIdx.x;
    const int jt = blockIdx.x;
    const int i  = blockIdx.y;
    const int b  = blockIdx.z;

    #pragma unroll
    for (int rep = 0; rep < 8; ++rep) {
        int flat = rep * 256 + t;
        int p = flat >> 7, jj = flat & 127;
        int plane = b * 8 + (p & 7) + (p >> 3) * 16;
        uint4 v = *(const uint4*)(C + (size_t)plane * 1179648 + (size_t)i * 3072 + jt * 1024 + jj * 8);
        unsigned short* dst = s_ct + jj * 136 + p;
        dst[0]   = (unsigned short)(v.x);
        dst[16]  = (unsigned short)(v.x >> 16);
        dst[32]  = (unsigned short)(v.y);
        dst[48]  = (unsigned short)(v.y >> 16);
        dst[64]  = (unsigned short)(v.z);
        dst[80]  = (unsigned short)(v.z >> 16);
        dst[96]  = (unsigned short)(v.w);
        dst[112] = (unsigned short)(v.w >> 16);
    }
    __syncthreads();

    const int l = t & 63, w = t >> 6;
    const int l15 = l & 15, lq = l >> 4;

    f32x4 acc[2][4];
    #pragma unroll
    for (int m = 0; m < 2; ++m)
        #pragma unroll
        for (int nt = 0; nt < 4; ++nt) {
            float bb = b_O[nt * 16 + l15];
            acc[m][nt] = (f32x4){bb, bb, bb, bb};
        }

    #pragma unroll
    for (int ks = 0; ks < 4; ++ks) {
        bf16x8 av0 = *(const bf16x8*)(s_ct + (w * 32 + l15) * 136 + ks * 32 + lq * 8);
        bf16x8 av1 = *(const bf16x8*)(s_ct + (w * 32 + 16 + l15) * 136 + ks * 32 + lq * 8);
        #pragma unroll
        for (int nt = 0; nt < 4; ++nt) {
            bf16x8 bh = *(const bf16x8*)(WoHi + (nt * 16 + l15) * 128 + ks * 32 + lq * 8);
            bf16x8 bl = *(const bf16x8*)(WoLo + (nt * 16 + l15) * 128 + ks * 32 + lq * 8);
            acc[0][nt] = __builtin_amdgcn_mfma_f32_16x16x32_bf16(av0, bh, acc[0][nt], 0, 0, 0);
            acc[0][nt] = __builtin_amdgcn_mfma_f32_16x16x32_bf16(av0, bl, acc[0][nt], 0, 0, 0);
            acc[1][nt] = __builtin_amdgcn_mfma_f32_16x16x32_bf16(av1, bh, acc[1][nt], 0, 0, 0);
            acc[1][nt] = __builtin_amdgcn_mfma_f32_16x16x32_bf16(av1, bl, acc[1][nt], 0, 0, 0);
        }
    }

    // D layout (verified): row = lq*4+q (j), col = l15 (cout within nt-tile)
    #pragma unroll
    for (int m = 0; m < 2; ++m) {
        #pragma unroll
        for (int q = 0; q < 4; ++q) {
            int j = w * 32 + m * 16 + lq * 4 + q;
            float* orow = out + ((size_t)(b * N_ + i) * N_ + jt * 128 + j) * 64 + l15;
            orow[0]  = acc[m][0][q];
            orow[16] = acc[m][1][q];
            orow[32] = acc[m][2][q];
            orow[48] = acc[m][3][q];
        }
    }
}

// ---------------------------------------------------------------------------
extern "C" void kernel_launch(void* const* d_in, const int* in_sizes, int n_in,
                              void* d_out, int out_size, void* d_ws, size_t ws_size,
                              hipStream_t stream)
{
    const float* e    = (const float*)d_in[0];
    const float* mask = (const float*)d_in[1];
    const float* ln_w = (const float*)d_in[2];
    const float* ln_b = (const float*)d_in[3];
    const float* W_V  = (const float*)d_in[4];
    const float* b_V  = (const float*)d_in[5];
    const float* W_EG = (const float*)d_in[6];
    const float* b_EG = (const float*)d_in[7];
    const float* W_O  = (const float*)d_in[8];
    const float* b_O  = (const float*)d_in[9];
    float* out = (float*)d_out;

    char* ws = (char*)d_ws;
    unsigned short* VtIn   = (unsigned short*)(ws);               // 37,748,736
    unsigned short* VtOut  = (unsigned short*)(ws + 37748736);    // 37,748,736
    unsigned short* A_in   = (unsigned short*)(ws + 75497472);    //  4,718,592
    unsigned short* A_outT = (unsigned short*)(ws + 80216064);    //  4,718,592
    float* EGin   = (float*)(ws + 84934656);                      // 18,874,368 (dead after k2m)
    float* EGoutT = (float*)(ws + 103809024);                     // 18,874,368 (dead after k2m)
    unsigned short* Cws    = (unsigned short*)(ws + 84934656);    // 75,497,472 (overlays EG)
    unsigned short* Whi = A_in;                                   // k0->k1 transient
    unsigned short* Wlo = A_in + 10240;
    unsigned short* WoHi = (unsigned short*)(ws + 160432128);     // 16,384 B (live to k4)
    unsigned short* WoLo = (unsigned short*)(ws + 160448512);     // 16,384 B

    hipLaunchKernelGGL(k0_prep, dim3(72), dim3(256), 0, stream,
                       W_V, W_EG, W_O, Whi, Wlo, WoHi, WoLo);
    hipLaunchKernelGGL(k1_ln_proj, dim3(96, 24, 2), dim3(256), 0, stream,
                       e, mask, ln_w, ln_b, Whi, Wlo, b_V, b_EG, VtIn, VtOut, EGin, EGoutT);
    hipLaunchKernelGGL(k2m, dim3(1536), dim3(256), 0, stream,
                       EGin, EGoutT, A_in, A_outT);
    hipLaunchKernelGGL(k3_mfma, dim3(2304), dim3(256), 0, stream,
                       A_in, VtIn, Cws);
    hipLaunchKernelGGL(k4_proj, dim3(3, 384, 2), dim3(256), 0, stream,
                       Cws, WoHi, WoLo, b_O, out);
}

// Round 19
// 205.849 us; speedup vs baseline: 1.8289x; 1.0459x over previous
//
#include <hip/hip_runtime.h>

#define N_ 384
#define LNEPS 1e-5f

typedef __attribute__((ext_vector_type(8))) short bf16x8;
typedef __attribute__((ext_vector_type(4))) float f32x4;

__device__ __forceinline__ float bf2f(unsigned int u) {
    union { unsigned int i; float f; } v; v.i = u << 16; return v.f;
}
__device__ __forceinline__ unsigned short f2bf(float f) {
    union { float f; unsigned int i; } v; v.f = f;
    return (unsigned short)((v.i + 0x7FFFu + ((v.i >> 16) & 1u)) >> 16);
}
__device__ __forceinline__ void gload16(const void* g, void* l) {
    __builtin_amdgcn_global_load_lds(
        (const __attribute__((address_space(1))) void*)g,
        (__attribute__((address_space(3))) void*)l, 16, 0, 0);
}

// ---------------------------------------------------------------------------
// Kernel 0: bf16 hi/lo for projection weights [col][k] AND transposed W_O.
// ---------------------------------------------------------------------------
__global__ __launch_bounds__(256) void k0_prep(
    const float* __restrict__ W_V, const float* __restrict__ W_EG,
    const float* __restrict__ W_O,
    unsigned short* __restrict__ Whi, unsigned short* __restrict__ Wlo,
    unsigned short* __restrict__ WoHi, unsigned short* __restrict__ WoLo)
{
    int x = blockIdx.x * 256 + threadIdx.x;
    if (x < 10240) {
        int col = x >> 6, k = x & 63;
        float wv = (col < 128) ? W_V[k * 128 + col] : W_EG[k * 32 + (col - 128)];
        unsigned short hi = f2bf(wv);
        Whi[x] = hi;
        Wlo[x] = f2bf(wv - bf2f(hi));
    } else if (x < 18432) {
        int y = x - 10240;
        int cout = y >> 7, c = y & 127;
        float wv = W_O[c * 64 + cout];
        unsigned short hi = f2bf(wv);
        WoHi[y] = hi;
        WoLo[y] = f2bf(wv - bf2f(hi));
    }
}

// ---------------------------------------------------------------------------
// Kernel 1: LN + V/EG projections (round-16/17/18-verified VERBATIM).
// ---------------------------------------------------------------------------
__global__ __launch_bounds__(256) void k1_ln_proj(
    const float* __restrict__ e, const float* __restrict__ mask,
    const float* __restrict__ ln_w, const float* __restrict__ ln_b,
    const unsigned short* __restrict__ Whi_g, const unsigned short* __restrict__ Wlo_g,
    const float* __restrict__ b_V, const float* __restrict__ b_EG,
    unsigned short* __restrict__ VtIn, unsigned short* __restrict__ VtOut,
    float* __restrict__ EGin, float* __restrict__ EGoutT)
{
    __shared__ __align__(16) char smem[25088];
    unsigned short* s_v = (unsigned short*)smem;
    float* s_eg = (float*)(smem + 16640);

    const int t = threadIdx.x;
    const int j0 = blockIdx.x * 4;
    const int i0 = blockIdx.y * 16;
    const int b  = blockIdx.z;

    const int l = t & 63, w = t >> 6;
    const int l15 = l & 15, lq = l >> 4;

    const int r = w * 16 + l15;
    const int r1f = i0 + (r >> 2), r2f = j0 + (r & 3);
    const float* erow = e + ((size_t)((b * N_ + r1f) * N_ + r2f)) * 64;
    float ev[16];
    {
        float4 e0 = *(const float4*)(erow + lq * 8);
        float4 e1 = *(const float4*)(erow + lq * 8 + 4);
        float4 e2 = *(const float4*)(erow + 32 + lq * 8);
        float4 e3 = *(const float4*)(erow + 32 + lq * 8 + 4);
        ev[0]=e0.x; ev[1]=e0.y; ev[2]=e0.z;  ev[3]=e0.w;
        ev[4]=e1.x; ev[5]=e1.y; ev[6]=e1.z;  ev[7]=e1.w;
        ev[8]=e2.x; ev[9]=e2.y; ev[10]=e2.z; ev[11]=e2.w;
        ev[12]=e3.x; ev[13]=e3.y; ev[14]=e3.z; ev[15]=e3.w;
    }
    float s = 0.f, sq = 0.f;
    #pragma unroll
    for (int j = 0; j < 16; ++j) { s += ev[j]; sq += ev[j] * ev[j]; }
    s  += __shfl_xor(s, 16);  s  += __shfl_xor(s, 32);
    sq += __shfl_xor(sq, 16); sq += __shfl_xor(sq, 32);
    const float mean = s * (1.f / 64.f);
    const float rstd = rsqrtf(sq * (1.f / 64.f) - mean * mean + LNEPS);

    bf16x8 ahi[2], alo[2];
    {
        float lnwv[16], lnbv[16];
        float4 w0 = *(const float4*)(ln_w + lq * 8);
        float4 w1 = *(const float4*)(ln_w + lq * 8 + 4);
        float4 w2 = *(const float4*)(ln_w + 32 + lq * 8);
        float4 w3 = *(const float4*)(ln_w + 32 + lq * 8 + 4);
        lnwv[0]=w0.x; lnwv[1]=w0.y; lnwv[2]=w0.z;  lnwv[3]=w0.w;
        lnwv[4]=w1.x; lnwv[5]=w1.y; lnwv[6]=w1.z;  lnwv[7]=w1.w;
        lnwv[8]=w2.x; lnwv[9]=w2.y; lnwv[10]=w2.z; lnwv[11]=w2.w;
        lnwv[12]=w3.x; lnwv[13]=w3.y; lnwv[14]=w3.z; lnwv[15]=w3.w;
        float4 b0 = *(const float4*)(ln_b + lq * 8);
        float4 b1 = *(const float4*)(ln_b + lq * 8 + 4);
        float4 b2 = *(const float4*)(ln_b + 32 + lq * 8);
        float4 b3 = *(const float4*)(ln_b + 32 + lq * 8 + 4);
        lnbv[0]=b0.x; lnbv[1]=b0.y; lnbv[2]=b0.z;  lnbv[3]=b0.w;
        lnbv[4]=b1.x; lnbv[5]=b1.y; lnbv[6]=b1.z;  lnbv[7]=b1.w;
        lnbv[8]=b2.x; lnbv[9]=b2.y; lnbv[10]=b2.z; lnbv[11]=b2.w;
        lnbv[12]=b3.x; lnbv[13]=b3.y; lnbv[14]=b3.z; lnbv[15]=b3.w;
        #pragma unroll
        for (int ks = 0; ks < 2; ++ks) {
            #pragma unroll
            for (int j = 0; j < 8; ++j) {
                float x = (ev[ks * 8 + j] - mean) * rstd * lnwv[ks * 8 + j] + lnbv[ks * 8 + j];
                unsigned short h = f2bf(x);
                unsigned short lo = f2bf(x - bf2f(h));
                ahi[ks][j] = (short)h;
                alo[ks][j] = (short)lo;
            }
        }
    }

    f32x4 acc[10];
    #pragma unroll
    for (int n = 0; n < 10; ++n) acc[n] = (f32x4){0.f, 0.f, 0.f, 0.f};

    #pragma unroll
    for (int n = 0; n < 10; ++n) {
        int brow = n * 16 + l15;
        const unsigned short* wh = Whi_g + brow * 64;
        bf16x8 bh0 = *(const bf16x8*)(wh + lq * 8);
        bf16x8 bh1 = *(const bf16x8*)(wh + 32 + lq * 8);
        acc[n] = __builtin_amdgcn_mfma_f32_16x16x32_bf16(ahi[0], bh0, acc[n], 0, 0, 0);
        acc[n] = __builtin_amdgcn_mfma_f32_16x16x32_bf16(ahi[1], bh1, acc[n], 0, 0, 0);
        acc[n] = __builtin_amdgcn_mfma_f32_16x16x32_bf16(alo[0], bh0, acc[n], 0, 0, 0);
        acc[n] = __builtin_amdgcn_mfma_f32_16x16x32_bf16(alo[1], bh1, acc[n], 0, 0, 0);
        if (n >= 8) {
            const unsigned short* wl = Wlo_g + brow * 64;
            bf16x8 bl0 = *(const bf16x8*)(wl + lq * 8);
            bf16x8 bl1 = *(const bf16x8*)(wl + 32 + lq * 8);
            acc[n] = __builtin_amdgcn_mfma_f32_16x16x32_bf16(ahi[0], bl0, acc[n], 0, 0, 0);
            acc[n] = __builtin_amdgcn_mfma_f32_16x16x32_bf16(ahi[1], bl1, acc[n], 0, 0, 0);
        }
    }

    #pragma unroll
    for (int n = 0; n < 8; ++n) {
        float bb = b_V[n * 16 + l15];
        #pragma unroll
        for (int q = 0; q < 4; ++q)
            s_v[(w * 16 + lq * 4 + q) * 130 + n * 16 + l15] = f2bf(acc[n][q] + bb);
    }
    #pragma unroll
    for (int n = 8; n < 10; ++n) {
        #pragma unroll
        for (int q = 0; q < 4; ++q)
            s_eg[(w * 16 + lq * 4 + q) * 33 + (n - 8) * 16 + l15] = acc[n][q];
    }
    __syncthreads();

    {
        const int rr = t & 63, g = t >> 6;
        const int r1 = i0 + (rr >> 2);
        const int r2 = j0 + (rr & 3);
        #pragma unroll
        for (int io = 0; io < 2; ++io) {
            #pragma unroll
            for (int hs = 0; hs < 2; ++hs) {
                const int h = g + hs * 4;
                uint4 u4;
                unsigned int wv[4];
                #pragma unroll
                for (int dp = 0; dp < 4; ++dp) {
                    int c0 = io * 64 + (2 * dp) * 8 + h;
                    int c1 = io * 64 + (2 * dp + 1) * 8 + h;
                    wv[dp] = (unsigned int)s_v[rr * 130 + c0]
                           | ((unsigned int)s_v[rr * 130 + c1] << 16);
                }
                u4.x = wv[0]; u4.y = wv[1]; u4.z = wv[2]; u4.w = wv[3];
                if (io == 0) {
                    *(uint4*)(VtIn + ((size_t)((b * 8 + h) * N_ + r2)) * 3072 + (size_t)r1 * 8) = u4;
                } else {
                    *(uint4*)(VtOut + ((size_t)((b * 8 + h) * N_ + r1)) * 3072 + (size_t)r2 * 8) = u4;
                }
            }
        }
    }
    {
        const int rr = t >> 2, cq = (t & 3) * 4;
        const int r1 = i0 + (rr >> 2);
        const int r2 = j0 + (rr & 3);
        const float maskv = mask[(size_t)(b * N_ + r1) * N_ + r2];
        float4 v0, v1;
        float tmp0[4], tmp1[4];
        #pragma unroll
        for (int u = 0; u < 4; ++u) {
            int c2 = cq + u;
            float x = s_eg[rr * 33 + c2] + b_EG[c2] + maskv;
            if (c2 >= 8) x = 1.f / (1.f + expf(-x));
            tmp0[u] = x;
            int c3 = 16 + cq + u;
            float y = s_eg[rr * 33 + c3] + b_EG[c3] + maskv;
            if ((cq + u) >= 8) y = 1.f / (1.f + expf(-y));
            tmp1[u] = y;
        }
        v0.x = tmp0[0]; v0.y = tmp0[1]; v0.z = tmp0[2]; v0.w = tmp0[3];
        v1.x = tmp1[0]; v1.y = tmp1[1]; v1.z = tmp1[2]; v1.w = tmp1[3];
        *(float4*)(EGin   + ((size_t)((b * N_ + r1) * N_ + r2)) * 16 + cq) = v0;
        *(float4*)(EGoutT + ((size_t)((b * N_ + r2) * N_ + r1)) * 16 + cq) = v1;
    }
}

// ---------------------------------------------------------------------------
// Kernel 2m: merged softmax over k (round-17/18-verified verbatim).
// ---------------------------------------------------------------------------
__global__ __launch_bounds__(256) void k2m(
    const float* __restrict__ EGin, const float* __restrict__ EGoutT,
    unsigned short* __restrict__ A_in, unsigned short* __restrict__ A_outT)
{
    __shared__ float s[384 * 17];
    const int t = threadIdx.x;
    const int bid = blockIdx.x;
    const float* EG = (bid < 768) ? EGin : EGoutT;
    unsigned short* A = (bid < 768) ? A_in : A_outT;
    const int b2 = (bid < 768) ? bid : bid - 768;
    const int i = b2 % N_, b = b2 / N_;
    const float* base = EG + ((size_t)(b * N_ + i) * N_) * 16;
    for (int x = t; x < 6144; x += 256) {
        int k = x >> 4, c = x & 15;
        s[k * 17 + c] = base[x];
    }
    __syncthreads();
    const int h = t >> 5, l = t & 31;
    float ev[12];
    float mx = -1e30f;
    #pragma unroll
    for (int j = 0; j < 12; ++j) {
        ev[j] = s[(l + 32 * j) * 17 + h];
        mx = fmaxf(mx, ev[j]);
    }
    #pragma unroll
    for (int off = 16; off >= 1; off >>= 1) mx = fmaxf(mx, __shfl_xor(mx, off));
    float sum = 0.f;
    #pragma unroll
    for (int j = 0; j < 12; ++j) { ev[j] = expf(ev[j] - mx); sum += ev[j]; }
    #pragma unroll
    for (int off = 16; off >= 1; off >>= 1) sum += __shfl_xor(sum, off);
    const float inv = 1.f / sum;
    unsigned short* arow = A + ((size_t)((b * 8 + h) * N_ + i)) * N_;
    #pragma unroll
    for (int j = 0; j < 12; ++j) {
        int k = l + 32 * j;
        arow[k] = f2bf(ev[j] * inv * s[k * 17 + 8 + h]);
    }
}

// ---------------------------------------------------------------------------
// Kernel 3: batched MFMA GEMM (round-17/18-verified body + XCD swizzle).
// CHANGE: B global loads prefetched one iteration ahead, issued during the
// MFMA phase so their latency hides under compute (T14 async-STAGE split).
// Values and layouts bit-identical.
// ---------------------------------------------------------------------------
__global__ __launch_bounds__(256) void k3_mfma(
    const unsigned short* __restrict__ Aall,   // [32][384][384]
    const unsigned short* __restrict__ Vtall,  // [32][384][3072]  (k-major)
    unsigned short* __restrict__ C)            // [32][384][3072]
{
    __shared__ __align__(16) short sAB[17408];   // sA [128][64] + sB [128][72]
    short* sA = sAB;
    unsigned short* sB = (unsigned short*)(sAB + 8192);

    const int t = threadIdx.x;
    const int flat = blockIdx.x;                 // 0..2303
    const int swz = (flat & 7) * 288 + (flat >> 3);
    const int z  = swz / 72;
    const int rem = swz % 72;
    const int i0 = (rem / 24) * 128;
    const int n0 = (rem % 24) * 128;

    const unsigned short* Ap = Aall + (size_t)z * 147456;
    const unsigned short* Bp = Vtall + (size_t)z * 1179648;

    const int l = t & 63;
    const int w = t >> 6;
    const int wr = w >> 1, wc = w & 1;
    const int l15 = l & 15, lq = l >> 4;
    const int srow = l >> 3, schunk = (l & 7) ^ (l >> 3);
    const int ko = t >> 4;                       // staging k-offset (0..15)
    const int o  = t & 15;                       // staging jd-oct

    f32x4 acc[4][4];
    #pragma unroll
    for (int mi = 0; mi < 4; ++mi)
        #pragma unroll
        for (int ni = 0; ni < 4; ++ni) acc[mi][ni] = (f32x4){0.f, 0.f, 0.f, 0.f};

    // prologue: B regs for kt=0
    uint4 vB[4];
    #pragma unroll
    for (int rep = 0; rep < 4; ++rep)
        vB[rep] = *(const uint4*)(Bp + (size_t)(rep * 16 + ko) * 3072 + n0 + o * 8);

    #pragma unroll 1
    for (int kt = 0; kt < 6; ++kt) {
        const int k0 = kt * 64;
        // A: async gload16 into sA (verified path)
        #pragma unroll
        for (int i = 0; i < 4; ++i) {
            int rbase = w * 32 + i * 8;
            gload16(Ap + (size_t)(i0 + rbase + srow) * 384 + k0 + schunk * 8,
                    (char*)sA + rbase * 128);
        }
        // B: scatter current regs into sB (identical mapping to round 17/18)
        #pragma unroll
        for (int rep = 0; rep < 4; ++rep) {
            int kk = rep * 16 + ko;
            uint4 v = vB[rep];
            int cc = ((kk >> 3) ^ o) & 7;
            int base = (o * 8) * 72 + cc * 8 + (kk & 7);
            sB[base]       = (unsigned short)(v.x);
            sB[base + 72]  = (unsigned short)(v.x >> 16);
            sB[base + 144] = (unsigned short)(v.y);
            sB[base + 216] = (unsigned short)(v.y >> 16);
            sB[base + 288] = (unsigned short)(v.z);
            sB[base + 360] = (unsigned short)(v.z >> 16);
            sB[base + 432] = (unsigned short)(v.w);
            sB[base + 504] = (unsigned short)(v.w >> 16);
        }
        __syncthreads();

        // prefetch next B tile (latency hides under the MFMA phase below)
        if (kt < 5) {
            #pragma unroll
            for (int rep = 0; rep < 4; ++rep)
                vB[rep] = *(const uint4*)(Bp + (size_t)(k0 + 64 + rep * 16 + ko) * 3072 + n0 + o * 8);
        }

        bf16x8 av[4][2], bv[4][2];
        #pragma unroll
        for (int mi = 0; mi < 4; ++mi) {
            int row = wr * 64 + mi * 16 + l15;
            #pragma unroll
            for (int ks = 0; ks < 2; ++ks) {
                int kc = ks * 4 + lq;
                av[mi][ks] = *(const bf16x8*)((const char*)sA + row * 128 + ((kc ^ (row & 7)) << 4));
            }
        }
        #pragma unroll
        for (int ni = 0; ni < 4; ++ni) {
            int jd = wc * 64 + ni * 16 + l15;
            #pragma unroll
            for (int ks = 0; ks < 2; ++ks) {
                int c = ks * 4 + lq;
                int cc = (c ^ ((jd >> 3) & 7)) & 7;
                bv[ni][ks] = *(const bf16x8*)((const char*)sB + (jd * 72 + cc * 8) * 2);
            }
        }
        #pragma unroll
        for (int mi = 0; mi < 4; ++mi)
            #pragma unroll
            for (int ni = 0; ni < 4; ++ni) {
                acc[mi][ni] = __builtin_amdgcn_mfma_f32_16x16x32_bf16(av[mi][0], bv[ni][0], acc[mi][ni], 0, 0, 0);
                acc[mi][ni] = __builtin_amdgcn_mfma_f32_16x16x32_bf16(av[mi][1], bv[ni][1], acc[mi][ni], 0, 0, 0);
            }
        __syncthreads();
    }

    unsigned short* Cp = C + (size_t)z * 1179648;
    #pragma unroll
    for (int mi = 0; mi < 4; ++mi) {
        #pragma unroll
        for (int qq = 0; qq < 4; ++qq) {
            int row = i0 + wr * 64 + mi * 16 + lq * 4 + qq;
            unsigned short* crow = Cp + (size_t)row * 3072 + n0 + wc * 64 + l15;
            #pragma unroll
            for (int ni = 0; ni < 4; ++ni) crow[ni * 16] = f2bf(acc[mi][ni][qq]);
        }
    }
}

// ---------------------------------------------------------------------------
// Kernel 4: out = b_O + Va @ W_O via MFMA (round-18-verified verbatim).
// ---------------------------------------------------------------------------
__global__ __launch_bounds__(256) void k4_proj(
    const unsigned short* __restrict__ C,
    const unsigned short* __restrict__ WoHi, const unsigned short* __restrict__ WoLo,
    const float* __restrict__ b_O, float* __restrict__ out)
{
    __shared__ __align__(16) unsigned short s_ct[128 * 136];   // 34,816 B
    const int t = threadIdx.x;
    const int jt = blockIdx.x;
    const int i  = blockIdx.y;
    const int b  = blockIdx.z;

    #pragma unroll
    for (int rep = 0; rep < 8; ++rep) {
        int flat = rep * 256 + t;
        int p = flat >> 7, jj = flat & 127;
        int plane = b * 8 + (p & 7) + (p >> 3) * 16;
        uint4 v = *(const uint4*)(C + (size_t)plane * 1179648 + (size_t)i * 3072 + jt * 1024 + jj * 8);
        unsigned short* dst = s_ct + jj * 136 + p;
        dst[0]   = (unsigned short)(v.x);
        dst[16]  = (unsigned short)(v.x >> 16);
        dst[32]  = (unsigned short)(v.y);
        dst[48]  = (unsigned short)(v.y >> 16);
        dst[64]  = (unsigned short)(v.z);
        dst[80]  = (unsigned short)(v.z >> 16);
        dst[96]  = (unsigned short)(v.w);
        dst[112] = (unsigned short)(v.w >> 16);
    }
    __syncthreads();

    const int l = t & 63, w = t >> 6;
    const int l15 = l & 15, lq = l >> 4;

    f32x4 acc[2][4];
    #pragma unroll
    for (int m = 0; m < 2; ++m)
        #pragma unroll
        for (int nt = 0; nt < 4; ++nt) {
            float bb = b_O[nt * 16 + l15];
            acc[m][nt] = (f32x4){bb, bb, bb, bb};
        }

    #pragma unroll
    for (int ks = 0; ks < 4; ++ks) {
        bf16x8 av0 = *(const bf16x8*)(s_ct + (w * 32 + l15) * 136 + ks * 32 + lq * 8);
        bf16x8 av1 = *(const bf16x8*)(s_ct + (w * 32 + 16 + l15) * 136 + ks * 32 + lq * 8);
        #pragma unroll
        for (int nt = 0; nt < 4; ++nt) {
            bf16x8 bh = *(const bf16x8*)(WoHi + (nt * 16 + l15) * 128 + ks * 32 + lq * 8);
            bf16x8 bl = *(const bf16x8*)(WoLo + (nt * 16 + l15) * 128 + ks * 32 + lq * 8);
            acc[0][nt] = __builtin_amdgcn_mfma_f32_16x16x32_bf16(av0, bh, acc[0][nt], 0, 0, 0);
            acc[0][nt] = __builtin_amdgcn_mfma_f32_16x16x32_bf16(av0, bl, acc[0][nt], 0, 0, 0);
            acc[1][nt] = __builtin_amdgcn_mfma_f32_16x16x32_bf16(av1, bh, acc[1][nt], 0, 0, 0);
            acc[1][nt] = __builtin_amdgcn_mfma_f32_16x16x32_bf16(av1, bl, acc[1][nt], 0, 0, 0);
        }
    }

    #pragma unroll
    for (int m = 0; m < 2; ++m) {
        #pragma unroll
        for (int q = 0; q < 4; ++q) {
            int j = w * 32 + m * 16 + lq * 4 + q;
            float* orow = out + ((size_t)(b * N_ + i) * N_ + jt * 128 + j) * 64 + l15;
            orow[0]  = acc[m][0][q];
            orow[16] = acc[m][1][q];
            orow[32] = acc[m][2][q];
            orow[48] = acc[m][3][q];
        }
    }
}

// ---------------------------------------------------------------------------
extern "C" void kernel_launch(void* const* d_in, const int* in_sizes, int n_in,
                              void* d_out, int out_size, void* d_ws, size_t ws_size,
                              hipStream_t stream)
{
    const float* e    = (const float*)d_in[0];
    const float* mask = (const float*)d_in[1];
    const float* ln_w = (const float*)d_in[2];
    const float* ln_b = (const float*)d_in[3];
    const float* W_V  = (const float*)d_in[4];
    const float* b_V  = (const float*)d_in[5];
    const float* W_EG = (const float*)d_in[6];
    const float* b_EG = (const float*)d_in[7];
    const float* W_O  = (const float*)d_in[8];
    const float* b_O  = (const float*)d_in[9];
    float* out = (float*)d_out;

    char* ws = (char*)d_ws;
    unsigned short* VtIn   = (unsigned short*)(ws);               // 37,748,736
    unsigned short* VtOut  = (unsigned short*)(ws + 37748736);    // 37,748,736
    unsigned short* A_in   = (unsigned short*)(ws + 75497472);    //  4,718,592
    unsigned short* A_outT = (unsigned short*)(ws + 80216064);    //  4,718,592
    float* EGin   = (float*)(ws + 84934656);                      // 18,874,368 (dead after k2m)
    float* EGoutT = (float*)(ws + 103809024);                     // 18,874,368 (dead after k2m)
    unsigned short* Cws    = (unsigned short*)(ws + 84934656);    // 75,497,472 (overlays EG)
    unsigned short* Whi = A_in;                                   // k0->k1 transient
    unsigned short* Wlo = A_in + 10240;
    unsigned short* WoHi = (unsigned short*)(ws + 160432128);     // 16,384 B (live to k4)
    unsigned short* WoLo = (unsigned short*)(ws + 160448512);     // 16,384 B

    hipLaunchKernelGGL(k0_prep, dim3(72), dim3(256), 0, stream,
                       W_V, W_EG, W_O, Whi, Wlo, WoHi, WoLo);
    hipLaunchKernelGGL(k1_ln_proj, dim3(96, 24, 2), dim3(256), 0, stream,
                       e, mask, ln_w, ln_b, Whi, Wlo, b_V, b_EG, VtIn, VtOut, EGin, EGoutT);
    hipLaunchKernelGGL(k2m, dim3(1536), dim3(256), 0, stream,
                       EGin, EGoutT, A_in, A_outT);
    hipLaunchKernelGGL(k3_mfma, dim3(2304), dim3(256), 0, stream,
                       A_in, VtIn, Cws);
    hipLaunchKernelGGL(k4_proj, dim3(3, 384, 2), dim3(256), 0, stream,
                       Cws, WoHi, WoLo, b_O, out);
}

// Round 20
// 203.706 us; speedup vs baseline: 1.8481x; 1.0105x over previous
//
#include <hip/hip_runtime.h>

#define N_ 384
#define LNEPS 1e-5f

typedef __attribute__((ext_vector_type(8))) short bf16x8;
typedef __attribute__((ext_vector_type(4))) float f32x4;

__device__ __forceinline__ float bf2f(unsigned int u) {
    union { unsigned int i; float f; } v; v.i = u << 16; return v.f;
}
__device__ __forceinline__ unsigned short f2bf(float f) {
    union { float f; unsigned int i; } v; v.f = f;
    return (unsigned short)((v.i + 0x7FFFu + ((v.i >> 16) & 1u)) >> 16);
}
__device__ __forceinline__ void gload16(const void* g, void* l) {
    __builtin_amdgcn_global_load_lds(
        (const __attribute__((address_space(1))) void*)g,
        (__attribute__((address_space(3))) void*)l, 16, 0, 0);
}

// ---------------------------------------------------------------------------
// Kernel 0: bf16 hi/lo for projection weights [col][k] AND transposed W_O.
// ---------------------------------------------------------------------------
__global__ __launch_bounds__(256) void k0_prep(
    const float* __restrict__ W_V, const float* __restrict__ W_EG,
    const float* __restrict__ W_O,
    unsigned short* __restrict__ Whi, unsigned short* __restrict__ Wlo,
    unsigned short* __restrict__ WoHi, unsigned short* __restrict__ WoLo)
{
    int x = blockIdx.x * 256 + threadIdx.x;
    if (x < 10240) {
        int col = x >> 6, k = x & 63;
        float wv = (col < 128) ? W_V[k * 128 + col] : W_EG[k * 32 + (col - 128)];
        unsigned short hi = f2bf(wv);
        Whi[x] = hi;
        Wlo[x] = f2bf(wv - bf2f(hi));
    } else if (x < 18432) {
        int y = x - 10240;
        int cout = y >> 7, c = y & 127;
        float wv = W_O[c * 64 + cout];
        unsigned short hi = f2bf(wv);
        WoHi[y] = hi;
        WoLo[y] = f2bf(wv - bf2f(hi));
    }
}

// ---------------------------------------------------------------------------
// Kernel 1: LN + V/EG projections (round-16..19-verified VERBATIM).
// ---------------------------------------------------------------------------
__global__ __launch_bounds__(256) void k1_ln_proj(
    const float* __restrict__ e, const float* __restrict__ mask,
    const float* __restrict__ ln_w, const float* __restrict__ ln_b,
    const unsigned short* __restrict__ Whi_g, const unsigned short* __restrict__ Wlo_g,
    const float* __restrict__ b_V, const float* __restrict__ b_EG,
    unsigned short* __restrict__ VtIn, unsigned short* __restrict__ VtOut,
    float* __restrict__ EGin, float* __restrict__ EGoutT)
{
    __shared__ __align__(16) char smem[25088];
    unsigned short* s_v = (unsigned short*)smem;
    float* s_eg = (float*)(smem + 16640);

    const int t = threadIdx.x;
    const int j0 = blockIdx.x * 4;
    const int i0 = blockIdx.y * 16;
    const int b  = blockIdx.z;

    const int l = t & 63, w = t >> 6;
    const int l15 = l & 15, lq = l >> 4;

    const int r = w * 16 + l15;
    const int r1f = i0 + (r >> 2), r2f = j0 + (r & 3);
    const float* erow = e + ((size_t)((b * N_ + r1f) * N_ + r2f)) * 64;
    float ev[16];
    {
        float4 e0 = *(const float4*)(erow + lq * 8);
        float4 e1 = *(const float4*)(erow + lq * 8 + 4);
        float4 e2 = *(const float4*)(erow + 32 + lq * 8);
        float4 e3 = *(const float4*)(erow + 32 + lq * 8 + 4);
        ev[0]=e0.x; ev[1]=e0.y; ev[2]=e0.z;  ev[3]=e0.w;
        ev[4]=e1.x; ev[5]=e1.y; ev[6]=e1.z;  ev[7]=e1.w;
        ev[8]=e2.x; ev[9]=e2.y; ev[10]=e2.z; ev[11]=e2.w;
        ev[12]=e3.x; ev[13]=e3.y; ev[14]=e3.z; ev[15]=e3.w;
    }
    float s = 0.f, sq = 0.f;
    #pragma unroll
    for (int j = 0; j < 16; ++j) { s += ev[j]; sq += ev[j] * ev[j]; }
    s  += __shfl_xor(s, 16);  s  += __shfl_xor(s, 32);
    sq += __shfl_xor(sq, 16); sq += __shfl_xor(sq, 32);
    const float mean = s * (1.f / 64.f);
    const float rstd = rsqrtf(sq * (1.f / 64.f) - mean * mean + LNEPS);

    bf16x8 ahi[2], alo[2];
    {
        float lnwv[16], lnbv[16];
        float4 w0 = *(const float4*)(ln_w + lq * 8);
        float4 w1 = *(const float4*)(ln_w + lq * 8 + 4);
        float4 w2 = *(const float4*)(ln_w + 32 + lq * 8);
        float4 w3 = *(const float4*)(ln_w + 32 + lq * 8 + 4);
        lnwv[0]=w0.x; lnwv[1]=w0.y; lnwv[2]=w0.z;  lnwv[3]=w0.w;
        lnwv[4]=w1.x; lnwv[5]=w1.y; lnwv[6]=w1.z;  lnwv[7]=w1.w;
        lnwv[8]=w2.x; lnwv[9]=w2.y; lnwv[10]=w2.z; lnwv[11]=w2.w;
        lnwv[12]=w3.x; lnwv[13]=w3.y; lnwv[14]=w3.z; lnwv[15]=w3.w;
        float4 b0 = *(const float4*)(ln_b + lq * 8);
        float4 b1 = *(const float4*)(ln_b + lq * 8 + 4);
        float4 b2 = *(const float4*)(ln_b + 32 + lq * 8);
        float4 b3 = *(const float4*)(ln_b + 32 + lq * 8 + 4);
        lnbv[0]=b0.x; lnbv[1]=b0.y; lnbv[2]=b0.z;  lnbv[3]=b0.w;
        lnbv[4]=b1.x; lnbv[5]=b1.y; lnbv[6]=b1.z;  lnbv[7]=b1.w;
        lnbv[8]=b2.x; lnbv[9]=b2.y; lnbv[10]=b2.z; lnbv[11]=b2.w;
        lnbv[12]=b3.x; lnbv[13]=b3.y; lnbv[14]=b3.z; lnbv[15]=b3.w;
        #pragma unroll
        for (int ks = 0; ks < 2; ++ks) {
            #pragma unroll
            for (int j = 0; j < 8; ++j) {
                float x = (ev[ks * 8 + j] - mean) * rstd * lnwv[ks * 8 + j] + lnbv[ks * 8 + j];
                unsigned short h = f2bf(x);
                unsigned short lo = f2bf(x - bf2f(h));
                ahi[ks][j] = (short)h;
                alo[ks][j] = (short)lo;
            }
        }
    }

    f32x4 acc[10];
    #pragma unroll
    for (int n = 0; n < 10; ++n) acc[n] = (f32x4){0.f, 0.f, 0.f, 0.f};

    #pragma unroll
    for (int n = 0; n < 10; ++n) {
        int brow = n * 16 + l15;
        const unsigned short* wh = Whi_g + brow * 64;
        bf16x8 bh0 = *(const bf16x8*)(wh + lq * 8);
        bf16x8 bh1 = *(const bf16x8*)(wh + 32 + lq * 8);
        acc[n] = __builtin_amdgcn_mfma_f32_16x16x32_bf16(ahi[0], bh0, acc[n], 0, 0, 0);
        acc[n] = __builtin_amdgcn_mfma_f32_16x16x32_bf16(ahi[1], bh1, acc[n], 0, 0, 0);
        acc[n] = __builtin_amdgcn_mfma_f32_16x16x32_bf16(alo[0], bh0, acc[n], 0, 0, 0);
        acc[n] = __builtin_amdgcn_mfma_f32_16x16x32_bf16(alo[1], bh1, acc[n], 0, 0, 0);
        if (n >= 8) {
            const unsigned short* wl = Wlo_g + brow * 64;
            bf16x8 bl0 = *(const bf16x8*)(wl + lq * 8);
            bf16x8 bl1 = *(const bf16x8*)(wl + 32 + lq * 8);
            acc[n] = __builtin_amdgcn_mfma_f32_16x16x32_bf16(ahi[0], bl0, acc[n], 0, 0, 0);
            acc[n] = __builtin_amdgcn_mfma_f32_16x16x32_bf16(ahi[1], bl1, acc[n], 0, 0, 0);
        }
    }

    #pragma unroll
    for (int n = 0; n < 8; ++n) {
        float bb = b_V[n * 16 + l15];
        #pragma unroll
        for (int q = 0; q < 4; ++q)
            s_v[(w * 16 + lq * 4 + q) * 130 + n * 16 + l15] = f2bf(acc[n][q] + bb);
    }
    #pragma unroll
    for (int n = 8; n < 10; ++n) {
        #pragma unroll
        for (int q = 0; q < 4; ++q)
            s_eg[(w * 16 + lq * 4 + q) * 33 + (n - 8) * 16 + l15] = acc[n][q];
    }
    __syncthreads();

    {
        const int rr = t & 63, g = t >> 6;
        const int r1 = i0 + (rr >> 2);
        const int r2 = j0 + (rr & 3);
        #pragma unroll
        for (int io = 0; io < 2; ++io) {
            #pragma unroll
            for (int hs = 0; hs < 2; ++hs) {
                const int h = g + hs * 4;
                uint4 u4;
                unsigned int wv[4];
                #pragma unroll
                for (int dp = 0; dp < 4; ++dp) {
                    int c0 = io * 64 + (2 * dp) * 8 + h;
                    int c1 = io * 64 + (2 * dp + 1) * 8 + h;
                    wv[dp] = (unsigned int)s_v[rr * 130 + c0]
                           | ((unsigned int)s_v[rr * 130 + c1] << 16);
                }
                u4.x = wv[0]; u4.y = wv[1]; u4.z = wv[2]; u4.w = wv[3];
                if (io == 0) {
                    *(uint4*)(VtIn + ((size_t)((b * 8 + h) * N_ + r2)) * 3072 + (size_t)r1 * 8) = u4;
                } else {
                    *(uint4*)(VtOut + ((size_t)((b * 8 + h) * N_ + r1)) * 3072 + (size_t)r2 * 8) = u4;
                }
            }
        }
    }
    {
        const int rr = t >> 2, cq = (t & 3) * 4;
        const int r1 = i0 + (rr >> 2);
        const int r2 = j0 + (rr & 3);
        const float maskv = mask[(size_t)(b * N_ + r1) * N_ + r2];
        float4 v0, v1;
        float tmp0[4], tmp1[4];
        #pragma unroll
        for (int u = 0; u < 4; ++u) {
            int c2 = cq + u;
            float x = s_eg[rr * 33 + c2] + b_EG[c2] + maskv;
            if (c2 >= 8) x = 1.f / (1.f + expf(-x));
            tmp0[u] = x;
            int c3 = 16 + cq + u;
            float y = s_eg[rr * 33 + c3] + b_EG[c3] + maskv;
            if ((cq + u) >= 8) y = 1.f / (1.f + expf(-y));
            tmp1[u] = y;
        }
        v0.x = tmp0[0]; v0.y = tmp0[1]; v0.z = tmp0[2]; v0.w = tmp0[3];
        v1.x = tmp1[0]; v1.y = tmp1[1]; v1.z = tmp1[2]; v1.w = tmp1[3];
        *(float4*)(EGin   + ((size_t)((b * N_ + r1) * N_ + r2)) * 16 + cq) = v0;
        *(float4*)(EGoutT + ((size_t)((b * N_ + r2) * N_ + r1)) * 16 + cq) = v1;
    }
}

// ---------------------------------------------------------------------------
// Kernel 2m: merged softmax over k (round-17..19-verified verbatim).
// ---------------------------------------------------------------------------
__global__ __launch_bounds__(256) void k2m(
    const float* __restrict__ EGin, const float* __restrict__ EGoutT,
    unsigned short* __restrict__ A_in, unsigned short* __restrict__ A_outT)
{
    __shared__ float s[384 * 17];
    const int t = threadIdx.x;
    const int bid = blockIdx.x;
    const float* EG = (bid < 768) ? EGin : EGoutT;
    unsigned short* A = (bid < 768) ? A_in : A_outT;
    const int b2 = (bid < 768) ? bid : bid - 768;
    const int i = b2 % N_, b = b2 / N_;
    const float* base = EG + ((size_t)(b * N_ + i) * N_) * 16;
    for (int x = t; x < 6144; x += 256) {
        int k = x >> 4, c = x & 15;
        s[k * 17 + c] = base[x];
    }
    __syncthreads();
    const int h = t >> 5, l = t & 31;
    float ev[12];
    float mx = -1e30f;
    #pragma unroll
    for (int j = 0; j < 12; ++j) {
        ev[j] = s[(l + 32 * j) * 17 + h];
        mx = fmaxf(mx, ev[j]);
    }
    #pragma unroll
    for (int off = 16; off >= 1; off >>= 1) mx = fmaxf(mx, __shfl_xor(mx, off));
    float sum = 0.f;
    #pragma unroll
    for (int j = 0; j < 12; ++j) { ev[j] = expf(ev[j] - mx); sum += ev[j]; }
    #pragma unroll
    for (int off = 16; off >= 1; off >>= 1) sum += __shfl_xor(sum, off);
    const float inv = 1.f / sum;
    unsigned short* arow = A + ((size_t)((b * 8 + h) * N_ + i)) * N_;
    #pragma unroll
    for (int j = 0; j < 12; ++j) {
        int k = l + 32 * j;
        arow[k] = f2bf(ev[j] * inv * s[k * 17 + 8 + h]);
    }
}

// ---------------------------------------------------------------------------
// Kernel 3: batched MFMA GEMM (round-19-verified body + XCD swizzle +
// B-reg prefetch). CHANGE: double-buffered sA; A gloads for kt+1 issued
// during kt's MFMA phase so their latency hides under compute too.
// Values bit-identical.
// ---------------------------------------------------------------------------
__global__ __launch_bounds__(256) void k3_mfma(
    const unsigned short* __restrict__ Aall,   // [32][384][384]
    const unsigned short* __restrict__ Vtall,  // [32][384][3072]  (k-major)
    unsigned short* __restrict__ C)            // [32][384][3072]
{
    __shared__ __align__(16) short sAB[25600];   // sA0 [128][64] + sA1 [128][64] + sB [128][72]
    unsigned short* sB = (unsigned short*)(sAB + 16384);

    const int t = threadIdx.x;
    const int flat = blockIdx.x;                 // 0..2303
    const int swz = (flat & 7) * 288 + (flat >> 3);
    const int z  = swz / 72;
    const int rem = swz % 72;
    const int i0 = (rem / 24) * 128;
    const int n0 = (rem % 24) * 128;

    const unsigned short* Ap = Aall + (size_t)z * 147456;
    const unsigned short* Bp = Vtall + (size_t)z * 1179648;

    const int l = t & 63;
    const int w = t >> 6;
    const int wr = w >> 1, wc = w & 1;
    const int l15 = l & 15, lq = l >> 4;
    const int srow = l >> 3, schunk = (l & 7) ^ (l >> 3);
    const int ko = t >> 4;                       // staging k-offset (0..15)
    const int o  = t & 15;                       // staging jd-oct

    f32x4 acc[4][4];
    #pragma unroll
    for (int mi = 0; mi < 4; ++mi)
        #pragma unroll
        for (int ni = 0; ni < 4; ++ni) acc[mi][ni] = (f32x4){0.f, 0.f, 0.f, 0.f};

    // prologue: A(kt=0) -> sA0, B regs for kt=0
    #pragma unroll
    for (int i = 0; i < 4; ++i) {
        int rbase = w * 32 + i * 8;
        gload16(Ap + (size_t)(i0 + rbase + srow) * 384 + schunk * 8,
                (char*)sAB + rbase * 128);
    }
    uint4 vB[4];
    #pragma unroll
    for (int rep = 0; rep < 4; ++rep)
        vB[rep] = *(const uint4*)(Bp + (size_t)(rep * 16 + ko) * 3072 + n0 + o * 8);

    #pragma unroll 1
    for (int kt = 0; kt < 6; ++kt) {
        short* sAcur = (kt & 1) ? (sAB + 8192) : sAB;
        short* sAnxt = (kt & 1) ? sAB : (sAB + 8192);

        // B: scatter current regs into sB (identical mapping)
        #pragma unroll
        for (int rep = 0; rep < 4; ++rep) {
            int kk = rep * 16 + ko;
            uint4 v = vB[rep];
            int cc = ((kk >> 3) ^ o) & 7;
            int base = (o * 8) * 72 + cc * 8 + (kk & 7);
            sB[base]       = (unsigned short)(v.x);
            sB[base + 72]  = (unsigned short)(v.x >> 16);
            sB[base + 144] = (unsigned short)(v.y);
            sB[base + 216] = (unsigned short)(v.y >> 16);
            sB[base + 288] = (unsigned short)(v.z);
            sB[base + 360] = (unsigned short)(v.z >> 16);
            sB[base + 432] = (unsigned short)(v.w);
            sB[base + 504] = (unsigned short)(v.w >> 16);
        }
        __syncthreads();

        // prefetch next tiles (latency hides under MFMA phase below)
        if (kt < 5) {
            const int k0n = (kt + 1) * 64;
            #pragma unroll
            for (int i = 0; i < 4; ++i) {
                int rbase = w * 32 + i * 8;
                gload16(Ap + (size_t)(i0 + rbase + srow) * 384 + k0n + schunk * 8,
                        (char*)sAnxt + rbase * 128);
            }
            #pragma unroll
            for (int rep = 0; rep < 4; ++rep)
                vB[rep] = *(const uint4*)(Bp + (size_t)(k0n + rep * 16 + ko) * 3072 + n0 + o * 8);
        }

        bf16x8 av[4][2], bv[4][2];
        #pragma unroll
        for (int mi = 0; mi < 4; ++mi) {
            int row = wr * 64 + mi * 16 + l15;
            #pragma unroll
            for (int ks = 0; ks < 2; ++ks) {
                int kc = ks * 4 + lq;
                av[mi][ks] = *(const bf16x8*)((const char*)sAcur + row * 128 + ((kc ^ (row & 7)) << 4));
            }
        }
        #pragma unroll
        for (int ni = 0; ni < 4; ++ni) {
            int jd = wc * 64 + ni * 16 + l15;
            #pragma unroll
            for (int ks = 0; ks < 2; ++ks) {
                int c = ks * 4 + lq;
                int cc = (c ^ ((jd >> 3) & 7)) & 7;
                bv[ni][ks] = *(const bf16x8*)((const char*)sB + (jd * 72 + cc * 8) * 2);
            }
        }
        #pragma unroll
        for (int mi = 0; mi < 4; ++mi)
            #pragma unroll
            for (int ni = 0; ni < 4; ++ni) {
                acc[mi][ni] = __builtin_amdgcn_mfma_f32_16x16x32_bf16(av[mi][0], bv[ni][0], acc[mi][ni], 0, 0, 0);
                acc[mi][ni] = __builtin_amdgcn_mfma_f32_16x16x32_bf16(av[mi][1], bv[ni][1], acc[mi][ni], 0, 0, 0);
            }
        __syncthreads();
    }

    unsigned short* Cp = C + (size_t)z * 1179648;
    #pragma unroll
    for (int mi = 0; mi < 4; ++mi) {
        #pragma unroll
        for (int qq = 0; qq < 4; ++qq) {
            int row = i0 + wr * 64 + mi * 16 + lq * 4 + qq;
            unsigned short* crow = Cp + (size_t)row * 3072 + n0 + wc * 64 + l15;
            #pragma unroll
            for (int ni = 0; ni < 4; ++ni) crow[ni * 16] = f2bf(acc[mi][ni][qq]);
        }
    }
}

// ---------------------------------------------------------------------------
// Kernel 4: out = b_O + Va @ W_O via MFMA (round-18/19-verified verbatim).
// ---------------------------------------------------------------------------
__global__ __launch_bounds__(256) void k4_proj(
    const unsigned short* __restrict__ C,
    const unsigned short* __restrict__ WoHi, const unsigned short* __restrict__ WoLo,
    const float* __restrict__ b_O, float* __restrict__ out)
{
    __shared__ __align__(16) unsigned short s_ct[128 * 136];   // 34,816 B
    const int t = threadIdx.x;
    const int jt = blockIdx.x;
    const int i  = blockIdx.y;
    const int b  = blockIdx.z;

    #pragma unroll
    for (int rep = 0; rep < 8; ++rep) {
        int flat = rep * 256 + t;
        int p = flat >> 7, jj = flat & 127;
        int plane = b * 8 + (p & 7) + (p >> 3) * 16;
        uint4 v = *(const uint4*)(C + (size_t)plane * 1179648 + (size_t)i * 3072 + jt * 1024 + jj * 8);
        unsigned short* dst = s_ct + jj * 136 + p;
        dst[0]   = (unsigned short)(v.x);
        dst[16]  = (unsigned short)(v.x >> 16);
        dst[32]  = (unsigned short)(v.y);
        dst[48]  = (unsigned short)(v.y >> 16);
        dst[64]  = (unsigned short)(v.z);
        dst[80]  = (unsigned short)(v.z >> 16);
        dst[96]  = (unsigned short)(v.w);
        dst[112] = (unsigned short)(v.w >> 16);
    }
    __syncthreads();

    const int l = t & 63, w = t >> 6;
    const int l15 = l & 15, lq = l >> 4;

    f32x4 acc[2][4];
    #pragma unroll
    for (int m = 0; m < 2; ++m)
        #pragma unroll
        for (int nt = 0; nt < 4; ++nt) {
            float bb = b_O[nt * 16 + l15];
            acc[m][nt] = (f32x4){bb, bb, bb, bb};
        }

    #pragma unroll
    for (int ks = 0; ks < 4; ++ks) {
        bf16x8 av0 = *(const bf16x8*)(s_ct + (w * 32 + l15) * 136 + ks * 32 + lq * 8);
        bf16x8 av1 = *(const bf16x8*)(s_ct + (w * 32 + 16 + l15) * 136 + ks * 32 + lq * 8);
        #pragma unroll
        for (int nt = 0; nt < 4; ++nt) {
            bf16x8 bh = *(const bf16x8*)(WoHi + (nt * 16 + l15) * 128 + ks * 32 + lq * 8);
            bf16x8 bl = *(const bf16x8*)(WoLo + (nt * 16 + l15) * 128 + ks * 32 + lq * 8);
            acc[0][nt] = __builtin_amdgcn_mfma_f32_16x16x32_bf16(av0, bh, acc[0][nt], 0, 0, 0);
            acc[0][nt] = __builtin_amdgcn_mfma_f32_16x16x32_bf16(av0, bl, acc[0][nt], 0, 0, 0);
            acc[1][nt] = __builtin_amdgcn_mfma_f32_16x16x32_bf16(av1, bh, acc[1][nt], 0, 0, 0);
            acc[1][nt] = __builtin_amdgcn_mfma_f32_16x16x32_bf16(av1, bl, acc[1][nt], 0, 0, 0);
        }
    }

    #pragma unroll
    for (int m = 0; m < 2; ++m) {
        #pragma unroll
        for (int q = 0; q < 4; ++q) {
            int j = w * 32 + m * 16 + lq * 4 + q;
            float* orow = out + ((size_t)(b * N_ + i) * N_ + jt * 128 + j) * 64 + l15;
            orow[0]  = acc[m][0][q];
            orow[16] = acc[m][1][q];
            orow[32] = acc[m][2][q];
            orow[48] = acc[m][3][q];
        }
    }
}

// ---------------------------------------------------------------------------
extern "C" void kernel_launch(void* const* d_in, const int* in_sizes, int n_in,
                              void* d_out, int out_size, void* d_ws, size_t ws_size,
                              hipStream_t stream)
{
    const float* e    = (const float*)d_in[0];
    const float* mask = (const float*)d_in[1];
    const float* ln_w = (const float*)d_in[2];
    const float* ln_b = (const float*)d_in[3];
    const float* W_V  = (const float*)d_in[4];
    const float* b_V  = (const float*)d_in[5];
    const float* W_EG = (const float*)d_in[6];
    const float* b_EG = (const float*)d_in[7];
    const float* W_O  = (const float*)d_in[8];
    const float* b_O  = (const float*)d_in[9];
    float* out = (float*)d_out;

    char* ws = (char*)d_ws;
    unsigned short* VtIn   = (unsigned short*)(ws);               // 37,748,736
    unsigned short* VtOut  = (unsigned short*)(ws + 37748736);    // 37,748,736
    unsigned short* A_in   = (unsigned short*)(ws + 75497472);    //  4,718,592
    unsigned short* A_outT = (unsigned short*)(ws + 80216064);    //  4,718,592
    float* EGin   = (float*)(ws + 84934656);                      // 18,874,368 (dead after k2m)
    float* EGoutT = (float*)(ws + 103809024);                     // 18,874,368 (dead after k2m)
    unsigned short* Cws    = (unsigned short*)(ws + 84934656);    // 75,497,472 (overlays EG)
    unsigned short* Whi = A_in;                                   // k0->k1 transient
    unsigned short* Wlo = A_in + 10240;
    unsigned short* WoHi = (unsigned short*)(ws + 160432128);     // 16,384 B (live to k4)
    unsigned short* WoLo = (unsigned short*)(ws + 160448512);     // 16,384 B

    hipLaunchKernelGGL(k0_prep, dim3(72), dim3(256), 0, stream,
                       W_V, W_EG, W_O, Whi, Wlo, WoHi, WoLo);
    hipLaunchKernelGGL(k1_ln_proj, dim3(96, 24, 2), dim3(256), 0, stream,
                       e, mask, ln_w, ln_b, Whi, Wlo, b_V, b_EG, VtIn, VtOut, EGin, EGoutT);
    hipLaunchKernelGGL(k2m, dim3(1536), dim3(256), 0, stream,
                       EGin, EGoutT, A_in, A_outT);
    hipLaunchKernelGGL(k3_mfma, dim3(2304), dim3(256), 0, stream,
                       A_in, VtIn, Cws);
    hipLaunchKernelGGL(k4_proj, dim3(3, 384, 2), dim3(256), 0, stream,
                       Cws, WoHi, WoLo, b_O, out);
}